// Round 9
// baseline (3899.146 us; speedup 1.0000x reference)
//
#include <hip/hip_runtime.h>
#include <cstdint>
#include <cstddef>

// VN-PointNet encoder. Inputs fp32, outputs fp32 (out 8x2046 ++ z0 8x3x3x4096).
// Early chain (pos..st3, st_pool) fp32 (argmax-exact), double-buffered LDS
// GEMM. Post-pool chain (c2,c3,std1,std2,z0) on bf16 MFMA with k-major
// transposed tensors [b][v][n][Cpad]. KNN: one wave/point, register top-8.
// Standard (B,C,3,N) layout: flat ((b*C+c)*3+v)*N + n.

typedef unsigned short u16;
using bh8  = __attribute__((ext_vector_type(8))) short;
using f32x4 = __attribute__((ext_vector_type(4))) float;

__device__ __forceinline__ float b2f(u16 v) {
  return __uint_as_float(((unsigned)v) << 16);
}
__device__ __forceinline__ u16 f2b(float f) {
  unsigned u = __float_as_uint(f);
  u += 0x7FFFu + ((u >> 16) & 1u);   // round-to-nearest-even
  return (u16)(u >> 16);
}

__device__ __forceinline__ float ldg(const float* p, size_t i) { return p[i]; }
__device__ __forceinline__ float ldg(const u16* p, size_t i) { return b2f(p[i]); }
__device__ __forceinline__ void st4(float* p, size_t i, float a, float b, float c, float d) {
  float4 v; v.x = a; v.y = b; v.z = c; v.w = d; *(float4*)(p + i) = v;
}

#define FMA4(A, S, V) { A.x += (S)*(V).x; A.y += (S)*(V).y; A.z += (S)*(V).z; A.w += (S)*(V).w; }

__device__ __forceinline__ unsigned long long packKey(float v, int n) {
  unsigned u = __float_as_uint(v);
  u = (u & 0x80000000u) ? ~u : (u | 0x80000000u);   // total-order float
  return ((unsigned long long)u << 32) | (unsigned long long)(0xFFFFFFFFu - (unsigned)n);
}

// ------------------------------------------- KNN top-20: one wave per point
#define CSWAP(T) { if (c > T) { unsigned long long tmp = T; T = c; c = tmp; } }
__global__ __launch_bounds__(256) void knn_kernel(const float* __restrict__ x,
                                                  int* __restrict__ idxOut, int N) {
  int b = blockIdx.y;
  int wv = threadIdx.x >> 6, lane = threadIdx.x & 63;
  int i = blockIdx.x * 4 + wv;
  const float* xb = x + (size_t)b * 3 * N;
  float xi0 = xb[i], xi1 = xb[N + i], xi2 = xb[2 * (size_t)N + i];
  float xxi = xi0 * xi0 + xi1 * xi1 + xi2 * xi2;
  unsigned long long t0 = 0, t1 = 0, t2 = 0, t3 = 0, t4 = 0, t5 = 0, t6 = 0, t7 = 0;
  #pragma unroll 8
  for (int s = 0; s < 64; ++s) {
    int j = s * 64 + lane;
    float a0 = xb[j], a1 = xb[N + j], a2 = xb[2 * (size_t)N + j];
    float inner = xi0 * a0 + xi1 * a1 + xi2 * a2;
    float xxj = a0 * a0 + a1 * a1 + a2 * a2;
    float pd = 2.f * inner - xxi - xxj;          // = -||xi-xj||^2
    unsigned long long c = packKey(pd, j);
    if (c > t7) { CSWAP(t0) CSWAP(t1) CSWAP(t2) CSWAP(t3) CSWAP(t4) CSWAP(t5) CSWAP(t6) CSWAP(t7) }
  }
  int* row = idxOut + ((size_t)b * N + i) * 20;
  for (int kk = 0; kk < 20; ++kk) {
    unsigned long long k = t0;
    #pragma unroll
    for (int off = 1; off < 64; off <<= 1) {
      unsigned long long o = __shfl_xor(k, off);
      if (o > k) k = o;
    }
    if (lane == 0) row[kk] = (int)(0xFFFFFFFFu - (unsigned)(k & 0xFFFFFFFFull));
    if (k == t0) { t0 = t1; t1 = t2; t2 = t3; t3 = t4; t4 = t5; t5 = t6; t6 = t7; t7 = 0; }
  }
}
#undef CSWAP

// ------------------------------------------------- pos layer: bn statistics
__global__ __launch_bounds__(256) void pos_stats(const float* __restrict__ x,
                                                 const int* __restrict__ idx,
                                                 const float* __restrict__ Wf,
                                                 float* __restrict__ statSum,
                                                 float* __restrict__ statSq, int N) {
  __shared__ float wf[64];
  __shared__ float part[4][42];
  int tid = threadIdx.x;
  if (tid < 63) wf[tid] = Wf[tid];
  __syncthreads();
  int b = blockIdx.y;
  int lin = blockIdx.x * 256 + tid;           // over N*20 exactly
  int n = lin / 20, kk = lin - n * 20;
  const float* xb = x + (size_t)b * 3 * N;
  int j = idx[((size_t)b * N + n) * 20 + kk];
  float c0 = xb[n], c1 = xb[N + n], c2 = xb[2 * (size_t)N + n];
  float a0 = xb[j], a1 = xb[N + j], a2 = xb[2 * (size_t)N + j];
  float e00 = a0 - c0, e01 = a1 - c1, e02 = a2 - c2;
  float e20 = a1 * c2 - a2 * c1, e21 = a2 * c0 - a0 * c2, e22 = a0 * c1 - a1 * c0;
  int lane = tid & 63, wave = tid >> 6;
  #pragma unroll
  for (int c = 0; c < 21; ++c) {
    float w0 = wf[c * 3], w1 = wf[c * 3 + 1], w2 = wf[c * 3 + 2];
    float p0 = w0 * e00 + w1 * c0 + w2 * e20;
    float p1 = w0 * e01 + w1 * c1 + w2 * e21;
    float p2 = w0 * e02 + w1 * c2 + w2 * e22;
    float nr = sqrtf(p0 * p0 + p1 * p1 + p2 * p2) + 1e-6f;
    float u1 = nr, u2 = nr * nr;
    #pragma unroll
    for (int off = 32; off; off >>= 1) { u1 += __shfl_down(u1, off); u2 += __shfl_down(u2, off); }
    if (lane == 0) { part[wave][c] = u1; part[wave][21 + c] = u2; }
  }
  __syncthreads();
  if (tid < 42) {
    float t = part[0][tid] + part[1][tid] + part[2][tid] + part[3][tid];
    if (tid < 21) atomicAdd(&statSum[tid], t);
    else atomicAdd(&statSq[tid - 21], t);
  }
}

// ------------- pos layer: lrelu + maxpool over k fused (one wave per point)
__global__ __launch_bounds__(64) void pos_apply(const float* __restrict__ x,
                                                const int* __restrict__ idx,
                                                const float* __restrict__ Wf,
                                                const float* __restrict__ Wd,
                                                const float* __restrict__ Wpool,
                                                const float* __restrict__ statMean,
                                                const float* __restrict__ statIstd,
                                                float* __restrict__ h0, int N) {
  __shared__ float wpool[441];
  __shared__ float hbuf[64];
  int tid = threadIdx.x;
  for (int l = tid; l < 441; l += 64) wpool[l] = Wpool[l];
  int b = blockIdx.y, n = blockIdx.x;
  bool act = tid < 63;
  int c = act ? tid / 3 : 0;
  int v = act ? tid - c * 3 : 0;
  const float* xb = x + (size_t)b * 3 * N;
  float c0 = xb[n], c1 = xb[N + n], c2 = xb[2 * (size_t)N + n];
  float wf0 = 0, wf1 = 0, wf2 = 0, wd0 = 0, wd1 = 0, wd2 = 0, mn = 0, is = 1.f;
  if (act) {
    wf0 = Wf[c * 3]; wf1 = Wf[c * 3 + 1]; wf2 = Wf[c * 3 + 2];
    wd0 = Wd[c * 3]; wd1 = Wd[c * 3 + 1]; wd2 = Wd[c * 3 + 2];
    mn = statMean[c]; is = statIstd[c];
  }
  __syncthreads();
  float best = -3.4e38f, bh = 0.f;
  const int* idxRow = idx + ((size_t)b * N + n) * 20;
  for (int kk = 0; kk < 20; ++kk) {
    int j = idxRow[kk];
    float a0 = xb[j], a1 = xb[N + j], a2 = xb[2 * (size_t)N + j];
    float av  = (v == 0) ? a0 : ((v == 1) ? a1 : a2);
    float cv  = (v == 0) ? c0 : ((v == 1) ? c1 : c2);
    float a1v = (v == 0) ? a1 : ((v == 1) ? a2 : a0);
    float a2v = (v == 0) ? a2 : ((v == 1) ? a0 : a1);
    float c1v = (v == 0) ? c1 : ((v == 1) ? c2 : c0);
    float c2v = (v == 0) ? c2 : ((v == 1) ? c0 : c1);
    float e0 = av - cv;                 // neighbor - center
    float e1 = cv;                      // center
    float e2 = a1v * c2v - a2v * c1v;   // cross(nb, center)[v]
    float p = wf0 * e0 + wf1 * e1 + wf2 * e2;
    float d = wd0 * e0 + wd1 * e1 + wd2 * e2;
    int base = c * 3;
    float pp = p * p;
    float n2 = __shfl(pp, base) + __shfl(pp, base + 1) + __shfl(pp, base + 2);
    float nr = sqrtf(n2) + 1e-6f;
    float sc = ((nr - mn) * is) / nr;
    float pb = p * sc;
    float pd2 = pb * d, dd = d * d;
    float dot = __shfl(pd2, base) + __shfl(pd2, base + 1) + __shfl(pd2, base + 2);
    float dsq = __shfl(dd, base) + __shfl(dd, base + 1) + __shfl(dd, base + 2);
    float h = (dot >= 0.f) ? pb : pb - (dot / (dsq + 1e-6f)) * d;
    hbuf[tid] = act ? h : 0.f;
    __syncthreads();
    float d2 = 0.f;
    #pragma unroll 7
    for (int cc = 0; cc < 21; ++cc) d2 += wpool[c * 21 + cc] * hbuf[cc * 3 + v];
    float hd = h * d2;
    float dotp = __shfl(hd, base) + __shfl(hd, base + 1) + __shfl(hd, base + 2);
    if (act && dotp > best) { best = dotp; bh = h; }   // strict >: first max = argmax
    __syncthreads();
  }
  if (act) h0[(((size_t)b * 21 + c) * 3 + v) * N + n] = bh;
}

// -------------------------------------------------------- fp32 VN "GEMM"
// (16*CPT)co x 64n tile, CPT co per thread, double-buffered LDS with
// software-pipelined global prefetch (1 barrier per K-tile).
// MODE 4: d=Wf.X; key=argmax_n <X[co],d>; per-(b,co,ntile) partial keys
// MODE 5: P = Wf.X -> write Y fp32 + stats
// MODE 6: D = Wf.X; read P from Y, bn+lrelu, write in place
template<int MODE, int CPT, typename TX, typename TY>
__global__ __launch_bounds__(256) void gemm_vn(
    const float* __restrict__ Wf,
    const TX* __restrict__ X, TY* __restrict__ Y,
    float* __restrict__ statSum, float* __restrict__ statSq,
    const float* __restrict__ statMean, const float* __restrict__ statIstd,
    unsigned long long* __restrict__ poolPart,
    int Cin, int Cout, int wstride, int N) {
  __shared__ float Xs[2][16][3][64];
  __shared__ float Wfs[2][16 * CPT][17];
  const int tid = threadIdx.x;
  const int tx = tid & 15, ty = tid >> 4;
  const int b = blockIdx.z;
  const int n0 = blockIdx.x * 64;
  const int co0 = blockIdx.y * (16 * CPT);
  const TX* Xb = X + (size_t)b * Cin * 3 * N;

  // per-thread staging coords (12 X elements/thread/K-tile)
  int baseOff[12], kkA[12];
  #pragma unroll
  for (int l0 = 0; l0 < 12; ++l0) {
    int l = l0 * 256 + tid;
    int n = l & 63, v = (l >> 6) % 3, kk = l / 192;
    baseOff[l0] = (kk * 3 + v) * N + n0 + n;
    kkA[l0] = kk;
  }
  float xr[12], wr[CPT];
  auto loadT = [&](int k0) {
    #pragma unroll
    for (int l0 = 0; l0 < 12; ++l0) {
      int ci = k0 + kkA[l0];
      xr[l0] = (ci < Cin) ? ldg(Xb, (size_t)k0 * 3 * N + baseOff[l0]) : 0.f;
    }
    #pragma unroll
    for (int c = 0; c < CPT; ++c) {
      int coL = ty + 16 * c, ci = k0 + tx;
      bool ok = (co0 + coL < Cout) && (ci < Cin);
      wr[c] = ok ? Wf[(size_t)(co0 + coL) * wstride + ci] : 0.f;
    }
  };
  auto storeT = [&](int buf) {
    #pragma unroll
    for (int l0 = 0; l0 < 12; ++l0) {
      int l = l0 * 256 + tid;
      int n = l & 63, v = (l >> 6) % 3, kk = l / 192;
      Xs[buf][kk][v][n] = xr[l0];
    }
    #pragma unroll
    for (int c = 0; c < CPT; ++c)
      Wfs[buf][ty + 16 * c][tx] = wr[c];
  };

  float4 acc[CPT][3];
  #pragma unroll
  for (int c = 0; c < CPT; ++c)
    #pragma unroll
    for (int v = 0; v < 3; ++v) acc[c][v] = {0.f, 0.f, 0.f, 0.f};

  const int KT = (Cin + 15) / 16;
  loadT(0);
  storeT(0);
  __syncthreads();
  for (int kt = 0; kt < KT; ++kt) {
    int cur = kt & 1;
    if (kt + 1 < KT) loadT((kt + 1) * 16);
    #pragma unroll
    for (int kk = 0; kk < 16; ++kk) {
      float4 x0 = *(const float4*)&Xs[cur][kk][0][tx * 4];
      float4 x1 = *(const float4*)&Xs[cur][kk][1][tx * 4];
      float4 x2 = *(const float4*)&Xs[cur][kk][2][tx * 4];
      #pragma unroll
      for (int c = 0; c < CPT; ++c) {
        float w = Wfs[cur][ty + 16 * c][kk];
        FMA4(acc[c][0], w, x0); FMA4(acc[c][1], w, x1); FMA4(acc[c][2], w, x2);
      }
    }
    if (kt + 1 < KT) storeT(cur ^ 1);
    __syncthreads();
  }

  #pragma unroll
  for (int c = 0; c < CPT; ++c) {
    int co = co0 + ty + 16 * c;
    float p_[3][4];
    #pragma unroll
    for (int v = 0; v < 3; ++v) {
      const float* av = (const float*)&acc[c][v];
      p_[v][0] = av[0]; p_[v][1] = av[1]; p_[v][2] = av[2]; p_[v][3] = av[3];
    }
    if constexpr (MODE == 4) {
      unsigned long long key = 0;
      if (co < Cout) {
        size_t xb2 = ((size_t)co * 3) * N + n0 + tx * 4;
        #pragma unroll
        for (int j = 0; j < 4; ++j) {
          float X0 = ldg(Xb, xb2 + j);
          float X1 = ldg(Xb, xb2 + N + j);
          float X2 = ldg(Xb, xb2 + 2 * (size_t)N + j);
          float dot = X0*p_[0][j] + X1*p_[1][j] + X2*p_[2][j];
          unsigned long long k2 = packKey(dot, n0 + tx * 4 + j);
          if (k2 > key) key = k2;
        }
      }
      #pragma unroll
      for (int off = 8; off; off >>= 1) {
        unsigned long long o = __shfl_down(key, off);
        if (o > key) key = o;
      }
      if (tx == 0 && co < Cout) poolPart[((size_t)b * Cout + co) * 64 + blockIdx.x] = key;
    } else if constexpr (MODE == 5) {
      float s1 = 0.f, s2 = 0.f;
      if (co < Cout) {
        size_t yb = ((size_t)b * Cout + co) * 3 * N + n0 + tx * 4;
        #pragma unroll
        for (int j = 0; j < 4; ++j) {
          float nr = sqrtf(p_[0][j]*p_[0][j] + p_[1][j]*p_[1][j] + p_[2][j]*p_[2][j]) + 1e-6f;
          s1 += nr; s2 += nr * nr;
        }
        st4(Y, yb,                 p_[0][0], p_[0][1], p_[0][2], p_[0][3]);
        st4(Y, yb + N,             p_[1][0], p_[1][1], p_[1][2], p_[1][3]);
        st4(Y, yb + 2 * (size_t)N, p_[2][0], p_[2][1], p_[2][2], p_[2][3]);
      }
      #pragma unroll
      for (int off = 8; off; off >>= 1) { s1 += __shfl_down(s1, off); s2 += __shfl_down(s2, off); }
      if (tx == 0 && co < Cout) { atomicAdd(&statSum[co], s1); atomicAdd(&statSq[co], s2); }
    } else if constexpr (MODE == 6) {
      if (co < Cout) {
        float mn = statMean[co], is = statIstd[co];
        size_t yb = ((size_t)b * Cout + co) * 3 * N + n0 + tx * 4;
        float4 P0 = *(const float4*)&Y[yb];
        float4 P1 = *(const float4*)&Y[yb + N];
        float4 P2 = *(const float4*)&Y[yb + 2 * (size_t)N];
        float pr[3][4] = {{P0.x,P0.y,P0.z,P0.w},{P1.x,P1.y,P1.z,P1.w},{P2.x,P2.y,P2.z,P2.w}};
        float o_[3][4];
        #pragma unroll
        for (int j = 0; j < 4; ++j) {
          float q0 = pr[0][j], q1 = pr[1][j], q2 = pr[2][j];
          float e0 = p_[0][j], e1 = p_[1][j], e2 = p_[2][j];
          float nr = sqrtf(q0*q0 + q1*q1 + q2*q2) + 1e-6f;
          float sc = ((nr - mn) * is) / nr;
          q0 *= sc; q1 *= sc; q2 *= sc;
          float dot = q0*e0 + q1*e1 + q2*e2;
          if (dot < 0.f) {
            float dsq = e0*e0 + e1*e1 + e2*e2;
            float t = dot / (dsq + 1e-6f);
            q0 -= t*e0; q1 -= t*e1; q2 -= t*e2;
          }
          o_[0][j] = q0; o_[1][j] = q1; o_[2][j] = q2;
        }
        st4(Y, yb,                 o_[0][0], o_[0][1], o_[0][2], o_[0][3]);
        st4(Y, yb + N,             o_[1][0], o_[1][1], o_[1][2], o_[1][3]);
        st4(Y, yb + 2 * (size_t)N, o_[2][0], o_[2][1], o_[2][2], o_[2][3]);
      }
    }
  }
}

// ------------------------------------- transposed-layout MFMA bf16 VN GEMM
// Tensors: Xt/P are [b][3][N][Cpad] bf16, channels zero-padded.
// MODE 0: Z = W.X -> fp32 standard layout (z0)
// MODE 1: P = W.X (+biasP) -> write P bf16 (incl. zero pad) + per-co stats
// MODE 2: D = W.X (+biasD); read P, bn+lrelu, write in place
template<int MODE, int NS>
__global__ __launch_bounds__(256) void mfma2(
    const u16* __restrict__ W, const u16* __restrict__ Xt,
    u16* __restrict__ P, float* __restrict__ Zout,
    const float* __restrict__ biasP, const float* __restrict__ biasD,
    float* __restrict__ statSum, float* __restrict__ statSq,
    const float* __restrict__ statMean, const float* __restrict__ statIstd,
    int Cout, int Cpad, int Kpad, int N) {
  const int tid = threadIdx.x, lane = tid & 63, w = tid >> 6;
  const int quad = lane >> 4, l16 = lane & 15;
  const int b = blockIdx.z, n0 = blockIdx.x * 64, co0 = blockIdx.y * 64;
  const int n = n0 + w * 16 + l16;
  const u16* Xb = Xt + (size_t)b * 3 * N * Kpad;
  f32x4 acc[NS][3];
  #pragma unroll
  for (int s = 0; s < NS; ++s)
    #pragma unroll
    for (int v = 0; v < 3; ++v) acc[s][v] = {0.f, 0.f, 0.f, 0.f};

  for (int k0 = 0; k0 < Kpad; k0 += 32) {
    bh8 bx[3];
    #pragma unroll
    for (int v = 0; v < 3; ++v)
      bx[v] = *(const bh8*)(Xb + ((size_t)v * N + n) * Kpad + k0 + quad * 8);
    #pragma unroll
    for (int s = 0; s < NS; ++s) {
      bh8 a = *(const bh8*)(W + (size_t)(co0 + s * 16 + l16) * Kpad + k0 + quad * 8);
      #pragma unroll
      for (int v = 0; v < 3; ++v)
        acc[s][v] = __builtin_amdgcn_mfma_f32_16x16x32_bf16(a, bx[v], acc[s][v], 0, 0, 0);
    }
  }

  u16* Pb = P + (size_t)b * 3 * N * Cpad;
  #pragma unroll
  for (int s = 0; s < NS; ++s) {
    int cb = co0 + s * 16 + quad * 4;
    if constexpr (MODE == 0) {
      #pragma unroll
      for (int r = 0; r < 4; ++r) {
        int co = cb + r;
        if (co < Cout) {
          size_t zb = (((size_t)b * Cout + co) * 3) * N + n;
          Zout[zb] = acc[s][0][r];
          Zout[zb + N] = acc[s][1][r];
          Zout[zb + 2 * (size_t)N] = acc[s][2][r];
        }
      }
    } else if constexpr (MODE == 1) {
      if (cb < Cpad) {
        float q[3][4];
        #pragma unroll
        for (int r = 0; r < 4; ++r) {
          int co = cb + r;
          float b0 = 0, b1 = 0, b2 = 0;
          if (biasP != nullptr && co < Cout) {
            size_t bi = ((size_t)b * Cout + co) * 3;
            b0 = biasP[bi]; b1 = biasP[bi + 1]; b2 = biasP[bi + 2];
          }
          float q0 = acc[s][0][r] + b0, q1 = acc[s][1][r] + b1, q2 = acc[s][2][r] + b2;
          if (co >= Cout) { q0 = 0.f; q1 = 0.f; q2 = 0.f; }
          q[0][r] = q0; q[1][r] = q1; q[2][r] = q2;
          float nr = sqrtf(q0*q0 + q1*q1 + q2*q2) + 1e-6f;
          float s1 = nr, s2 = nr * nr;
          #pragma unroll
          for (int off = 1; off < 16; off <<= 1) { s1 += __shfl_xor(s1, off); s2 += __shfl_xor(s2, off); }
          if (l16 == 0 && co < Cout) { atomicAdd(&statSum[co], s1); atomicAdd(&statSq[co], s2); }
        }
        #pragma unroll
        for (int v = 0; v < 3; ++v) {
          u16 ob[4];
          ob[0] = f2b(q[v][0]); ob[1] = f2b(q[v][1]); ob[2] = f2b(q[v][2]); ob[3] = f2b(q[v][3]);
          *(ushort4*)(Pb + ((size_t)v * N + n) * Cpad + cb) = *(ushort4*)ob;
        }
      }
    } else {  // MODE 2
      if (cb < Cpad) {
        u16 pa[3][4];
        #pragma unroll
        for (int v = 0; v < 3; ++v)
          *(ushort4*)pa[v] = *(const ushort4*)(Pb + ((size_t)v * N + n) * Cpad + cb);
        float o[3][4];
        #pragma unroll
        for (int r = 0; r < 4; ++r) {
          int co = cb + r;
          float r0 = 0.f, r1 = 0.f, r2 = 0.f;
          if (co < Cout) {
            float p0 = b2f(pa[0][r]), p1 = b2f(pa[1][r]), p2 = b2f(pa[2][r]);
            float d0 = acc[s][0][r], d1 = acc[s][1][r], d2 = acc[s][2][r];
            if (biasD != nullptr) {
              size_t bi = ((size_t)b * Cout + co) * 3;
              d0 += biasD[bi]; d1 += biasD[bi + 1]; d2 += biasD[bi + 2];
            }
            float mn = statMean[co], is = statIstd[co];
            float nr = sqrtf(p0*p0 + p1*p1 + p2*p2) + 1e-6f;
            float sc = ((nr - mn) * is) / nr;
            float q0 = p0 * sc, q1 = p1 * sc, q2 = p2 * sc;
            float dot = q0*d0 + q1*d1 + q2*d2;
            if (dot < 0.f) {
              float dsq = d0*d0 + d1*d1 + d2*d2;
              float t = dot / (dsq + 1e-6f);
              q0 -= t*d0; q1 -= t*d1; q2 -= t*d2;
            }
            r0 = q0; r1 = q1; r2 = q2;
          }
          o[0][r] = r0; o[1][r] = r1; o[2][r] = r2;
        }
        #pragma unroll
        for (int v = 0; v < 3; ++v) {
          u16 ob[4];
          ob[0] = f2b(o[v][0]); ob[1] = f2b(o[v][1]); ob[2] = f2b(o[v][2]); ob[3] = f2b(o[v][3]);
          *(ushort4*)(Pb + ((size_t)v * N + n) * Cpad + cb) = *(ushort4*)ob;
        }
      }
    }
  }
}

// weight fp32 -> padded bf16 [CoutPad x Kpad]
__global__ void w_to_bf16(const float* __restrict__ W, u16* __restrict__ Wp,
                          int Cout, int Cin, int wstride, int CoutPad, int Kpad) {
  int t = blockIdx.x * 256 + threadIdx.x;
  if (t >= CoutPad * Kpad) return;
  int co = t / Kpad, ci = t - co * Kpad;
  Wp[t] = (co < Cout && ci < Cin) ? f2b(W[(size_t)co * wstride + ci]) : (u16)0;
}

// ----------------------------------------------------------- small kernels
__global__ void zero_kernel(float* p, int n) {
  int t = blockIdx.x * 256 + threadIdx.x;
  if (t < n) p[t] = 0.f;
}

// computes mean/istd AND re-zeroes sum/sq (512 wide) for the next layer
__global__ void finalize_kernel(float* __restrict__ sum, float* __restrict__ sq,
                                float* __restrict__ mean, float* __restrict__ istd,
                                int C, float invCount) {
  int c = blockIdx.x * 256 + threadIdx.x;
  if (c < C) {
    float m = sum[c] * invCount;
    float v = sq[c] * invCount - m * m;
    if (v < 0.f) v = 0.f;
    mean[c] = m;
    istd[c] = 1.f / sqrtf(v + 1e-5f);
  }
  if (c < 512) { sum[c] = 0.f; sq[c] = 0.f; }
}

__global__ __launch_bounds__(64) void pool_reduce(const unsigned long long* __restrict__ part,
                                                  const float* __restrict__ s3,
                                                  float* __restrict__ pooled, int N) {
  int co = blockIdx.x, b = blockIdx.y, lane = threadIdx.x;
  unsigned long long key = part[((size_t)b * 341 + co) * 64 + lane];
  #pragma unroll
  for (int off = 32; off; off >>= 1) {
    unsigned long long o = __shfl_down(key, off);
    if (o > key) key = o;
  }
  if (lane == 0) {
    int n = (int)(0xFFFFFFFFu - (unsigned)(key & 0xFFFFFFFFull));
    size_t base = ((size_t)b * 341 + co) * 3;
    pooled[base + 0] = s3[(base + 0) * N + n];
    pooled[base + 1] = s3[(base + 1) * N + n];
    pooled[base + 2] = s3[(base + 2) * N + n];
  }
}

// vn_lrelu on (B,Cin,3) tiny tensors (bn stats over batch axis only)
__global__ __launch_bounds__(64) void stf_lrelu(const float* __restrict__ Wf,
                                                const float* __restrict__ Wd,
                                                const float* __restrict__ X,
                                                float* __restrict__ Y, int Cin, int Cout) {
  __shared__ float P[24], D[24], NORM[8], SC[8], DOT[8], DSQ[8], MS[2];
  int co = blockIdx.x, tid = threadIdx.x;
  if (tid < 48) {
    int l = tid < 24 ? tid : tid - 24;
    int b = l / 3, v = l - b * 3;
    const float* W = (tid < 24 ? Wf : Wd) + (size_t)co * Cin;
    const float* xb = X + ((size_t)b * Cin) * 3 + v;
    float acc = 0.f;
    for (int ci = 0; ci < Cin; ++ci) acc += W[ci] * xb[ci * 3];
    if (tid < 24) P[l] = acc; else D[l] = acc;
  }
  __syncthreads();
  if (tid < 8) NORM[tid] = sqrtf(P[tid*3]*P[tid*3] + P[tid*3+1]*P[tid*3+1] + P[tid*3+2]*P[tid*3+2]) + 1e-6f;
  __syncthreads();
  if (tid == 0) {
    float m = 0.f;
    for (int b2 = 0; b2 < 8; ++b2) m += NORM[b2];
    m *= 0.125f;
    float var = 0.f;
    for (int b2 = 0; b2 < 8; ++b2) { float dd = NORM[b2] - m; var += dd * dd; }
    var *= 0.125f;
    MS[0] = m; MS[1] = 1.f / sqrtf(var + 1e-5f);
  }
  __syncthreads();
  if (tid < 8) {
    float sc = ((NORM[tid] - MS[0]) * MS[1]) / NORM[tid];
    float dot = 0.f, dsq = 0.f;
    for (int v = 0; v < 3; ++v) {
      float pb = P[tid*3+v] * sc; float dv = D[tid*3+v];
      dot += pb * dv; dsq += dv * dv;
    }
    SC[tid] = sc; DOT[tid] = dot; DSQ[tid] = dsq;
  }
  __syncthreads();
  if (tid < 24) {
    int b = tid / 3;
    float pb = P[tid] * SC[b];
    float o = (DOT[b] >= 0.f) ? pb : pb - (DOT[b] / (DSQ[b] + 1e-6f)) * D[tid];
    Y[((size_t)b * Cout + co) * 3 + (tid - b * 3)] = o;
  }
}

__global__ void vnlin_small(const float* __restrict__ W, const float* __restrict__ X,
                            float* __restrict__ Y, int Cin, int Cout) {
  int t = blockIdx.x * 256 + threadIdx.x;   // over 8*Cout*3
  if (t >= 8 * Cout * 3) return;
  int v = t % 3, r = t / 3;
  int co = r % Cout, b = r / Cout;
  float acc = 0.f;
  for (int ci = 0; ci < Cin; ++ci) acc += W[(size_t)co * Cin + ci] * X[((size_t)b * Cin + ci) * 3 + v];
  Y[t] = acc;
}

// concat [h1 ; broadcast sfin ; zero-pad] -> transposed bf16 [b][v][n][64]
__global__ void concat_t(const float* __restrict__ h1, const float* __restrict__ sfin,
                         u16* __restrict__ s2bb, int N) {
  size_t t = (size_t)blockIdx.x * 256 + threadIdx.x;  // over 8*3*4096*64
  int c = (int)(t & 63); size_t r = t >> 6;
  int n = (int)(r & 4095); r >>= 12;
  int v = (int)(r % 3); int b = (int)(r / 3);
  float val = 0.f;
  if (c < 21) val = h1[(((size_t)b * 21 + c) * 3 + v) * N + n];
  else if (c < 42) val = sfin[((size_t)b * 21 + (c - 21)) * 3 + v];
  s2bb[t] = f2b(val);
}

// in-place bn on transposed H + accumulate per-(c,v) sums for h_mean
__global__ __launch_bounds__(384) void bn_apply_mean(u16* __restrict__ H,
    const float* __restrict__ sMean, const float* __restrict__ sIstd,
    float* __restrict__ HmAcc, int N) {
  int c = threadIdx.x;
  if (c >= 341) return;
  int b = blockIdx.y, nt = blockIdx.x;
  float mn = sMean[c], is = sIstd[c];
  float a0 = 0.f, a1 = 0.f, a2 = 0.f;
  size_t base = (size_t)b * 3 * N * 352;
  for (int n = nt * 256; n < nt * 256 + 256; ++n) {
    size_t i0 = base + ((size_t)0 * N + n) * 352 + c;
    size_t i1 = base + ((size_t)1 * N + n) * 352 + c;
    size_t i2 = base + ((size_t)2 * N + n) * 352 + c;
    float p0 = b2f(H[i0]), p1 = b2f(H[i1]), p2 = b2f(H[i2]);
    float nr = sqrtf(p0*p0 + p1*p1 + p2*p2) + 1e-6f;
    float sc = ((nr - mn) * is) / nr;
    p0 *= sc; p1 *= sc; p2 *= sc;
    H[i0] = f2b(p0); H[i1] = f2b(p1); H[i2] = f2b(p2);
    a0 += p0; a1 += p1; a2 += p2;
  }
  size_t hb = ((size_t)b * 341 + c) * 3;
  atomicAdd(&HmAcc[hb], a0); atomicAdd(&HmAcc[hb + 1], a1); atomicAdd(&HmAcc[hb + 2], a2);
}

__global__ void hm_finalize(float* Hm, float invN) {
  int t = blockIdx.x * 256 + threadIdx.x;
  if (t < 8 * 341 * 3) Hm[t] *= invN;
}

// bias terms for std1: W[:,341:682] . h_mean   (n-invariant half of concat)
__global__ void bias_kernel(const float* __restrict__ Wf, const float* __restrict__ Wd,
                            const float* __restrict__ Hm,
                            float* __restrict__ biasP, float* __restrict__ biasD) {
  int t = blockIdx.x * 256 + threadIdx.x;   // over 8*341*3
  if (t >= 8 * 341 * 3) return;
  int v = t % 3, r = t / 3;
  int co = r % 341, b = r / 341;
  const float* hm = Hm + (size_t)b * 1023 + v;
  float ap = 0.f, ad = 0.f;
  for (int j = 0; j < 341; ++j) {
    float h = hm[j * 3];
    ap += Wf[(size_t)co * 682 + 341 + j] * h;
    ad += Wd[(size_t)co * 682 + 341 + j] * h;
  }
  biasP[t] = ap; biasD[t] = ad;
}

// h_std einsum + max over N on transposed H; rows >=341 use h_mean
__global__ __launch_bounds__(256) void final_max_t(const u16* __restrict__ H,
    const float* __restrict__ Hm, const float* __restrict__ z0,
    float* __restrict__ out, int N) {
  __shared__ float red[3][4][64];
  int b = blockIdx.y;
  int il = threadIdx.x & 63, nsub = threadIdx.x >> 6;
  int i = blockIdx.x * 64 + il;
  bool valid = i < 682, lo = i < 341;
  float c0 = 0, c1 = 0, c2 = 0;
  if (valid && !lo) {
    size_t hb = ((size_t)b * 341 + (i - 341)) * 3;
    c0 = Hm[hb]; c1 = Hm[hb + 1]; c2 = Hm[hb + 2];
  }
  const float* zb = z0 + (size_t)b * 9 * N;
  const u16* Hb = H + (size_t)b * 3 * N * 352;
  float m0 = -3.4e38f, m1 = -3.4e38f, m2 = -3.4e38f;
  int ii = lo ? i : 0;
  for (int n = nsub; n < N; n += 4) {
    float a0, a1, a2;
    if (lo) {
      a0 = b2f(Hb[((size_t)0 * N + n) * 352 + ii]);
      a1 = b2f(Hb[((size_t)1 * N + n) * 352 + ii]);
      a2 = b2f(Hb[((size_t)2 * N + n) * 352 + ii]);
    } else { a0 = c0; a1 = c1; a2 = c2; }
    float s0 = a0 * zb[n]                + a1 * zb[3 * (size_t)N + n] + a2 * zb[6 * (size_t)N + n];
    float s1 = a0 * zb[N + n]            + a1 * zb[4 * (size_t)N + n] + a2 * zb[7 * (size_t)N + n];
    float s2 = a0 * zb[2 * (size_t)N + n]+ a1 * zb[5 * (size_t)N + n] + a2 * zb[8 * (size_t)N + n];
    m0 = fmaxf(m0, s0); m1 = fmaxf(m1, s1); m2 = fmaxf(m2, s2);
  }
  red[0][nsub][il] = m0; red[1][nsub][il] = m1; red[2][nsub][il] = m2;
  __syncthreads();
  if (nsub == 0 && valid) {
    for (int q = 1; q < 4; ++q) {
      m0 = fmaxf(m0, red[0][q][il]); m1 = fmaxf(m1, red[1][q][il]); m2 = fmaxf(m2, red[2][q][il]);
    }
    size_t ob = (size_t)b * 2046 + (size_t)i * 3;
    out[ob] = m0; out[ob + 1] = m1; out[ob + 2] = m2;
  }
}

// ------------------------------------------------------------------- host
extern "C" void kernel_launch(void* const* d_in, const int* in_sizes, int n_in,
                              void* d_out, int out_size, void* d_ws, size_t ws_size,
                              hipStream_t stream) {
  (void)in_sizes; (void)n_in; (void)out_size; (void)ws_size;
  const float* x       = (const float*)d_in[0];
  const float* pos_Wf  = (const float*)d_in[1];
  const float* pos_Wd  = (const float*)d_in[2];
  const float* pool_Wd = (const float*)d_in[3];
  const float* c1_Wf   = (const float*)d_in[4];
  const float* c1_Wd   = (const float*)d_in[5];
  const float* st1_Wf  = (const float*)d_in[6];
  const float* st1_Wd  = (const float*)d_in[7];
  const float* st2_Wf  = (const float*)d_in[8];
  const float* st2_Wd  = (const float*)d_in[9];
  const float* st3_Wf  = (const float*)d_in[10];
  const float* st3_Wd  = (const float*)d_in[11];
  const float* stp_Wd  = (const float*)d_in[12];
  const float* stf1_Wf = (const float*)d_in[13];
  const float* stf1_Wd = (const float*)d_in[14];
  const float* stf2_Wf = (const float*)d_in[15];
  const float* stf2_Wd = (const float*)d_in[16];
  const float* stf3_W  = (const float*)d_in[17];
  const float* c2_Wf   = (const float*)d_in[18];
  const float* c2_Wd   = (const float*)d_in[19];
  const float* c3_W    = (const float*)d_in[20];
  const float* std1_Wf = (const float*)d_in[21];
  const float* std1_Wd = (const float*)d_in[22];
  const float* std2_Wf = (const float*)d_in[23];
  const float* std2_Wd = (const float*)d_in[24];
  const float* stdlin  = (const float*)d_in[25];

  float* outv  = (float*)d_out;           // fp32: [8*2046] ++ z0 [8*3*3*4096]
  float* z0out = outv + 8 * 2046;

  const int N = 4096;
  char* ws = (char*)d_ws;
  size_t off = 0;
  auto alloc = [&](size_t bytes) -> char* {
    char* p = ws + off;
    off += (bytes + 255) & ~(size_t)255;
    return p;
  };
  float* stats = (float*)alloc(2048 * sizeof(float));
  float* sSum = stats, *sSq = stats + 512, *sMean = stats + 1024, *sIstd = stats + 1536;
  int* idx = (int*)alloc((size_t)8 * N * 20 * 4);
  unsigned long long* poolPart = (unsigned long long*)alloc((size_t)8 * 341 * 64 * 8);
  float* pooled = (float*)alloc(8 * 341 * 3 * 4);
  float* stf1o  = (float*)alloc(8 * 170 * 3 * 4);
  float* stf2o  = (float*)alloc(8 * 85 * 3 * 4);
  float* sfin   = (float*)alloc(8 * 21 * 3 * 4);
  float* Hm     = (float*)alloc(8 * 1023 * 4);
  float* biasP  = (float*)alloc(8 * 341 * 3 * 4);
  float* biasD  = (float*)alloc(8 * 341 * 3 * 4);
  const size_t E21 = (size_t)8 * 21 * 3 * N, E42 = (size_t)8 * 42 * 3 * N;
  const size_t E341 = (size_t)8 * 341 * 3 * N;
  const size_t T352 = (size_t)8 * 3 * N * 352 * 2;
  const size_t T192 = (size_t)8 * 3 * N * 192 * 2;
  const size_t T64  = (size_t)8 * 3 * N * 64 * 2;
  char* regionA = alloc(T352);
  char* regionB = alloc(E341 * 4);
  float* h0  = (float*)regionA;
  float* h1  = h0 + E21;
  float* s1b = h0 + 2 * E21;
  float* s2b = h0 + 3 * E21;                  // st2 out (fp32), st3 input
  float* st3o = (float*)regionB;              // st3 P then in-place out (fp32, argmax-exact)
  u16* Hbuf  = (u16*)regionB;                 // c3 out ^T, live until final_max
  u16* Pstd2 = (u16*)(regionB + T352);        // std2 P / out ^T
  u16* s2bb  = (u16*)(regionB + T352 + T192); // concat out ^T (Cpad 64)
  u16* h2b   = (u16*)(regionB + T352 + T192 + T64); // c2 P / out ^T
  u16* Pstd1 = (u16*)regionA;                 // std1 P / out ^T (early stack dead)
  // padded bf16 weights in poolPart (dead after pool_reduce); sizes in u16
  u16* W1fp = (u16*)poolPart;                 // 384x352
  u16* W1dp = W1fp + 384 * 352;
  u16* W2fp = W1dp + 384 * 352;               // 192x352
  u16* W2dp = W2fp + 192 * 352;
  u16* Wc3p = W2dp + 192 * 352;               // 384x64
  u16* Wc2f = Wc3p + 384 * 64;                // 64x64
  u16* Wc2d = Wc2f + 64 * 64;
  u16* Wzp  = Wc2d + 64 * 64;                 // 16x192

  dim3 blk256(256), blk64(64);
  // fp32 lrelu layer: MODE5 (P+stats) -> finalize -> MODE6 (D + apply in place)
  auto run_lrelu32 = [&](const float* Wf, const float* Wd, const float* X, float* Y,
                         int Cin, int Cout, int wstride, float invCnt) {
    dim3 grid(64, (Cout + 31) / 32, 8);
    gemm_vn<5, 2><<<grid, blk256, 0, stream>>>(Wf, X, Y, sSum, sSq,
                                               nullptr, nullptr, nullptr, Cin, Cout, wstride, N);
    finalize_kernel<<<dim3(2), blk256, 0, stream>>>(sSum, sSq, sMean, sIstd, Cout, invCnt);
    gemm_vn<6, 2><<<grid, blk256, 0, stream>>>(Wd, X, Y, nullptr, nullptr,
                                               sMean, sIstd, nullptr, Cin, Cout, wstride, N);
  };
  const float invBN = 1.f / (8.f * N);
  // bf16 mfma lrelu layer (transposed tensors)
  auto run_mfma = [&](const u16* Wf, const u16* Wd, const u16* X, u16* P,
                      const float* bP, const float* bD,
                      int Cout, int Cpad, int Kpad, int coTiles) {
    dim3 grid(64, coTiles, 8);
    mfma2<1, 4><<<grid, blk256, 0, stream>>>(Wf, X, P, nullptr, bP, nullptr,
                                             sSum, sSq, nullptr, nullptr, Cout, Cpad, Kpad, N);
    finalize_kernel<<<dim3(2), blk256, 0, stream>>>(sSum, sSq, sMean, sIstd, Cout, invBN);
    mfma2<2, 4><<<grid, blk256, 0, stream>>>(Wd, X, P, nullptr, nullptr, bD,
                                             nullptr, nullptr, sMean, sIstd, Cout, Cpad, Kpad, N);
  };

  // 0. zero stats once; thereafter finalize_kernel self-zeroes for next layer
  zero_kernel<<<dim3(4), blk256, 0, stream>>>(stats, 1024);
  // 1. KNN (one wave per point)
  knn_kernel<<<dim3(N / 4, 8), blk256, 0, stream>>>(x, idx, N);
  // 2. pos layer
  pos_stats<<<dim3(N * 20 / 256, 8), blk256, 0, stream>>>(x, idx, pos_Wf, sSum, sSq, N);
  finalize_kernel<<<dim3(2), blk256, 0, stream>>>(sSum, sSq, sMean, sIstd, 21, 1.f / (8.f * N * 20.f));
  pos_apply<<<dim3(N, 8), blk64, 0, stream>>>(x, idx, pos_Wf, pos_Wd, pool_Wd, sMean, sIstd, h0, N);

  // 3. early fp32 chain (argmax-exact path)
  run_lrelu32(c1_Wf, c1_Wd, h0, h1, 21, 21, 21, invBN);
  run_lrelu32(st1_Wf, st1_Wd, h1, s1b, 21, 21, 21, invBN);
  run_lrelu32(st2_Wf, st2_Wd, s1b, s2b, 21, 42, 21, invBN);
  run_lrelu32(st3_Wf, st3_Wd, s2b, st3o, 42, 341, 42, invBN);

  // 4. st_pool over N (fp32-exact argmax), 64-co tiles
  gemm_vn<4, 4><<<dim3(64, 6, 8), blk256, 0, stream>>>(stp_Wd, st3o, (float*)nullptr,
                                                       nullptr, nullptr, nullptr, nullptr,
                                                       poolPart, 341, 341, 341, N);
  pool_reduce<<<dim3(341, 8), blk64, 0, stream>>>(poolPart, st3o, pooled, N);

  // 5. weights -> padded bf16 (poolPart now dead)
  w_to_bf16<<<dim3((384 * 352 + 255) / 256), blk256, 0, stream>>>(std1_Wf, W1fp, 341, 341, 682, 384, 352);
  w_to_bf16<<<dim3((384 * 352 + 255) / 256), blk256, 0, stream>>>(std1_Wd, W1dp, 341, 341, 682, 384, 352);
  w_to_bf16<<<dim3((192 * 352 + 255) / 256), blk256, 0, stream>>>(std2_Wf, W2fp, 170, 341, 341, 192, 352);
  w_to_bf16<<<dim3((192 * 352 + 255) / 256), blk256, 0, stream>>>(std2_Wd, W2dp, 170, 341, 341, 192, 352);
  w_to_bf16<<<dim3((384 * 64 + 255) / 256), blk256, 0, stream>>>(c3_W, Wc3p, 341, 42, 42, 384, 64);
  w_to_bf16<<<dim3((64 * 64 + 255) / 256), blk256, 0, stream>>>(c2_Wf, Wc2f, 42, 42, 42, 64, 64);
  w_to_bf16<<<dim3((64 * 64 + 255) / 256), blk256, 0, stream>>>(c2_Wd, Wc2d, 42, 42, 42, 64, 64);
  w_to_bf16<<<dim3((16 * 192 + 255) / 256), blk256, 0, stream>>>(stdlin, Wzp, 3, 170, 170, 16, 192);

  // 6. stf chain (tiny)
  stf_lrelu<<<dim3(170), blk64, 0, stream>>>(stf1_Wf, stf1_Wd, pooled, stf1o, 341, 170);
  stf_lrelu<<<dim3(85),  blk64, 0, stream>>>(stf2_Wf, stf2_Wd, stf1o, stf2o, 170, 85);
  vnlin_small<<<dim3(2), blk256, 0, stream>>>(stf3_W, stf2o, sfin, 85, 21);

  // 7. concat -> transposed bf16; c2 (mfma)
  concat_t<<<dim3((8 * 3 * 4096 * 64) / 256), blk256, 0, stream>>>(h1, sfin, s2bb, N);
  run_mfma(Wc2f, Wc2d, s2bb, h2b, nullptr, nullptr, 42, 64, 64, 1);

  // 8. c3 + bn (mfma P+stats, then fused bn-apply + h_mean)
  {
    dim3 grid(64, 6, 8);
    mfma2<1, 4><<<grid, blk256, 0, stream>>>(Wc3p, h2b, Hbuf, nullptr, nullptr, nullptr,
                                             sSum, sSq, nullptr, nullptr, 341, 352, 64, N);
  }
  finalize_kernel<<<dim3(2), blk256, 0, stream>>>(sSum, sSq, sMean, sIstd, 341, invBN);
  zero_kernel<<<dim3(32), blk256, 0, stream>>>(Hm, 8 * 1023);
  bn_apply_mean<<<dim3(16, 8), dim3(384), 0, stream>>>(Hbuf, sMean, sIstd, Hm, N);
  hm_finalize<<<dim3(32), blk256, 0, stream>>>(Hm, 1.f / (float)N);
  bias_kernel<<<dim3(32), blk256, 0, stream>>>(std1_Wf, std1_Wd, Hm, biasP, biasD);

  // 9. VNStdFeature (mfma)
  run_mfma(W1fp, W1dp, Hbuf, Pstd1, biasP, biasD, 341, 352, 352, 6);
  run_mfma(W2fp, W2dp, Pstd1, Pstd2, nullptr, nullptr, 170, 192, 352, 3);

  // 10. z0 (mfma MODE0, fp32 out) + fused einsum/max
  mfma2<0, 1><<<dim3(64, 1, 8), blk256, 0, stream>>>(Wzp, Pstd2, nullptr, z0out,
                                                     nullptr, nullptr, nullptr, nullptr,
                                                     nullptr, nullptr, 3, 16, 192, N);
  final_max_t<<<dim3(11, 8), blk256, 0, stream>>>(Hbuf, Hm, z0out, outv, N);
}

// Round 10
// 3626.805 us; speedup vs baseline: 1.0751x; 1.0751x over previous
//
#include <hip/hip_runtime.h>
#include <cstdint>
#include <cstddef>

// VN-PointNet encoder. Inputs fp32, outputs fp32 (out 8x2046 ++ z0 8x3x3x4096).
// Early chain (pos..st3, st_pool) fp32 (argmax-exact), single-buffered LDS
// GEMM (R8 structure; R9's dbuf killed occupancy 34->12% and regressed).
// st_pool uses CPT=4 (48 FMA : 3 ds_read_b128). Post-pool chain
// (c2,c3,std1,std2,z0) on bf16 MFMA with k-major transposed tensors
// [b][v][n][Cpad]. KNN: one wave/point, register top-8.
// Standard (B,C,3,N) layout: flat ((b*C+c)*3+v)*N + n.

typedef unsigned short u16;
using bh8  = __attribute__((ext_vector_type(8))) short;
using f32x4 = __attribute__((ext_vector_type(4))) float;

__device__ __forceinline__ float b2f(u16 v) {
  return __uint_as_float(((unsigned)v) << 16);
}
__device__ __forceinline__ u16 f2b(float f) {
  unsigned u = __float_as_uint(f);
  u += 0x7FFFu + ((u >> 16) & 1u);   // round-to-nearest-even
  return (u16)(u >> 16);
}

__device__ __forceinline__ float ldg(const float* p, size_t i) { return p[i]; }
__device__ __forceinline__ float ldg(const u16* p, size_t i) { return b2f(p[i]); }
__device__ __forceinline__ void st4(float* p, size_t i, float a, float b, float c, float d) {
  float4 v; v.x = a; v.y = b; v.z = c; v.w = d; *(float4*)(p + i) = v;
}

#define FMA4(A, S, V) { A.x += (S)*(V).x; A.y += (S)*(V).y; A.z += (S)*(V).z; A.w += (S)*(V).w; }

__device__ __forceinline__ unsigned long long packKey(float v, int n) {
  unsigned u = __float_as_uint(v);
  u = (u & 0x80000000u) ? ~u : (u | 0x80000000u);   // total-order float
  return ((unsigned long long)u << 32) | (unsigned long long)(0xFFFFFFFFu - (unsigned)n);
}

// ------------------------------------------- KNN top-20: one wave per point
#define CSWAP(T) { if (c > T) { unsigned long long tmp = T; T = c; c = tmp; } }
__global__ __launch_bounds__(256) void knn_kernel(const float* __restrict__ x,
                                                  int* __restrict__ idxOut, int N) {
  int b = blockIdx.y;
  int wv = threadIdx.x >> 6, lane = threadIdx.x & 63;
  int i = blockIdx.x * 4 + wv;
  const float* xb = x + (size_t)b * 3 * N;
  float xi0 = xb[i], xi1 = xb[N + i], xi2 = xb[2 * (size_t)N + i];
  float xxi = xi0 * xi0 + xi1 * xi1 + xi2 * xi2;
  unsigned long long t0 = 0, t1 = 0, t2 = 0, t3 = 0, t4 = 0, t5 = 0, t6 = 0, t7 = 0;
  #pragma unroll 8
  for (int s = 0; s < 64; ++s) {
    int j = s * 64 + lane;
    float a0 = xb[j], a1 = xb[N + j], a2 = xb[2 * (size_t)N + j];
    float inner = xi0 * a0 + xi1 * a1 + xi2 * a2;
    float xxj = a0 * a0 + a1 * a1 + a2 * a2;
    float pd = 2.f * inner - xxi - xxj;          // = -||xi-xj||^2
    unsigned long long c = packKey(pd, j);
    if (c > t7) { CSWAP(t0) CSWAP(t1) CSWAP(t2) CSWAP(t3) CSWAP(t4) CSWAP(t5) CSWAP(t6) CSWAP(t7) }
  }
  int* row = idxOut + ((size_t)b * N + i) * 20;
  for (int kk = 0; kk < 20; ++kk) {
    unsigned long long k = t0;
    #pragma unroll
    for (int off = 1; off < 64; off <<= 1) {
      unsigned long long o = __shfl_xor(k, off);
      if (o > k) k = o;
    }
    if (lane == 0) row[kk] = (int)(0xFFFFFFFFu - (unsigned)(k & 0xFFFFFFFFull));
    if (k == t0) { t0 = t1; t1 = t2; t2 = t3; t3 = t4; t4 = t5; t5 = t6; t6 = t7; t7 = 0; }
  }
}
#undef CSWAP

// ------------------------------------------------- pos layer: bn statistics
__global__ __launch_bounds__(256) void pos_stats(const float* __restrict__ x,
                                                 const int* __restrict__ idx,
                                                 const float* __restrict__ Wf,
                                                 float* __restrict__ statSum,
                                                 float* __restrict__ statSq, int N) {
  __shared__ float wf[64];
  __shared__ float part[4][42];
  int tid = threadIdx.x;
  if (tid < 63) wf[tid] = Wf[tid];
  __syncthreads();
  int b = blockIdx.y;
  int lin = blockIdx.x * 256 + tid;           // over N*20 exactly
  int n = lin / 20, kk = lin - n * 20;
  const float* xb = x + (size_t)b * 3 * N;
  int j = idx[((size_t)b * N + n) * 20 + kk];
  float c0 = xb[n], c1 = xb[N + n], c2 = xb[2 * (size_t)N + n];
  float a0 = xb[j], a1 = xb[N + j], a2 = xb[2 * (size_t)N + j];
  float e00 = a0 - c0, e01 = a1 - c1, e02 = a2 - c2;
  float e20 = a1 * c2 - a2 * c1, e21 = a2 * c0 - a0 * c2, e22 = a0 * c1 - a1 * c0;
  int lane = tid & 63, wave = tid >> 6;
  #pragma unroll
  for (int c = 0; c < 21; ++c) {
    float w0 = wf[c * 3], w1 = wf[c * 3 + 1], w2 = wf[c * 3 + 2];
    float p0 = w0 * e00 + w1 * c0 + w2 * e20;
    float p1 = w0 * e01 + w1 * c1 + w2 * e21;
    float p2 = w0 * e02 + w1 * c2 + w2 * e22;
    float nr = sqrtf(p0 * p0 + p1 * p1 + p2 * p2) + 1e-6f;
    float u1 = nr, u2 = nr * nr;
    #pragma unroll
    for (int off = 32; off; off >>= 1) { u1 += __shfl_down(u1, off); u2 += __shfl_down(u2, off); }
    if (lane == 0) { part[wave][c] = u1; part[wave][21 + c] = u2; }
  }
  __syncthreads();
  if (tid < 42) {
    float t = part[0][tid] + part[1][tid] + part[2][tid] + part[3][tid];
    if (tid < 21) atomicAdd(&statSum[tid], t);
    else atomicAdd(&statSq[tid - 21], t);
  }
}

// ------------- pos layer: lrelu + maxpool over k fused (one wave per point)
__global__ __launch_bounds__(64) void pos_apply(const float* __restrict__ x,
                                                const int* __restrict__ idx,
                                                const float* __restrict__ Wf,
                                                const float* __restrict__ Wd,
                                                const float* __restrict__ Wpool,
                                                const float* __restrict__ statMean,
                                                const float* __restrict__ statIstd,
                                                float* __restrict__ h0, int N) {
  __shared__ float wpool[441];
  __shared__ float hbuf[64];
  int tid = threadIdx.x;
  for (int l = tid; l < 441; l += 64) wpool[l] = Wpool[l];
  int b = blockIdx.y, n = blockIdx.x;
  bool act = tid < 63;
  int c = act ? tid / 3 : 0;
  int v = act ? tid - c * 3 : 0;
  const float* xb = x + (size_t)b * 3 * N;
  float c0 = xb[n], c1 = xb[N + n], c2 = xb[2 * (size_t)N + n];
  float wf0 = 0, wf1 = 0, wf2 = 0, wd0 = 0, wd1 = 0, wd2 = 0, mn = 0, is = 1.f;
  if (act) {
    wf0 = Wf[c * 3]; wf1 = Wf[c * 3 + 1]; wf2 = Wf[c * 3 + 2];
    wd0 = Wd[c * 3]; wd1 = Wd[c * 3 + 1]; wd2 = Wd[c * 3 + 2];
    mn = statMean[c]; is = statIstd[c];
  }
  __syncthreads();
  float best = -3.4e38f, bh = 0.f;
  const int* idxRow = idx + ((size_t)b * N + n) * 20;
  for (int kk = 0; kk < 20; ++kk) {
    int j = idxRow[kk];
    float a0 = xb[j], a1 = xb[N + j], a2 = xb[2 * (size_t)N + j];
    float av  = (v == 0) ? a0 : ((v == 1) ? a1 : a2);
    float cv  = (v == 0) ? c0 : ((v == 1) ? c1 : c2);
    float a1v = (v == 0) ? a1 : ((v == 1) ? a2 : a0);
    float a2v = (v == 0) ? a2 : ((v == 1) ? a0 : a1);
    float c1v = (v == 0) ? c1 : ((v == 1) ? c2 : c0);
    float c2v = (v == 0) ? c2 : ((v == 1) ? c0 : c1);
    float e0 = av - cv;                 // neighbor - center
    float e1 = cv;                      // center
    float e2 = a1v * c2v - a2v * c1v;   // cross(nb, center)[v]
    float p = wf0 * e0 + wf1 * e1 + wf2 * e2;
    float d = wd0 * e0 + wd1 * e1 + wd2 * e2;
    int base = c * 3;
    float pp = p * p;
    float n2 = __shfl(pp, base) + __shfl(pp, base + 1) + __shfl(pp, base + 2);
    float nr = sqrtf(n2) + 1e-6f;
    float sc = ((nr - mn) * is) / nr;
    float pb = p * sc;
    float pd2 = pb * d, dd = d * d;
    float dot = __shfl(pd2, base) + __shfl(pd2, base + 1) + __shfl(pd2, base + 2);
    float dsq = __shfl(dd, base) + __shfl(dd, base + 1) + __shfl(dd, base + 2);
    float h = (dot >= 0.f) ? pb : pb - (dot / (dsq + 1e-6f)) * d;
    hbuf[tid] = act ? h : 0.f;
    __syncthreads();
    float d2 = 0.f;
    #pragma unroll 7
    for (int cc = 0; cc < 21; ++cc) d2 += wpool[c * 21 + cc] * hbuf[cc * 3 + v];
    float hd = h * d2;
    float dotp = __shfl(hd, base) + __shfl(hd, base + 1) + __shfl(hd, base + 2);
    if (act && dotp > best) { best = dotp; bh = h; }   // strict >: first max = argmax
    __syncthreads();
  }
  if (act) h0[(((size_t)b * 21 + c) * 3 + v) * N + n] = bh;
}

// -------------------------------------------------------- fp32 VN "GEMM"
// (16*CPT)co x 64n tile, CPT co per thread, single-buffered LDS (R8 struct).
// MODE 4: d=Wf.X; key=argmax_n <X[co],d>; per-(b,co,ntile) partial keys
// MODE 5: P = Wf.X -> write Y fp32 + stats
// MODE 6: D = Wf.X; read P from Y, bn+lrelu, write in place
template<int MODE, int CPT, typename TX, typename TY>
__global__ __launch_bounds__(256) void gemm_vn(
    const float* __restrict__ Wf,
    const TX* __restrict__ X, TY* __restrict__ Y,
    float* __restrict__ statSum, float* __restrict__ statSq,
    const float* __restrict__ statMean, const float* __restrict__ statIstd,
    unsigned long long* __restrict__ poolPart,
    int Cin, int Cout, int wstride, int N) {
  __shared__ float Xs[16][3][64];
  __shared__ float Wfs[16 * CPT][17];
  const int tid = threadIdx.x;
  const int tx = tid & 15, ty = tid >> 4;
  const int b = blockIdx.z;
  const int n0 = blockIdx.x * 64;
  const int co0 = blockIdx.y * (16 * CPT);
  const TX* Xb = X + (size_t)b * Cin * 3 * N;

  float4 acc[CPT][3];
  #pragma unroll
  for (int c = 0; c < CPT; ++c)
    #pragma unroll
    for (int v = 0; v < 3; ++v) acc[c][v] = {0.f, 0.f, 0.f, 0.f};

  for (int k0 = 0; k0 < Cin; k0 += 16) {
    #pragma unroll
    for (int l0 = 0; l0 < 12; ++l0) {
      int l = l0 * 256 + tid;
      int n = l & 63, v = (l >> 6) % 3, kk = l / 192;
      int ci = k0 + kk;
      Xs[kk][v][n] = (ci < Cin) ? ldg(Xb, ((size_t)ci * 3 + v) * N + n0 + n) : 0.f;
    }
    {
      int kk = tid & 15, coL = tid >> 4, ci = k0 + kk;
      #pragma unroll
      for (int c = 0; c < CPT; ++c) {
        int co = co0 + coL + 16 * c;
        bool ok = (co < Cout) && (ci < Cin);
        Wfs[coL + 16 * c][kk] = ok ? Wf[(size_t)co * wstride + ci] : 0.f;
      }
    }
    __syncthreads();
    #pragma unroll
    for (int kk = 0; kk < 16; ++kk) {
      float4 x0 = *(const float4*)&Xs[kk][0][tx * 4];
      float4 x1 = *(const float4*)&Xs[kk][1][tx * 4];
      float4 x2 = *(const float4*)&Xs[kk][2][tx * 4];
      #pragma unroll
      for (int c = 0; c < CPT; ++c) {
        float w = Wfs[ty + 16 * c][kk];
        FMA4(acc[c][0], w, x0); FMA4(acc[c][1], w, x1); FMA4(acc[c][2], w, x2);
      }
    }
    __syncthreads();
  }

  #pragma unroll
  for (int c = 0; c < CPT; ++c) {
    int co = co0 + ty + 16 * c;
    float p_[3][4];
    #pragma unroll
    for (int v = 0; v < 3; ++v) {
      const float* av = (const float*)&acc[c][v];
      p_[v][0] = av[0]; p_[v][1] = av[1]; p_[v][2] = av[2]; p_[v][3] = av[3];
    }
    if constexpr (MODE == 4) {
      unsigned long long key = 0;
      if (co < Cout) {
        size_t xb2 = ((size_t)co * 3) * N + n0 + tx * 4;
        #pragma unroll
        for (int j = 0; j < 4; ++j) {
          float X0 = ldg(Xb, xb2 + j);
          float X1 = ldg(Xb, xb2 + N + j);
          float X2 = ldg(Xb, xb2 + 2 * (size_t)N + j);
          float dot = X0*p_[0][j] + X1*p_[1][j] + X2*p_[2][j];
          unsigned long long k2 = packKey(dot, n0 + tx * 4 + j);
          if (k2 > key) key = k2;
        }
      }
      #pragma unroll
      for (int off = 8; off; off >>= 1) {
        unsigned long long o = __shfl_down(key, off);
        if (o > key) key = o;
      }
      if (tx == 0 && co < Cout) poolPart[((size_t)b * Cout + co) * 64 + blockIdx.x] = key;
    } else if constexpr (MODE == 5) {
      float s1 = 0.f, s2 = 0.f;
      if (co < Cout) {
        size_t yb = ((size_t)b * Cout + co) * 3 * N + n0 + tx * 4;
        #pragma unroll
        for (int j = 0; j < 4; ++j) {
          float nr = sqrtf(p_[0][j]*p_[0][j] + p_[1][j]*p_[1][j] + p_[2][j]*p_[2][j]) + 1e-6f;
          s1 += nr; s2 += nr * nr;
        }
        st4(Y, yb,                 p_[0][0], p_[0][1], p_[0][2], p_[0][3]);
        st4(Y, yb + N,             p_[1][0], p_[1][1], p_[1][2], p_[1][3]);
        st4(Y, yb + 2 * (size_t)N, p_[2][0], p_[2][1], p_[2][2], p_[2][3]);
      }
      #pragma unroll
      for (int off = 8; off; off >>= 1) { s1 += __shfl_down(s1, off); s2 += __shfl_down(s2, off); }
      if (tx == 0 && co < Cout) { atomicAdd(&statSum[co], s1); atomicAdd(&statSq[co], s2); }
    } else if constexpr (MODE == 6) {
      if (co < Cout) {
        float mn = statMean[co], is = statIstd[co];
        size_t yb = ((size_t)b * Cout + co) * 3 * N + n0 + tx * 4;
        float4 P0 = *(const float4*)&Y[yb];
        float4 P1 = *(const float4*)&Y[yb + N];
        float4 P2 = *(const float4*)&Y[yb + 2 * (size_t)N];
        float pr[3][4] = {{P0.x,P0.y,P0.z,P0.w},{P1.x,P1.y,P1.z,P1.w},{P2.x,P2.y,P2.z,P2.w}};
        float o_[3][4];
        #pragma unroll
        for (int j = 0; j < 4; ++j) {
          float q0 = pr[0][j], q1 = pr[1][j], q2 = pr[2][j];
          float e0 = p_[0][j], e1 = p_[1][j], e2 = p_[2][j];
          float nr = sqrtf(q0*q0 + q1*q1 + q2*q2) + 1e-6f;
          float sc = ((nr - mn) * is) / nr;
          q0 *= sc; q1 *= sc; q2 *= sc;
          float dot = q0*e0 + q1*e1 + q2*e2;
          if (dot < 0.f) {
            float dsq = e0*e0 + e1*e1 + e2*e2;
            float t = dot / (dsq + 1e-6f);
            q0 -= t*e0; q1 -= t*e1; q2 -= t*e2;
          }
          o_[0][j] = q0; o_[1][j] = q1; o_[2][j] = q2;
        }
        st4(Y, yb,                 o_[0][0], o_[0][1], o_[0][2], o_[0][3]);
        st4(Y, yb + N,             o_[1][0], o_[1][1], o_[1][2], o_[1][3]);
        st4(Y, yb + 2 * (size_t)N, o_[2][0], o_[2][1], o_[2][2], o_[2][3]);
      }
    }
  }
}

// ------------------------------------- transposed-layout MFMA bf16 VN GEMM
// Tensors: Xt/P are [b][3][N][Cpad] bf16, channels zero-padded.
// MODE 0: Z = W.X -> fp32 standard layout (z0)
// MODE 1: P = W.X (+biasP) -> write P bf16 (incl. zero pad) + per-co stats
// MODE 2: D = W.X (+biasD); read P, bn+lrelu, write in place
template<int MODE, int NS>
__global__ __launch_bounds__(256) void mfma2(
    const u16* __restrict__ W, const u16* __restrict__ Xt,
    u16* __restrict__ P, float* __restrict__ Zout,
    const float* __restrict__ biasP, const float* __restrict__ biasD,
    float* __restrict__ statSum, float* __restrict__ statSq,
    const float* __restrict__ statMean, const float* __restrict__ statIstd,
    int Cout, int Cpad, int Kpad, int N) {
  const int tid = threadIdx.x, lane = tid & 63, w = tid >> 6;
  const int quad = lane >> 4, l16 = lane & 15;
  const int b = blockIdx.z, n0 = blockIdx.x * 64, co0 = blockIdx.y * 64;
  const int n = n0 + w * 16 + l16;
  const u16* Xb = Xt + (size_t)b * 3 * N * Kpad;
  f32x4 acc[NS][3];
  #pragma unroll
  for (int s = 0; s < NS; ++s)
    #pragma unroll
    for (int v = 0; v < 3; ++v) acc[s][v] = {0.f, 0.f, 0.f, 0.f};

  for (int k0 = 0; k0 < Kpad; k0 += 32) {
    bh8 bx[3];
    #pragma unroll
    for (int v = 0; v < 3; ++v)
      bx[v] = *(const bh8*)(Xb + ((size_t)v * N + n) * Kpad + k0 + quad * 8);
    #pragma unroll
    for (int s = 0; s < NS; ++s) {
      bh8 a = *(const bh8*)(W + (size_t)(co0 + s * 16 + l16) * Kpad + k0 + quad * 8);
      #pragma unroll
      for (int v = 0; v < 3; ++v)
        acc[s][v] = __builtin_amdgcn_mfma_f32_16x16x32_bf16(a, bx[v], acc[s][v], 0, 0, 0);
    }
  }

  u16* Pb = P + (size_t)b * 3 * N * Cpad;
  #pragma unroll
  for (int s = 0; s < NS; ++s) {
    int cb = co0 + s * 16 + quad * 4;
    if constexpr (MODE == 0) {
      #pragma unroll
      for (int r = 0; r < 4; ++r) {
        int co = cb + r;
        if (co < Cout) {
          size_t zb = (((size_t)b * Cout + co) * 3) * N + n;
          Zout[zb] = acc[s][0][r];
          Zout[zb + N] = acc[s][1][r];
          Zout[zb + 2 * (size_t)N] = acc[s][2][r];
        }
      }
    } else if constexpr (MODE == 1) {
      if (cb < Cpad) {
        float q[3][4];
        #pragma unroll
        for (int r = 0; r < 4; ++r) {
          int co = cb + r;
          float b0 = 0, b1 = 0, b2 = 0;
          if (biasP != nullptr && co < Cout) {
            size_t bi = ((size_t)b * Cout + co) * 3;
            b0 = biasP[bi]; b1 = biasP[bi + 1]; b2 = biasP[bi + 2];
          }
          float q0 = acc[s][0][r] + b0, q1 = acc[s][1][r] + b1, q2 = acc[s][2][r] + b2;
          if (co >= Cout) { q0 = 0.f; q1 = 0.f; q2 = 0.f; }
          q[0][r] = q0; q[1][r] = q1; q[2][r] = q2;
          float nr = sqrtf(q0*q0 + q1*q1 + q2*q2) + 1e-6f;
          float s1 = nr, s2 = nr * nr;
          #pragma unroll
          for (int off = 1; off < 16; off <<= 1) { s1 += __shfl_xor(s1, off); s2 += __shfl_xor(s2, off); }
          if (l16 == 0 && co < Cout) { atomicAdd(&statSum[co], s1); atomicAdd(&statSq[co], s2); }
        }
        #pragma unroll
        for (int v = 0; v < 3; ++v) {
          u16 ob[4];
          ob[0] = f2b(q[v][0]); ob[1] = f2b(q[v][1]); ob[2] = f2b(q[v][2]); ob[3] = f2b(q[v][3]);
          *(ushort4*)(Pb + ((size_t)v * N + n) * Cpad + cb) = *(ushort4*)ob;
        }
      }
    } else {  // MODE 2
      if (cb < Cpad) {
        u16 pa[3][4];
        #pragma unroll
        for (int v = 0; v < 3; ++v)
          *(ushort4*)pa[v] = *(const ushort4*)(Pb + ((size_t)v * N + n) * Cpad + cb);
        float o[3][4];
        #pragma unroll
        for (int r = 0; r < 4; ++r) {
          int co = cb + r;
          float r0 = 0.f, r1 = 0.f, r2 = 0.f;
          if (co < Cout) {
            float p0 = b2f(pa[0][r]), p1 = b2f(pa[1][r]), p2 = b2f(pa[2][r]);
            float d0 = acc[s][0][r], d1 = acc[s][1][r], d2 = acc[s][2][r];
            if (biasD != nullptr) {
              size_t bi = ((size_t)b * Cout + co) * 3;
              d0 += biasD[bi]; d1 += biasD[bi + 1]; d2 += biasD[bi + 2];
            }
            float mn = statMean[co], is = statIstd[co];
            float nr = sqrtf(p0*p0 + p1*p1 + p2*p2) + 1e-6f;
            float sc = ((nr - mn) * is) / nr;
            float q0 = p0 * sc, q1 = p1 * sc, q2 = p2 * sc;
            float dot = q0*d0 + q1*d1 + q2*d2;
            if (dot < 0.f) {
              float dsq = d0*d0 + d1*d1 + d2*d2;
              float t = dot / (dsq + 1e-6f);
              q0 -= t*d0; q1 -= t*d1; q2 -= t*d2;
            }
            r0 = q0; r1 = q1; r2 = q2;
          }
          o[0][r] = r0; o[1][r] = r1; o[2][r] = r2;
        }
        #pragma unroll
        for (int v = 0; v < 3; ++v) {
          u16 ob[4];
          ob[0] = f2b(o[v][0]); ob[1] = f2b(o[v][1]); ob[2] = f2b(o[v][2]); ob[3] = f2b(o[v][3]);
          *(ushort4*)(Pb + ((size_t)v * N + n) * Cpad + cb) = *(ushort4*)ob;
        }
      }
    }
  }
}

// weight fp32 -> padded bf16 [CoutPad x Kpad]
__global__ void w_to_bf16(const float* __restrict__ W, u16* __restrict__ Wp,
                          int Cout, int Cin, int wstride, int CoutPad, int Kpad) {
  int t = blockIdx.x * 256 + threadIdx.x;
  if (t >= CoutPad * Kpad) return;
  int co = t / Kpad, ci = t - co * Kpad;
  Wp[t] = (co < Cout && ci < Cin) ? f2b(W[(size_t)co * wstride + ci]) : (u16)0;
}

// ----------------------------------------------------------- small kernels
__global__ void zero_kernel(float* p, int n) {
  int t = blockIdx.x * 256 + threadIdx.x;
  if (t < n) p[t] = 0.f;
}

// computes mean/istd AND re-zeroes sum/sq (512 wide) for the next layer
__global__ void finalize_kernel(float* __restrict__ sum, float* __restrict__ sq,
                                float* __restrict__ mean, float* __restrict__ istd,
                                int C, float invCount) {
  int c = blockIdx.x * 256 + threadIdx.x;
  if (c < C) {
    float m = sum[c] * invCount;
    float v = sq[c] * invCount - m * m;
    if (v < 0.f) v = 0.f;
    mean[c] = m;
    istd[c] = 1.f / sqrtf(v + 1e-5f);
  }
  if (c < 512) { sum[c] = 0.f; sq[c] = 0.f; }
}

__global__ __launch_bounds__(64) void pool_reduce(const unsigned long long* __restrict__ part,
                                                  const float* __restrict__ s3,
                                                  float* __restrict__ pooled, int N) {
  int co = blockIdx.x, b = blockIdx.y, lane = threadIdx.x;
  unsigned long long key = part[((size_t)b * 341 + co) * 64 + lane];
  #pragma unroll
  for (int off = 32; off; off >>= 1) {
    unsigned long long o = __shfl_down(key, off);
    if (o > key) key = o;
  }
  if (lane == 0) {
    int n = (int)(0xFFFFFFFFu - (unsigned)(key & 0xFFFFFFFFull));
    size_t base = ((size_t)b * 341 + co) * 3;
    pooled[base + 0] = s3[(base + 0) * N + n];
    pooled[base + 1] = s3[(base + 1) * N + n];
    pooled[base + 2] = s3[(base + 2) * N + n];
  }
}

// vn_lrelu on (B,Cin,3) tiny tensors (bn stats over batch axis only)
__global__ __launch_bounds__(64) void stf_lrelu(const float* __restrict__ Wf,
                                                const float* __restrict__ Wd,
                                                const float* __restrict__ X,
                                                float* __restrict__ Y, int Cin, int Cout) {
  __shared__ float P[24], D[24], NORM[8], SC[8], DOT[8], DSQ[8], MS[2];
  int co = blockIdx.x, tid = threadIdx.x;
  if (tid < 48) {
    int l = tid < 24 ? tid : tid - 24;
    int b = l / 3, v = l - b * 3;
    const float* W = (tid < 24 ? Wf : Wd) + (size_t)co * Cin;
    const float* xb = X + ((size_t)b * Cin) * 3 + v;
    float acc = 0.f;
    for (int ci = 0; ci < Cin; ++ci) acc += W[ci] * xb[ci * 3];
    if (tid < 24) P[l] = acc; else D[l] = acc;
  }
  __syncthreads();
  if (tid < 8) NORM[tid] = sqrtf(P[tid*3]*P[tid*3] + P[tid*3+1]*P[tid*3+1] + P[tid*3+2]*P[tid*3+2]) + 1e-6f;
  __syncthreads();
  if (tid == 0) {
    float m = 0.f;
    for (int b2 = 0; b2 < 8; ++b2) m += NORM[b2];
    m *= 0.125f;
    float var = 0.f;
    for (int b2 = 0; b2 < 8; ++b2) { float dd = NORM[b2] - m; var += dd * dd; }
    var *= 0.125f;
    MS[0] = m; MS[1] = 1.f / sqrtf(var + 1e-5f);
  }
  __syncthreads();
  if (tid < 8) {
    float sc = ((NORM[tid] - MS[0]) * MS[1]) / NORM[tid];
    float dot = 0.f, dsq = 0.f;
    for (int v = 0; v < 3; ++v) {
      float pb = P[tid*3+v] * sc; float dv = D[tid*3+v];
      dot += pb * dv; dsq += dv * dv;
    }
    SC[tid] = sc; DOT[tid] = dot; DSQ[tid] = dsq;
  }
  __syncthreads();
  if (tid < 24) {
    int b = tid / 3;
    float pb = P[tid] * SC[b];
    float o = (DOT[b] >= 0.f) ? pb : pb - (DOT[b] / (DSQ[b] + 1e-6f)) * D[tid];
    Y[((size_t)b * Cout + co) * 3 + (tid - b * 3)] = o;
  }
}

__global__ void vnlin_small(const float* __restrict__ W, const float* __restrict__ X,
                            float* __restrict__ Y, int Cin, int Cout) {
  int t = blockIdx.x * 256 + threadIdx.x;   // over 8*Cout*3
  if (t >= 8 * Cout * 3) return;
  int v = t % 3, r = t / 3;
  int co = r % Cout, b = r / Cout;
  float acc = 0.f;
  for (int ci = 0; ci < Cin; ++ci) acc += W[(size_t)co * Cin + ci] * X[((size_t)b * Cin + ci) * 3 + v];
  Y[t] = acc;
}

// concat [h1 ; broadcast sfin ; zero-pad] -> transposed bf16 [b][v][n][64]
// via LDS tile: h1 read coalesced over n, s2bb written coalesced over c.
__global__ __launch_bounds__(256) void concat_tt(const float* __restrict__ h1,
                                                 const float* __restrict__ sfin,
                                                 u16* __restrict__ s2bb, int N) {
  __shared__ u16 tile[64][66];
  int b = blockIdx.z, v = blockIdx.y, n0 = blockIdx.x * 64;
  int tn = threadIdx.x & 63, tc = threadIdx.x >> 6;   // tc in [0,4)
  for (int c = tc; c < 64; c += 4) {
    u16 val = 0;
    if (c < 21) val = f2b(h1[(((size_t)b * 21 + c) * 3 + v) * N + n0 + tn]);
    else if (c < 42) val = f2b(sfin[((size_t)b * 21 + (c - 21)) * 3 + v]);
    tile[c][tn] = val;
  }
  __syncthreads();
  u16* dst = s2bb + (((size_t)b * 3 + v) * N + n0) * 64;
  for (int n = tc; n < 64; n += 4)
    dst[(size_t)n * 64 + tn] = tile[tn][n];
}

// in-place bn on transposed H + accumulate per-(c,v) sums for h_mean
__global__ __launch_bounds__(384) void bn_apply_mean(u16* __restrict__ H,
    const float* __restrict__ sMean, const float* __restrict__ sIstd,
    float* __restrict__ HmAcc, int N) {
  int c = threadIdx.x;
  if (c >= 341) return;
  int b = blockIdx.y, nt = blockIdx.x;
  float mn = sMean[c], is = sIstd[c];
  float a0 = 0.f, a1 = 0.f, a2 = 0.f;
  size_t base = (size_t)b * 3 * N * 352;
  for (int n = nt * 256; n < nt * 256 + 256; ++n) {
    size_t i0 = base + ((size_t)0 * N + n) * 352 + c;
    size_t i1 = base + ((size_t)1 * N + n) * 352 + c;
    size_t i2 = base + ((size_t)2 * N + n) * 352 + c;
    float p0 = b2f(H[i0]), p1 = b2f(H[i1]), p2 = b2f(H[i2]);
    float nr = sqrtf(p0*p0 + p1*p1 + p2*p2) + 1e-6f;
    float sc = ((nr - mn) * is) / nr;
    p0 *= sc; p1 *= sc; p2 *= sc;
    H[i0] = f2b(p0); H[i1] = f2b(p1); H[i2] = f2b(p2);
    a0 += p0; a1 += p1; a2 += p2;
  }
  size_t hb = ((size_t)b * 341 + c) * 3;
  atomicAdd(&HmAcc[hb], a0); atomicAdd(&HmAcc[hb + 1], a1); atomicAdd(&HmAcc[hb + 2], a2);
}

__global__ void hm_finalize(float* Hm, float invN) {
  int t = blockIdx.x * 256 + threadIdx.x;
  if (t < 8 * 341 * 3) Hm[t] *= invN;
}

// bias terms for std1: W[:,341:682] . h_mean   (n-invariant half of concat)
__global__ void bias_kernel(const float* __restrict__ Wf, const float* __restrict__ Wd,
                            const float* __restrict__ Hm,
                            float* __restrict__ biasP, float* __restrict__ biasD) {
  int t = blockIdx.x * 256 + threadIdx.x;   // over 8*341*3
  if (t >= 8 * 341 * 3) return;
  int v = t % 3, r = t / 3;
  int co = r % 341, b = r / 341;
  const float* hm = Hm + (size_t)b * 1023 + v;
  float ap = 0.f, ad = 0.f;
  for (int j = 0; j < 341; ++j) {
    float h = hm[j * 3];
    ap += Wf[(size_t)co * 682 + 341 + j] * h;
    ad += Wd[(size_t)co * 682 + 341 + j] * h;
  }
  biasP[t] = ap; biasD[t] = ad;
}

// h_std einsum + max over N on transposed H; rows >=341 use h_mean
__global__ __launch_bounds__(256) void final_max_t(const u16* __restrict__ H,
    const float* __restrict__ Hm, const float* __restrict__ z0,
    float* __restrict__ out, int N) {
  __shared__ float red[3][4][64];
  int b = blockIdx.y;
  int il = threadIdx.x & 63, nsub = threadIdx.x >> 6;
  int i = blockIdx.x * 64 + il;
  bool valid = i < 682, lo = i < 341;
  float c0 = 0, c1 = 0, c2 = 0;
  if (valid && !lo) {
    size_t hb = ((size_t)b * 341 + (i - 341)) * 3;
    c0 = Hm[hb]; c1 = Hm[hb + 1]; c2 = Hm[hb + 2];
  }
  const float* zb = z0 + (size_t)b * 9 * N;
  const u16* Hb = H + (size_t)b * 3 * N * 352;
  float m0 = -3.4e38f, m1 = -3.4e38f, m2 = -3.4e38f;
  int ii = lo ? i : 0;
  for (int n = nsub; n < N; n += 4) {
    float a0, a1, a2;
    if (lo) {
      a0 = b2f(Hb[((size_t)0 * N + n) * 352 + ii]);
      a1 = b2f(Hb[((size_t)1 * N + n) * 352 + ii]);
      a2 = b2f(Hb[((size_t)2 * N + n) * 352 + ii]);
    } else { a0 = c0; a1 = c1; a2 = c2; }
    float s0 = a0 * zb[n]                + a1 * zb[3 * (size_t)N + n] + a2 * zb[6 * (size_t)N + n];
    float s1 = a0 * zb[N + n]            + a1 * zb[4 * (size_t)N + n] + a2 * zb[7 * (size_t)N + n];
    float s2 = a0 * zb[2 * (size_t)N + n]+ a1 * zb[5 * (size_t)N + n] + a2 * zb[8 * (size_t)N + n];
    m0 = fmaxf(m0, s0); m1 = fmaxf(m1, s1); m2 = fmaxf(m2, s2);
  }
  red[0][nsub][il] = m0; red[1][nsub][il] = m1; red[2][nsub][il] = m2;
  __syncthreads();
  if (nsub == 0 && valid) {
    for (int q = 1; q < 4; ++q) {
      m0 = fmaxf(m0, red[0][q][il]); m1 = fmaxf(m1, red[1][q][il]); m2 = fmaxf(m2, red[2][q][il]);
    }
    size_t ob = (size_t)b * 2046 + (size_t)i * 3;
    out[ob] = m0; out[ob + 1] = m1; out[ob + 2] = m2;
  }
}

// ------------------------------------------------------------------- host
extern "C" void kernel_launch(void* const* d_in, const int* in_sizes, int n_in,
                              void* d_out, int out_size, void* d_ws, size_t ws_size,
                              hipStream_t stream) {
  (void)in_sizes; (void)n_in; (void)out_size; (void)ws_size;
  const float* x       = (const float*)d_in[0];
  const float* pos_Wf  = (const float*)d_in[1];
  const float* pos_Wd  = (const float*)d_in[2];
  const float* pool_Wd = (const float*)d_in[3];
  const float* c1_Wf   = (const float*)d_in[4];
  const float* c1_Wd   = (const float*)d_in[5];
  const float* st1_Wf  = (const float*)d_in[6];
  const float* st1_Wd  = (const float*)d_in[7];
  const float* st2_Wf  = (const float*)d_in[8];
  const float* st2_Wd  = (const float*)d_in[9];
  const float* st3_Wf  = (const float*)d_in[10];
  const float* st3_Wd  = (const float*)d_in[11];
  const float* stp_Wd  = (const float*)d_in[12];
  const float* stf1_Wf = (const float*)d_in[13];
  const float* stf1_Wd = (const float*)d_in[14];
  const float* stf2_Wf = (const float*)d_in[15];
  const float* stf2_Wd = (const float*)d_in[16];
  const float* stf3_W  = (const float*)d_in[17];
  const float* c2_Wf   = (const float*)d_in[18];
  const float* c2_Wd   = (const float*)d_in[19];
  const float* c3_W    = (const float*)d_in[20];
  const float* std1_Wf = (const float*)d_in[21];
  const float* std1_Wd = (const float*)d_in[22];
  const float* std2_Wf = (const float*)d_in[23];
  const float* std2_Wd = (const float*)d_in[24];
  const float* stdlin  = (const float*)d_in[25];

  float* outv  = (float*)d_out;           // fp32: [8*2046] ++ z0 [8*3*3*4096]
  float* z0out = outv + 8 * 2046;

  const int N = 4096;
  char* ws = (char*)d_ws;
  size_t off = 0;
  auto alloc = [&](size_t bytes) -> char* {
    char* p = ws + off;
    off += (bytes + 255) & ~(size_t)255;
    return p;
  };
  float* stats = (float*)alloc(2048 * sizeof(float));
  float* sSum = stats, *sSq = stats + 512, *sMean = stats + 1024, *sIstd = stats + 1536;
  int* idx = (int*)alloc((size_t)8 * N * 20 * 4);
  unsigned long long* poolPart = (unsigned long long*)alloc((size_t)8 * 341 * 64 * 8);
  float* pooled = (float*)alloc(8 * 341 * 3 * 4);
  float* stf1o  = (float*)alloc(8 * 170 * 3 * 4);
  float* stf2o  = (float*)alloc(8 * 85 * 3 * 4);
  float* sfin   = (float*)alloc(8 * 21 * 3 * 4);
  float* Hm     = (float*)alloc(8 * 1023 * 4);
  float* biasP  = (float*)alloc(8 * 341 * 3 * 4);
  float* biasD  = (float*)alloc(8 * 341 * 3 * 4);
  const size_t E21 = (size_t)8 * 21 * 3 * N, E42 = (size_t)8 * 42 * 3 * N;
  const size_t E341 = (size_t)8 * 341 * 3 * N;
  const size_t T352 = (size_t)8 * 3 * N * 352 * 2;
  const size_t T192 = (size_t)8 * 3 * N * 192 * 2;
  const size_t T64  = (size_t)8 * 3 * N * 64 * 2;
  char* regionA = alloc(T352);
  char* regionB = alloc(E341 * 4);
  float* h0  = (float*)regionA;
  float* h1  = h0 + E21;
  float* s1b = h0 + 2 * E21;
  float* s2b = h0 + 3 * E21;                  // st2 out (fp32), st3 input
  float* st3o = (float*)regionB;              // st3 P then in-place out (fp32, argmax-exact)
  u16* Hbuf  = (u16*)regionB;                 // c3 out ^T, live until final_max
  u16* Pstd2 = (u16*)(regionB + T352);        // std2 P / out ^T
  u16* s2bb  = (u16*)(regionB + T352 + T192); // concat out ^T (Cpad 64)
  u16* h2b   = (u16*)(regionB + T352 + T192 + T64); // c2 P / out ^T
  u16* Pstd1 = (u16*)regionA;                 // std1 P / out ^T (early stack dead)
  // padded bf16 weights in poolPart (dead after pool_reduce); sizes in u16
  u16* W1fp = (u16*)poolPart;                 // 384x352
  u16* W1dp = W1fp + 384 * 352;
  u16* W2fp = W1dp + 384 * 352;               // 192x352
  u16* W2dp = W2fp + 192 * 352;
  u16* Wc3p = W2dp + 192 * 352;               // 384x64
  u16* Wc2f = Wc3p + 384 * 64;                // 64x64
  u16* Wc2d = Wc2f + 64 * 64;
  u16* Wzp  = Wc2d + 64 * 64;                 // 16x192

  dim3 blk256(256), blk64(64);
  // fp32 lrelu layer: MODE5 (P+stats) -> finalize -> MODE6 (D + apply in place)
  auto run_lrelu32 = [&](const float* Wf, const float* Wd, const float* X, float* Y,
                         int Cin, int Cout, int wstride, float invCnt) {
    dim3 grid(64, (Cout + 31) / 32, 8);
    gemm_vn<5, 2><<<grid, blk256, 0, stream>>>(Wf, X, Y, sSum, sSq,
                                               nullptr, nullptr, nullptr, Cin, Cout, wstride, N);
    finalize_kernel<<<dim3(2), blk256, 0, stream>>>(sSum, sSq, sMean, sIstd, Cout, invCnt);
    gemm_vn<6, 2><<<grid, blk256, 0, stream>>>(Wd, X, Y, nullptr, nullptr,
                                               sMean, sIstd, nullptr, Cin, Cout, wstride, N);
  };
  const float invBN = 1.f / (8.f * N);
  // bf16 mfma lrelu layer (transposed tensors)
  auto run_mfma = [&](const u16* Wf, const u16* Wd, const u16* X, u16* P,
                      const float* bP, const float* bD,
                      int Cout, int Cpad, int Kpad, int coTiles) {
    dim3 grid(64, coTiles, 8);
    mfma2<1, 4><<<grid, blk256, 0, stream>>>(Wf, X, P, nullptr, bP, nullptr,
                                             sSum, sSq, nullptr, nullptr, Cout, Cpad, Kpad, N);
    finalize_kernel<<<dim3(2), blk256, 0, stream>>>(sSum, sSq, sMean, sIstd, Cout, invBN);
    mfma2<2, 4><<<grid, blk256, 0, stream>>>(Wd, X, P, nullptr, nullptr, bD,
                                             nullptr, nullptr, sMean, sIstd, Cout, Cpad, Kpad, N);
  };

  // 0. zero stats once; thereafter finalize_kernel self-zeroes for next layer
  zero_kernel<<<dim3(4), blk256, 0, stream>>>(stats, 1024);
  // 1. KNN (one wave per point)
  knn_kernel<<<dim3(N / 4, 8), blk256, 0, stream>>>(x, idx, N);
  // 2. pos layer
  pos_stats<<<dim3(N * 20 / 256, 8), blk256, 0, stream>>>(x, idx, pos_Wf, sSum, sSq, N);
  finalize_kernel<<<dim3(2), blk256, 0, stream>>>(sSum, sSq, sMean, sIstd, 21, 1.f / (8.f * N * 20.f));
  pos_apply<<<dim3(N, 8), blk64, 0, stream>>>(x, idx, pos_Wf, pos_Wd, pool_Wd, sMean, sIstd, h0, N);

  // 3. early fp32 chain (argmax-exact path)
  run_lrelu32(c1_Wf, c1_Wd, h0, h1, 21, 21, 21, invBN);
  run_lrelu32(st1_Wf, st1_Wd, h1, s1b, 21, 21, 21, invBN);
  run_lrelu32(st2_Wf, st2_Wd, s1b, s2b, 21, 42, 21, invBN);
  run_lrelu32(st3_Wf, st3_Wd, s2b, st3o, 42, 341, 42, invBN);

  // 4. st_pool over N (fp32-exact argmax), CPT=4 -> 64-co tiles
  gemm_vn<4, 4><<<dim3(64, 6, 8), blk256, 0, stream>>>(stp_Wd, st3o, (float*)nullptr,
                                                       nullptr, nullptr, nullptr, nullptr,
                                                       poolPart, 341, 341, 341, N);
  pool_reduce<<<dim3(341, 8), blk64, 0, stream>>>(poolPart, st3o, pooled, N);

  // 5. weights -> padded bf16 (poolPart now dead)
  w_to_bf16<<<dim3((384 * 352 + 255) / 256), blk256, 0, stream>>>(std1_Wf, W1fp, 341, 341, 682, 384, 352);
  w_to_bf16<<<dim3((384 * 352 + 255) / 256), blk256, 0, stream>>>(std1_Wd, W1dp, 341, 341, 682, 384, 352);
  w_to_bf16<<<dim3((192 * 352 + 255) / 256), blk256, 0, stream>>>(std2_Wf, W2fp, 170, 341, 341, 192, 352);
  w_to_bf16<<<dim3((192 * 352 + 255) / 256), blk256, 0, stream>>>(std2_Wd, W2dp, 170, 341, 341, 192, 352);
  w_to_bf16<<<dim3((384 * 64 + 255) / 256), blk256, 0, stream>>>(c3_W, Wc3p, 341, 42, 42, 384, 64);
  w_to_bf16<<<dim3((64 * 64 + 255) / 256), blk256, 0, stream>>>(c2_Wf, Wc2f, 42, 42, 42, 64, 64);
  w_to_bf16<<<dim3((64 * 64 + 255) / 256), blk256, 0, stream>>>(c2_Wd, Wc2d, 42, 42, 42, 64, 64);
  w_to_bf16<<<dim3((16 * 192 + 255) / 256), blk256, 0, stream>>>(stdlin, Wzp, 3, 170, 170, 16, 192);

  // 6. stf chain (tiny)
  stf_lrelu<<<dim3(170), blk64, 0, stream>>>(stf1_Wf, stf1_Wd, pooled, stf1o, 341, 170);
  stf_lrelu<<<dim3(85),  blk64, 0, stream>>>(stf2_Wf, stf2_Wd, stf1o, stf2o, 170, 85);
  vnlin_small<<<dim3(2), blk256, 0, stream>>>(stf3_W, stf2o, sfin, 85, 21);

  // 7. concat -> transposed bf16 (LDS-tiled); c2 (mfma)
  concat_tt<<<dim3(N / 64, 3, 8), blk256, 0, stream>>>(h1, sfin, s2bb, N);
  run_mfma(Wc2f, Wc2d, s2bb, h2b, nullptr, nullptr, 42, 64, 64, 1);

  // 8. c3 + bn (mfma P+stats, then fused bn-apply + h_mean)
  {
    dim3 grid(64, 6, 8);
    mfma2<1, 4><<<grid, blk256, 0, stream>>>(Wc3p, h2b, Hbuf, nullptr, nullptr, nullptr,
                                             sSum, sSq, nullptr, nullptr, 341, 352, 64, N);
  }
  finalize_kernel<<<dim3(2), blk256, 0, stream>>>(sSum, sSq, sMean, sIstd, 341, invBN);
  zero_kernel<<<dim3(32), blk256, 0, stream>>>(Hm, 8 * 1023);
  bn_apply_mean<<<dim3(16, 8), dim3(384), 0, stream>>>(Hbuf, sMean, sIstd, Hm, N);
  hm_finalize<<<dim3(32), blk256, 0, stream>>>(Hm, 1.f / (float)N);
  bias_kernel<<<dim3(32), blk256, 0, stream>>>(std1_Wf, std1_Wd, Hm, biasP, biasD);

  // 9. VNStdFeature (mfma)
  run_mfma(W1fp, W1dp, Hbuf, Pstd1, biasP, biasD, 341, 352, 352, 6);
  run_mfma(W2fp, W2dp, Pstd1, Pstd2, nullptr, nullptr, 170, 192, 352, 3);

  // 10. z0 (mfma MODE0, fp32 out) + fused einsum/max
  mfma2<0, 1><<<dim3(64, 1, 8), blk256, 0, stream>>>(Wzp, Pstd2, nullptr, z0out,
                                                     nullptr, nullptr, nullptr, nullptr,
                                                     nullptr, nullptr, 3, 16, 192, N);
  final_max_t<<<dim3(11, 8), blk256, 0, stream>>>(Hbuf, Hm, z0out, outv, N);
}

// Round 11
// 2895.420 us; speedup vs baseline: 1.3467x; 1.2526x over previous
//
#include <hip/hip_runtime.h>
#include <cstdint>
#include <cstddef>

// VN-PointNet encoder. Inputs fp32, outputs fp32 (out 8x2046 ++ z0 8x3x3x4096).
// Early chain (pos..st3, st_pool) fp32 (argmax-exact), single-buffered LDS
// GEMM. st_pool CPT=4. Post-pool chain (c2,c3,std1,std2,z0) on bf16 MFMA with
// k-major transposed tensors [b][v][n][Cpad]. KNN: one wave/point reg top-8.
// final_max: n-tiled partials (R10's 88-block version was 2.7% occupancy).
// Standard (B,C,3,N) layout: flat ((b*C+c)*3+v)*N + n.

typedef unsigned short u16;
using bh8  = __attribute__((ext_vector_type(8))) short;
using f32x4 = __attribute__((ext_vector_type(4))) float;

__device__ __forceinline__ float b2f(u16 v) {
  return __uint_as_float(((unsigned)v) << 16);
}
__device__ __forceinline__ u16 f2b(float f) {
  unsigned u = __float_as_uint(f);
  u += 0x7FFFu + ((u >> 16) & 1u);   // round-to-nearest-even
  return (u16)(u >> 16);
}

__device__ __forceinline__ float ldg(const float* p, size_t i) { return p[i]; }
__device__ __forceinline__ float ldg(const u16* p, size_t i) { return b2f(p[i]); }
__device__ __forceinline__ void st4(float* p, size_t i, float a, float b, float c, float d) {
  float4 v; v.x = a; v.y = b; v.z = c; v.w = d; *(float4*)(p + i) = v;
}

#define FMA4(A, S, V) { A.x += (S)*(V).x; A.y += (S)*(V).y; A.z += (S)*(V).z; A.w += (S)*(V).w; }

__device__ __forceinline__ unsigned long long packKey(float v, int n) {
  unsigned u = __float_as_uint(v);
  u = (u & 0x80000000u) ? ~u : (u | 0x80000000u);   // total-order float
  return ((unsigned long long)u << 32) | (unsigned long long)(0xFFFFFFFFu - (unsigned)n);
}

// ------------------------------------------- KNN top-20: one wave per point
#define CSWAP(T) { if (c > T) { unsigned long long tmp = T; T = c; c = tmp; } }
__global__ __launch_bounds__(256) void knn_kernel(const float* __restrict__ x,
                                                  int* __restrict__ idxOut, int N) {
  int b = blockIdx.y;
  int wv = threadIdx.x >> 6, lane = threadIdx.x & 63;
  int i = blockIdx.x * 4 + wv;
  const float* xb = x + (size_t)b * 3 * N;
  float xi0 = xb[i], xi1 = xb[N + i], xi2 = xb[2 * (size_t)N + i];
  float xxi = xi0 * xi0 + xi1 * xi1 + xi2 * xi2;
  unsigned long long t0 = 0, t1 = 0, t2 = 0, t3 = 0, t4 = 0, t5 = 0, t6 = 0, t7 = 0;
  #pragma unroll 8
  for (int s = 0; s < 64; ++s) {
    int j = s * 64 + lane;
    float a0 = xb[j], a1 = xb[N + j], a2 = xb[2 * (size_t)N + j];
    float inner = xi0 * a0 + xi1 * a1 + xi2 * a2;
    float xxj = a0 * a0 + a1 * a1 + a2 * a2;
    float pd = 2.f * inner - xxi - xxj;          // = -||xi-xj||^2
    unsigned long long c = packKey(pd, j);
    if (c > t7) { CSWAP(t0) CSWAP(t1) CSWAP(t2) CSWAP(t3) CSWAP(t4) CSWAP(t5) CSWAP(t6) CSWAP(t7) }
  }
  int* row = idxOut + ((size_t)b * N + i) * 20;
  for (int kk = 0; kk < 20; ++kk) {
    unsigned long long k = t0;
    #pragma unroll
    for (int off = 1; off < 64; off <<= 1) {
      unsigned long long o = __shfl_xor(k, off);
      if (o > k) k = o;
    }
    if (lane == 0) row[kk] = (int)(0xFFFFFFFFu - (unsigned)(k & 0xFFFFFFFFull));
    if (k == t0) { t0 = t1; t1 = t2; t2 = t3; t3 = t4; t4 = t5; t5 = t6; t6 = t7; t7 = 0; }
  }
}
#undef CSWAP

// ------------------------------------------------- pos layer: bn statistics
__global__ __launch_bounds__(256) void pos_stats(const float* __restrict__ x,
                                                 const int* __restrict__ idx,
                                                 const float* __restrict__ Wf,
                                                 float* __restrict__ statSum,
                                                 float* __restrict__ statSq, int N) {
  __shared__ float wf[64];
  __shared__ float part[4][42];
  int tid = threadIdx.x;
  if (tid < 63) wf[tid] = Wf[tid];
  __syncthreads();
  int b = blockIdx.y;
  int lin = blockIdx.x * 256 + tid;           // over N*20 exactly
  int n = lin / 20, kk = lin - n * 20;
  const float* xb = x + (size_t)b * 3 * N;
  int j = idx[((size_t)b * N + n) * 20 + kk];
  float c0 = xb[n], c1 = xb[N + n], c2 = xb[2 * (size_t)N + n];
  float a0 = xb[j], a1 = xb[N + j], a2 = xb[2 * (size_t)N + j];
  float e00 = a0 - c0, e01 = a1 - c1, e02 = a2 - c2;
  float e20 = a1 * c2 - a2 * c1, e21 = a2 * c0 - a0 * c2, e22 = a0 * c1 - a1 * c0;
  int lane = tid & 63, wave = tid >> 6;
  #pragma unroll
  for (int c = 0; c < 21; ++c) {
    float w0 = wf[c * 3], w1 = wf[c * 3 + 1], w2 = wf[c * 3 + 2];
    float p0 = w0 * e00 + w1 * c0 + w2 * e20;
    float p1 = w0 * e01 + w1 * c1 + w2 * e21;
    float p2 = w0 * e02 + w1 * c2 + w2 * e22;
    float nr = sqrtf(p0 * p0 + p1 * p1 + p2 * p2) + 1e-6f;
    float u1 = nr, u2 = nr * nr;
    #pragma unroll
    for (int off = 32; off; off >>= 1) { u1 += __shfl_down(u1, off); u2 += __shfl_down(u2, off); }
    if (lane == 0) { part[wave][c] = u1; part[wave][21 + c] = u2; }
  }
  __syncthreads();
  if (tid < 42) {
    float t = part[0][tid] + part[1][tid] + part[2][tid] + part[3][tid];
    if (tid < 21) atomicAdd(&statSum[tid], t);
    else atomicAdd(&statSq[tid - 21], t);
  }
}

// ------------- pos layer: lrelu + maxpool over k fused (one wave per point)
__global__ __launch_bounds__(64) void pos_apply(const float* __restrict__ x,
                                                const int* __restrict__ idx,
                                                const float* __restrict__ Wf,
                                                const float* __restrict__ Wd,
                                                const float* __restrict__ Wpool,
                                                const float* __restrict__ statMean,
                                                const float* __restrict__ statIstd,
                                                float* __restrict__ h0, int N) {
  __shared__ float wpool[441];
  __shared__ float hbuf[64];
  int tid = threadIdx.x;
  for (int l = tid; l < 441; l += 64) wpool[l] = Wpool[l];
  int b = blockIdx.y, n = blockIdx.x;
  bool act = tid < 63;
  int c = act ? tid / 3 : 0;
  int v = act ? tid - c * 3 : 0;
  const float* xb = x + (size_t)b * 3 * N;
  float c0 = xb[n], c1 = xb[N + n], c2 = xb[2 * (size_t)N + n];
  float wf0 = 0, wf1 = 0, wf2 = 0, wd0 = 0, wd1 = 0, wd2 = 0, mn = 0, is = 1.f;
  if (act) {
    wf0 = Wf[c * 3]; wf1 = Wf[c * 3 + 1]; wf2 = Wf[c * 3 + 2];
    wd0 = Wd[c * 3]; wd1 = Wd[c * 3 + 1]; wd2 = Wd[c * 3 + 2];
    mn = statMean[c]; is = statIstd[c];
  }
  __syncthreads();
  float best = -3.4e38f, bh = 0.f;
  const int* idxRow = idx + ((size_t)b * N + n) * 20;
  for (int kk = 0; kk < 20; ++kk) {
    int j = idxRow[kk];
    float a0 = xb[j], a1 = xb[N + j], a2 = xb[2 * (size_t)N + j];
    float av  = (v == 0) ? a0 : ((v == 1) ? a1 : a2);
    float cv  = (v == 0) ? c0 : ((v == 1) ? c1 : c2);
    float a1v = (v == 0) ? a1 : ((v == 1) ? a2 : a0);
    float a2v = (v == 0) ? a2 : ((v == 1) ? a0 : a1);
    float c1v = (v == 0) ? c1 : ((v == 1) ? c2 : c0);
    float c2v = (v == 0) ? c2 : ((v == 1) ? c0 : c1);
    float e0 = av - cv;                 // neighbor - center
    float e1 = cv;                      // center
    float e2 = a1v * c2v - a2v * c1v;   // cross(nb, center)[v]
    float p = wf0 * e0 + wf1 * e1 + wf2 * e2;
    float d = wd0 * e0 + wd1 * e1 + wd2 * e2;
    int base = c * 3;
    float pp = p * p;
    float n2 = __shfl(pp, base) + __shfl(pp, base + 1) + __shfl(pp, base + 2);
    float nr = sqrtf(n2) + 1e-6f;
    float sc = ((nr - mn) * is) / nr;
    float pb = p * sc;
    float pd2 = pb * d, dd = d * d;
    float dot = __shfl(pd2, base) + __shfl(pd2, base + 1) + __shfl(pd2, base + 2);
    float dsq = __shfl(dd, base) + __shfl(dd, base + 1) + __shfl(dd, base + 2);
    float h = (dot >= 0.f) ? pb : pb - (dot / (dsq + 1e-6f)) * d;
    hbuf[tid] = act ? h : 0.f;
    __syncthreads();
    float d2 = 0.f;
    #pragma unroll 7
    for (int cc = 0; cc < 21; ++cc) d2 += wpool[c * 21 + cc] * hbuf[cc * 3 + v];
    float hd = h * d2;
    float dotp = __shfl(hd, base) + __shfl(hd, base + 1) + __shfl(hd, base + 2);
    if (act && dotp > best) { best = dotp; bh = h; }   // strict >: first max = argmax
    __syncthreads();
  }
  if (act) h0[(((size_t)b * 21 + c) * 3 + v) * N + n] = bh;
}

// -------------------------------------------------------- fp32 VN "GEMM"
// (16*CPT)co x 64n tile, CPT co per thread, single-buffered LDS.
// MODE 4: d=Wf.X; key=argmax_n <X[co],d>; per-(b,co,ntile) partial keys
// MODE 5: P = Wf.X -> write Y fp32 + stats
// MODE 6: D = Wf.X; read P from Y, bn+lrelu, write in place
template<int MODE, int CPT, typename TX, typename TY>
__global__ __launch_bounds__(256) void gemm_vn(
    const float* __restrict__ Wf,
    const TX* __restrict__ X, TY* __restrict__ Y,
    float* __restrict__ statSum, float* __restrict__ statSq,
    const float* __restrict__ statMean, const float* __restrict__ statIstd,
    unsigned long long* __restrict__ poolPart,
    int Cin, int Cout, int wstride, int N) {
  __shared__ float Xs[16][3][64];
  __shared__ float Wfs[16 * CPT][17];
  const int tid = threadIdx.x;
  const int tx = tid & 15, ty = tid >> 4;
  const int b = blockIdx.z;
  const int n0 = blockIdx.x * 64;
  const int co0 = blockIdx.y * (16 * CPT);
  const TX* Xb = X + (size_t)b * Cin * 3 * N;

  float4 acc[CPT][3];
  #pragma unroll
  for (int c = 0; c < CPT; ++c)
    #pragma unroll
    for (int v = 0; v < 3; ++v) acc[c][v] = {0.f, 0.f, 0.f, 0.f};

  for (int k0 = 0; k0 < Cin; k0 += 16) {
    #pragma unroll
    for (int l0 = 0; l0 < 12; ++l0) {
      int l = l0 * 256 + tid;
      int n = l & 63, v = (l >> 6) % 3, kk = l / 192;
      int ci = k0 + kk;
      Xs[kk][v][n] = (ci < Cin) ? ldg(Xb, ((size_t)ci * 3 + v) * N + n0 + n) : 0.f;
    }
    {
      int kk = tid & 15, coL = tid >> 4, ci = k0 + kk;
      #pragma unroll
      for (int c = 0; c < CPT; ++c) {
        int co = co0 + coL + 16 * c;
        bool ok = (co < Cout) && (ci < Cin);
        Wfs[coL + 16 * c][kk] = ok ? Wf[(size_t)co * wstride + ci] : 0.f;
      }
    }
    __syncthreads();
    #pragma unroll
    for (int kk = 0; kk < 16; ++kk) {
      float4 x0 = *(const float4*)&Xs[kk][0][tx * 4];
      float4 x1 = *(const float4*)&Xs[kk][1][tx * 4];
      float4 x2 = *(const float4*)&Xs[kk][2][tx * 4];
      #pragma unroll
      for (int c = 0; c < CPT; ++c) {
        float w = Wfs[ty + 16 * c][kk];
        FMA4(acc[c][0], w, x0); FMA4(acc[c][1], w, x1); FMA4(acc[c][2], w, x2);
      }
    }
    __syncthreads();
  }

  #pragma unroll
  for (int c = 0; c < CPT; ++c) {
    int co = co0 + ty + 16 * c;
    float p_[3][4];
    #pragma unroll
    for (int v = 0; v < 3; ++v) {
      const float* av = (const float*)&acc[c][v];
      p_[v][0] = av[0]; p_[v][1] = av[1]; p_[v][2] = av[2]; p_[v][3] = av[3];
    }
    if constexpr (MODE == 4) {
      unsigned long long key = 0;
      if (co < Cout) {
        size_t xb2 = ((size_t)co * 3) * N + n0 + tx * 4;
        #pragma unroll
        for (int j = 0; j < 4; ++j) {
          float X0 = ldg(Xb, xb2 + j);
          float X1 = ldg(Xb, xb2 + N + j);
          float X2 = ldg(Xb, xb2 + 2 * (size_t)N + j);
          float dot = X0*p_[0][j] + X1*p_[1][j] + X2*p_[2][j];
          unsigned long long k2 = packKey(dot, n0 + tx * 4 + j);
          if (k2 > key) key = k2;
        }
      }
      #pragma unroll
      for (int off = 8; off; off >>= 1) {
        unsigned long long o = __shfl_down(key, off);
        if (o > key) key = o;
      }
      if (tx == 0 && co < Cout) poolPart[((size_t)b * Cout + co) * 64 + blockIdx.x] = key;
    } else if constexpr (MODE == 5) {
      float s1 = 0.f, s2 = 0.f;
      if (co < Cout) {
        size_t yb = ((size_t)b * Cout + co) * 3 * N + n0 + tx * 4;
        #pragma unroll
        for (int j = 0; j < 4; ++j) {
          float nr = sqrtf(p_[0][j]*p_[0][j] + p_[1][j]*p_[1][j] + p_[2][j]*p_[2][j]) + 1e-6f;
          s1 += nr; s2 += nr * nr;
        }
        st4(Y, yb,                 p_[0][0], p_[0][1], p_[0][2], p_[0][3]);
        st4(Y, yb + N,             p_[1][0], p_[1][1], p_[1][2], p_[1][3]);
        st4(Y, yb + 2 * (size_t)N, p_[2][0], p_[2][1], p_[2][2], p_[2][3]);
      }
      #pragma unroll
      for (int off = 8; off; off >>= 1) { s1 += __shfl_down(s1, off); s2 += __shfl_down(s2, off); }
      if (tx == 0 && co < Cout) { atomicAdd(&statSum[co], s1); atomicAdd(&statSq[co], s2); }
    } else if constexpr (MODE == 6) {
      if (co < Cout) {
        float mn = statMean[co], is = statIstd[co];
        size_t yb = ((size_t)b * Cout + co) * 3 * N + n0 + tx * 4;
        float4 P0 = *(const float4*)&Y[yb];
        float4 P1 = *(const float4*)&Y[yb + N];
        float4 P2 = *(const float4*)&Y[yb + 2 * (size_t)N];
        float pr[3][4] = {{P0.x,P0.y,P0.z,P0.w},{P1.x,P1.y,P1.z,P1.w},{P2.x,P2.y,P2.z,P2.w}};
        float o_[3][4];
        #pragma unroll
        for (int j = 0; j < 4; ++j) {
          float q0 = pr[0][j], q1 = pr[1][j], q2 = pr[2][j];
          float e0 = p_[0][j], e1 = p_[1][j], e2 = p_[2][j];
          float nr = sqrtf(q0*q0 + q1*q1 + q2*q2) + 1e-6f;
          float sc = ((nr - mn) * is) / nr;
          q0 *= sc; q1 *= sc; q2 *= sc;
          float dot = q0*e0 + q1*e1 + q2*e2;
          if (dot < 0.f) {
            float dsq = e0*e0 + e1*e1 + e2*e2;
            float t = dot / (dsq + 1e-6f);
            q0 -= t*e0; q1 -= t*e1; q2 -= t*e2;
          }
          o_[0][j] = q0; o_[1][j] = q1; o_[2][j] = q2;
        }
        st4(Y, yb,                 o_[0][0], o_[0][1], o_[0][2], o_[0][3]);
        st4(Y, yb + N,             o_[1][0], o_[1][1], o_[1][2], o_[1][3]);
        st4(Y, yb + 2 * (size_t)N, o_[2][0], o_[2][1], o_[2][2], o_[2][3]);
      }
    }
  }
}

// ------------------------------------- transposed-layout MFMA bf16 VN GEMM
// Tensors: Xt/P are [b][3][N][Cpad] bf16, channels zero-padded.
// MODE 0: Z = W.X -> fp32 standard layout (z0)
// MODE 1: P = W.X (+biasP) -> write P bf16 (incl. zero pad) + per-co stats
// MODE 2: D = W.X (+biasD); read P, bn+lrelu, write in place
template<int MODE, int NS>
__global__ __launch_bounds__(256) void mfma2(
    const u16* __restrict__ W, const u16* __restrict__ Xt,
    u16* __restrict__ P, float* __restrict__ Zout,
    const float* __restrict__ biasP, const float* __restrict__ biasD,
    float* __restrict__ statSum, float* __restrict__ statSq,
    const float* __restrict__ statMean, const float* __restrict__ statIstd,
    int Cout, int Cpad, int Kpad, int N) {
  const int tid = threadIdx.x, lane = tid & 63, w = tid >> 6;
  const int quad = lane >> 4, l16 = lane & 15;
  const int b = blockIdx.z, n0 = blockIdx.x * 64, co0 = blockIdx.y * 64;
  const int n = n0 + w * 16 + l16;
  const u16* Xb = Xt + (size_t)b * 3 * N * Kpad;
  f32x4 acc[NS][3];
  #pragma unroll
  for (int s = 0; s < NS; ++s)
    #pragma unroll
    for (int v = 0; v < 3; ++v) acc[s][v] = {0.f, 0.f, 0.f, 0.f};

  for (int k0 = 0; k0 < Kpad; k0 += 32) {
    bh8 bx[3];
    #pragma unroll
    for (int v = 0; v < 3; ++v)
      bx[v] = *(const bh8*)(Xb + ((size_t)v * N + n) * Kpad + k0 + quad * 8);
    #pragma unroll
    for (int s = 0; s < NS; ++s) {
      bh8 a = *(const bh8*)(W + (size_t)(co0 + s * 16 + l16) * Kpad + k0 + quad * 8);
      #pragma unroll
      for (int v = 0; v < 3; ++v)
        acc[s][v] = __builtin_amdgcn_mfma_f32_16x16x32_bf16(a, bx[v], acc[s][v], 0, 0, 0);
    }
  }

  u16* Pb = P + (size_t)b * 3 * N * Cpad;
  #pragma unroll
  for (int s = 0; s < NS; ++s) {
    int cb = co0 + s * 16 + quad * 4;
    if constexpr (MODE == 0) {
      #pragma unroll
      for (int r = 0; r < 4; ++r) {
        int co = cb + r;
        if (co < Cout) {
          size_t zb = (((size_t)b * Cout + co) * 3) * N + n;
          Zout[zb] = acc[s][0][r];
          Zout[zb + N] = acc[s][1][r];
          Zout[zb + 2 * (size_t)N] = acc[s][2][r];
        }
      }
    } else if constexpr (MODE == 1) {
      if (cb < Cpad) {
        float q[3][4];
        #pragma unroll
        for (int r = 0; r < 4; ++r) {
          int co = cb + r;
          float b0 = 0, b1 = 0, b2 = 0;
          if (biasP != nullptr && co < Cout) {
            size_t bi = ((size_t)b * Cout + co) * 3;
            b0 = biasP[bi]; b1 = biasP[bi + 1]; b2 = biasP[bi + 2];
          }
          float q0 = acc[s][0][r] + b0, q1 = acc[s][1][r] + b1, q2 = acc[s][2][r] + b2;
          if (co >= Cout) { q0 = 0.f; q1 = 0.f; q2 = 0.f; }
          q[0][r] = q0; q[1][r] = q1; q[2][r] = q2;
          float nr = sqrtf(q0*q0 + q1*q1 + q2*q2) + 1e-6f;
          float s1 = nr, s2 = nr * nr;
          #pragma unroll
          for (int off = 1; off < 16; off <<= 1) { s1 += __shfl_xor(s1, off); s2 += __shfl_xor(s2, off); }
          if (l16 == 0 && co < Cout) { atomicAdd(&statSum[co], s1); atomicAdd(&statSq[co], s2); }
        }
        #pragma unroll
        for (int v = 0; v < 3; ++v) {
          u16 ob[4];
          ob[0] = f2b(q[v][0]); ob[1] = f2b(q[v][1]); ob[2] = f2b(q[v][2]); ob[3] = f2b(q[v][3]);
          *(ushort4*)(Pb + ((size_t)v * N + n) * Cpad + cb) = *(ushort4*)ob;
        }
      }
    } else {  // MODE 2
      if (cb < Cpad) {
        u16 pa[3][4];
        #pragma unroll
        for (int v = 0; v < 3; ++v)
          *(ushort4*)pa[v] = *(const ushort4*)(Pb + ((size_t)v * N + n) * Cpad + cb);
        float o[3][4];
        #pragma unroll
        for (int r = 0; r < 4; ++r) {
          int co = cb + r;
          float r0 = 0.f, r1 = 0.f, r2 = 0.f;
          if (co < Cout) {
            float p0 = b2f(pa[0][r]), p1 = b2f(pa[1][r]), p2 = b2f(pa[2][r]);
            float d0 = acc[s][0][r], d1 = acc[s][1][r], d2 = acc[s][2][r];
            if (biasD != nullptr) {
              size_t bi = ((size_t)b * Cout + co) * 3;
              d0 += biasD[bi]; d1 += biasD[bi + 1]; d2 += biasD[bi + 2];
            }
            float mn = statMean[co], is = statIstd[co];
            float nr = sqrtf(p0*p0 + p1*p1 + p2*p2) + 1e-6f;
            float sc = ((nr - mn) * is) / nr;
            float q0 = p0 * sc, q1 = p1 * sc, q2 = p2 * sc;
            float dot = q0*d0 + q1*d1 + q2*d2;
            if (dot < 0.f) {
              float dsq = d0*d0 + d1*d1 + d2*d2;
              float t = dot / (dsq + 1e-6f);
              q0 -= t*d0; q1 -= t*d1; q2 -= t*d2;
            }
            r0 = q0; r1 = q1; r2 = q2;
          }
          o[0][r] = r0; o[1][r] = r1; o[2][r] = r2;
        }
        #pragma unroll
        for (int v = 0; v < 3; ++v) {
          u16 ob[4];
          ob[0] = f2b(o[v][0]); ob[1] = f2b(o[v][1]); ob[2] = f2b(o[v][2]); ob[3] = f2b(o[v][3]);
          *(ushort4*)(Pb + ((size_t)v * N + n) * Cpad + cb) = *(ushort4*)ob;
        }
      }
    }
  }
}

// weight fp32 -> padded bf16 [CoutPad x Kpad]
__global__ void w_to_bf16(const float* __restrict__ W, u16* __restrict__ Wp,
                          int Cout, int Cin, int wstride, int CoutPad, int Kpad) {
  int t = blockIdx.x * 256 + threadIdx.x;
  if (t >= CoutPad * Kpad) return;
  int co = t / Kpad, ci = t - co * Kpad;
  Wp[t] = (co < Cout && ci < Cin) ? f2b(W[(size_t)co * wstride + ci]) : (u16)0;
}

// ----------------------------------------------------------- small kernels
__global__ void zero_kernel(float* p, int n) {
  int t = blockIdx.x * 256 + threadIdx.x;
  if (t < n) p[t] = 0.f;
}

// computes mean/istd AND re-zeroes sum/sq (512 wide) for the next layer
__global__ void finalize_kernel(float* __restrict__ sum, float* __restrict__ sq,
                                float* __restrict__ mean, float* __restrict__ istd,
                                int C, float invCount) {
  int c = blockIdx.x * 256 + threadIdx.x;
  if (c < C) {
    float m = sum[c] * invCount;
    float v = sq[c] * invCount - m * m;
    if (v < 0.f) v = 0.f;
    mean[c] = m;
    istd[c] = 1.f / sqrtf(v + 1e-5f);
  }
  if (c < 512) { sum[c] = 0.f; sq[c] = 0.f; }
}

__global__ __launch_bounds__(64) void pool_reduce(const unsigned long long* __restrict__ part,
                                                  const float* __restrict__ s3,
                                                  float* __restrict__ pooled, int N) {
  int co = blockIdx.x, b = blockIdx.y, lane = threadIdx.x;
  unsigned long long key = part[((size_t)b * 341 + co) * 64 + lane];
  #pragma unroll
  for (int off = 32; off; off >>= 1) {
    unsigned long long o = __shfl_down(key, off);
    if (o > key) key = o;
  }
  if (lane == 0) {
    int n = (int)(0xFFFFFFFFu - (unsigned)(key & 0xFFFFFFFFull));
    size_t base = ((size_t)b * 341 + co) * 3;
    pooled[base + 0] = s3[(base + 0) * N + n];
    pooled[base + 1] = s3[(base + 1) * N + n];
    pooled[base + 2] = s3[(base + 2) * N + n];
  }
}

// vn_lrelu on (B,Cin,3) tiny tensors (bn stats over batch axis only)
__global__ __launch_bounds__(64) void stf_lrelu(const float* __restrict__ Wf,
                                                const float* __restrict__ Wd,
                                                const float* __restrict__ X,
                                                float* __restrict__ Y, int Cin, int Cout) {
  __shared__ float P[24], D[24], NORM[8], SC[8], DOT[8], DSQ[8], MS[2];
  int co = blockIdx.x, tid = threadIdx.x;
  if (tid < 48) {
    int l = tid < 24 ? tid : tid - 24;
    int b = l / 3, v = l - b * 3;
    const float* W = (tid < 24 ? Wf : Wd) + (size_t)co * Cin;
    const float* xb = X + ((size_t)b * Cin) * 3 + v;
    float acc = 0.f;
    for (int ci = 0; ci < Cin; ++ci) acc += W[ci] * xb[ci * 3];
    if (tid < 24) P[l] = acc; else D[l] = acc;
  }
  __syncthreads();
  if (tid < 8) NORM[tid] = sqrtf(P[tid*3]*P[tid*3] + P[tid*3+1]*P[tid*3+1] + P[tid*3+2]*P[tid*3+2]) + 1e-6f;
  __syncthreads();
  if (tid == 0) {
    float m = 0.f;
    for (int b2 = 0; b2 < 8; ++b2) m += NORM[b2];
    m *= 0.125f;
    float var = 0.f;
    for (int b2 = 0; b2 < 8; ++b2) { float dd = NORM[b2] - m; var += dd * dd; }
    var *= 0.125f;
    MS[0] = m; MS[1] = 1.f / sqrtf(var + 1e-5f);
  }
  __syncthreads();
  if (tid < 8) {
    float sc = ((NORM[tid] - MS[0]) * MS[1]) / NORM[tid];
    float dot = 0.f, dsq = 0.f;
    for (int v = 0; v < 3; ++v) {
      float pb = P[tid*3+v] * sc; float dv = D[tid*3+v];
      dot += pb * dv; dsq += dv * dv;
    }
    SC[tid] = sc; DOT[tid] = dot; DSQ[tid] = dsq;
  }
  __syncthreads();
  if (tid < 24) {
    int b = tid / 3;
    float pb = P[tid] * SC[b];
    float o = (DOT[b] >= 0.f) ? pb : pb - (DOT[b] / (DSQ[b] + 1e-6f)) * D[tid];
    Y[((size_t)b * Cout + co) * 3 + (tid - b * 3)] = o;
  }
}

__global__ void vnlin_small(const float* __restrict__ W, const float* __restrict__ X,
                            float* __restrict__ Y, int Cin, int Cout) {
  int t = blockIdx.x * 256 + threadIdx.x;   // over 8*Cout*3
  if (t >= 8 * Cout * 3) return;
  int v = t % 3, r = t / 3;
  int co = r % Cout, b = r / Cout;
  float acc = 0.f;
  for (int ci = 0; ci < Cin; ++ci) acc += W[(size_t)co * Cin + ci] * X[((size_t)b * Cin + ci) * 3 + v];
  Y[t] = acc;
}

// concat [h1 ; broadcast sfin ; zero-pad] -> transposed bf16 [b][v][n][64]
__global__ __launch_bounds__(256) void concat_tt(const float* __restrict__ h1,
                                                 const float* __restrict__ sfin,
                                                 u16* __restrict__ s2bb, int N) {
  __shared__ u16 tile[64][66];
  int b = blockIdx.z, v = blockIdx.y, n0 = blockIdx.x * 64;
  int tn = threadIdx.x & 63, tc = threadIdx.x >> 6;   // tc in [0,4)
  for (int c = tc; c < 64; c += 4) {
    u16 val = 0;
    if (c < 21) val = f2b(h1[(((size_t)b * 21 + c) * 3 + v) * N + n0 + tn]);
    else if (c < 42) val = f2b(sfin[((size_t)b * 21 + (c - 21)) * 3 + v]);
    tile[c][tn] = val;
  }
  __syncthreads();
  u16* dst = s2bb + (((size_t)b * 3 + v) * N + n0) * 64;
  for (int n = tc; n < 64; n += 4)
    dst[(size_t)n * 64 + tn] = tile[tn][n];
}

// in-place bn on transposed H + accumulate per-(c,v) sums for h_mean
__global__ __launch_bounds__(384) void bn_apply_mean(u16* __restrict__ H,
    const float* __restrict__ sMean, const float* __restrict__ sIstd,
    float* __restrict__ HmAcc, int N) {
  int c = threadIdx.x;
  if (c >= 341) return;
  int b = blockIdx.y, nt = blockIdx.x;
  float mn = sMean[c], is = sIstd[c];
  float a0 = 0.f, a1 = 0.f, a2 = 0.f;
  size_t base = (size_t)b * 3 * N * 352;
  for (int n = nt * 64; n < nt * 64 + 64; ++n) {
    size_t i0 = base + ((size_t)0 * N + n) * 352 + c;
    size_t i1 = base + ((size_t)1 * N + n) * 352 + c;
    size_t i2 = base + ((size_t)2 * N + n) * 352 + c;
    float p0 = b2f(H[i0]), p1 = b2f(H[i1]), p2 = b2f(H[i2]);
    float nr = sqrtf(p0*p0 + p1*p1 + p2*p2) + 1e-6f;
    float sc = ((nr - mn) * is) / nr;
    p0 *= sc; p1 *= sc; p2 *= sc;
    H[i0] = f2b(p0); H[i1] = f2b(p1); H[i2] = f2b(p2);
    a0 += p0; a1 += p1; a2 += p2;
  }
  size_t hb = ((size_t)b * 341 + c) * 3;
  atomicAdd(&HmAcc[hb], a0); atomicAdd(&HmAcc[hb + 1], a1); atomicAdd(&HmAcc[hb + 2], a2);
}

__global__ void hm_finalize(float* Hm, float invN) {
  int t = blockIdx.x * 256 + threadIdx.x;
  if (t < 8 * 341 * 3) Hm[t] *= invN;
}

// bias terms for std1: W[:,341:682] . h_mean   (n-invariant half of concat)
__global__ void bias_kernel(const float* __restrict__ Wf, const float* __restrict__ Wd,
                            const float* __restrict__ Hm,
                            float* __restrict__ biasP, float* __restrict__ biasD) {
  int t = blockIdx.x * 256 + threadIdx.x;   // over 8*341*3
  if (t >= 8 * 341 * 3) return;
  int v = t % 3, r = t / 3;
  int co = r % 341, b = r / 341;
  const float* hm = Hm + (size_t)b * 1023 + v;
  float ap = 0.f, ad = 0.f;
  for (int j = 0; j < 341; ++j) {
    float h = hm[j * 3];
    ap += Wf[(size_t)co * 682 + 341 + j] * h;
    ad += Wd[(size_t)co * 682 + 341 + j] * h;
  }
  biasP[t] = ap; biasD[t] = ad;
}

// h_std einsum + partial max over an n-chunk; rows >=341 use h_mean.
// part layout: [((b*682+i)*3+v)*NT + nt]
__global__ __launch_bounds__(256) void final_max_part(const u16* __restrict__ H,
    const float* __restrict__ Hm, const float* __restrict__ z0,
    float* __restrict__ part, int N, int NT) {
  __shared__ float red[3][4][64];
  int b = blockIdx.z, nt = blockIdx.y;
  int il = threadIdx.x & 63, nsub = threadIdx.x >> 6;
  int i = blockIdx.x * 64 + il;
  bool valid = i < 682, lo = i < 341;
  float c0 = 0, c1 = 0, c2 = 0;
  if (valid && !lo) {
    size_t hb = ((size_t)b * 341 + (i - 341)) * 3;
    c0 = Hm[hb]; c1 = Hm[hb + 1]; c2 = Hm[hb + 2];
  }
  const float* zb = z0 + (size_t)b * 9 * N;
  const u16* Hb = H + (size_t)b * 3 * N * 352;
  float m0 = -3.4e38f, m1 = -3.4e38f, m2 = -3.4e38f;
  int ii = lo ? i : 0;
  int chunk = N / NT, nBeg = nt * chunk;
  for (int n = nBeg + nsub; n < nBeg + chunk; n += 4) {
    float a0, a1, a2;
    if (lo) {
      a0 = b2f(Hb[((size_t)0 * N + n) * 352 + ii]);
      a1 = b2f(Hb[((size_t)1 * N + n) * 352 + ii]);
      a2 = b2f(Hb[((size_t)2 * N + n) * 352 + ii]);
    } else { a0 = c0; a1 = c1; a2 = c2; }
    float s0 = a0 * zb[n]                + a1 * zb[3 * (size_t)N + n] + a2 * zb[6 * (size_t)N + n];
    float s1 = a0 * zb[N + n]            + a1 * zb[4 * (size_t)N + n] + a2 * zb[7 * (size_t)N + n];
    float s2 = a0 * zb[2 * (size_t)N + n]+ a1 * zb[5 * (size_t)N + n] + a2 * zb[8 * (size_t)N + n];
    m0 = fmaxf(m0, s0); m1 = fmaxf(m1, s1); m2 = fmaxf(m2, s2);
  }
  red[0][nsub][il] = m0; red[1][nsub][il] = m1; red[2][nsub][il] = m2;
  __syncthreads();
  if (nsub == 0 && valid) {
    for (int q = 1; q < 4; ++q) {
      m0 = fmaxf(m0, red[0][q][il]); m1 = fmaxf(m1, red[1][q][il]); m2 = fmaxf(m2, red[2][q][il]);
    }
    size_t pb = ((size_t)b * 682 + i) * 3;
    part[(pb + 0) * NT + nt] = m0;
    part[(pb + 1) * NT + nt] = m1;
    part[(pb + 2) * NT + nt] = m2;
  }
}

__global__ void final_max_reduce(const float* __restrict__ part,
                                 float* __restrict__ out, int NT) {
  int t = blockIdx.x * 256 + threadIdx.x;   // over 8*682*3
  if (t >= 8 * 682 * 3) return;
  const float* p = part + (size_t)t * NT;
  float m = p[0];
  for (int k = 1; k < NT; ++k) m = fmaxf(m, p[k]);
  // t = (b*682 + i)*3 + v ; out index = b*2046 + i*3 + v  (same thing)
  out[t] = m;
}

// ------------------------------------------------------------------- host
extern "C" void kernel_launch(void* const* d_in, const int* in_sizes, int n_in,
                              void* d_out, int out_size, void* d_ws, size_t ws_size,
                              hipStream_t stream) {
  (void)in_sizes; (void)n_in; (void)out_size; (void)ws_size;
  const float* x       = (const float*)d_in[0];
  const float* pos_Wf  = (const float*)d_in[1];
  const float* pos_Wd  = (const float*)d_in[2];
  const float* pool_Wd = (const float*)d_in[3];
  const float* c1_Wf   = (const float*)d_in[4];
  const float* c1_Wd   = (const float*)d_in[5];
  const float* st1_Wf  = (const float*)d_in[6];
  const float* st1_Wd  = (const float*)d_in[7];
  const float* st2_Wf  = (const float*)d_in[8];
  const float* st2_Wd  = (const float*)d_in[9];
  const float* st3_Wf  = (const float*)d_in[10];
  const float* st3_Wd  = (const float*)d_in[11];
  const float* stp_Wd  = (const float*)d_in[12];
  const float* stf1_Wf = (const float*)d_in[13];
  const float* stf1_Wd = (const float*)d_in[14];
  const float* stf2_Wf = (const float*)d_in[15];
  const float* stf2_Wd = (const float*)d_in[16];
  const float* stf3_W  = (const float*)d_in[17];
  const float* c2_Wf   = (const float*)d_in[18];
  const float* c2_Wd   = (const float*)d_in[19];
  const float* c3_W    = (const float*)d_in[20];
  const float* std1_Wf = (const float*)d_in[21];
  const float* std1_Wd = (const float*)d_in[22];
  const float* std2_Wf = (const float*)d_in[23];
  const float* std2_Wd = (const float*)d_in[24];
  const float* stdlin  = (const float*)d_in[25];

  float* outv  = (float*)d_out;           // fp32: [8*2046] ++ z0 [8*3*3*4096]
  float* z0out = outv + 8 * 2046;

  const int N = 4096;
  const int NT = 32;                       // final_max n-tiles
  char* ws = (char*)d_ws;
  size_t off = 0;
  auto alloc = [&](size_t bytes) -> char* {
    char* p = ws + off;
    off += (bytes + 255) & ~(size_t)255;
    return p;
  };
  float* stats = (float*)alloc(2048 * sizeof(float));
  float* sSum = stats, *sSq = stats + 512, *sMean = stats + 1024, *sIstd = stats + 1536;
  int* idx = (int*)alloc((size_t)8 * N * 20 * 4);
  unsigned long long* poolPart = (unsigned long long*)alloc((size_t)8 * 341 * 64 * 8);
  float* fmPart = (float*)alloc((size_t)8 * 682 * 3 * NT * 4);
  float* pooled = (float*)alloc(8 * 341 * 3 * 4);
  float* stf1o  = (float*)alloc(8 * 170 * 3 * 4);
  float* stf2o  = (float*)alloc(8 * 85 * 3 * 4);
  float* sfin   = (float*)alloc(8 * 21 * 3 * 4);
  float* Hm     = (float*)alloc(8 * 1023 * 4);
  float* biasP  = (float*)alloc(8 * 341 * 3 * 4);
  float* biasD  = (float*)alloc(8 * 341 * 3 * 4);
  const size_t E21 = (size_t)8 * 21 * 3 * N, E42 = (size_t)8 * 42 * 3 * N;
  const size_t E341 = (size_t)8 * 341 * 3 * N;
  const size_t T352 = (size_t)8 * 3 * N * 352 * 2;
  const size_t T192 = (size_t)8 * 3 * N * 192 * 2;
  const size_t T64  = (size_t)8 * 3 * N * 64 * 2;
  char* regionA = alloc(T352);
  char* regionB = alloc(E341 * 4);
  float* h0  = (float*)regionA;
  float* h1  = h0 + E21;
  float* s1b = h0 + 2 * E21;
  float* s2b = h0 + 3 * E21;                  // st2 out (fp32), st3 input
  float* st3o = (float*)regionB;              // st3 P then in-place out (fp32, argmax-exact)
  u16* Hbuf  = (u16*)regionB;                 // c3 out ^T, live until final_max
  u16* Pstd2 = (u16*)(regionB + T352);        // std2 P / out ^T
  u16* s2bb  = (u16*)(regionB + T352 + T192); // concat out ^T (Cpad 64)
  u16* h2b   = (u16*)(regionB + T352 + T192 + T64); // c2 P / out ^T
  u16* Pstd1 = (u16*)regionA;                 // std1 P / out ^T (early stack dead)
  // padded bf16 weights in poolPart (dead after pool_reduce); sizes in u16
  u16* W1fp = (u16*)poolPart;                 // 384x352
  u16* W1dp = W1fp + 384 * 352;
  u16* W2fp = W1dp + 384 * 352;               // 192x352
  u16* W2dp = W2fp + 192 * 352;
  u16* Wc3p = W2dp + 192 * 352;               // 384x64
  u16* Wc2f = Wc3p + 384 * 64;                // 64x64
  u16* Wc2d = Wc2f + 64 * 64;
  u16* Wzp  = Wc2d + 64 * 64;                 // 16x192

  dim3 blk256(256), blk64(64);
  // fp32 lrelu layer: MODE5 (P+stats) -> finalize -> MODE6 (D + apply in place)
  auto run_lrelu32 = [&](const float* Wf, const float* Wd, const float* X, float* Y,
                         int Cin, int Cout, int wstride, float invCnt) {
    dim3 grid(64, (Cout + 31) / 32, 8);
    gemm_vn<5, 2><<<grid, blk256, 0, stream>>>(Wf, X, Y, sSum, sSq,
                                               nullptr, nullptr, nullptr, Cin, Cout, wstride, N);
    finalize_kernel<<<dim3(2), blk256, 0, stream>>>(sSum, sSq, sMean, sIstd, Cout, invCnt);
    gemm_vn<6, 2><<<grid, blk256, 0, stream>>>(Wd, X, Y, nullptr, nullptr,
                                               sMean, sIstd, nullptr, Cin, Cout, wstride, N);
  };
  const float invBN = 1.f / (8.f * N);
  // bf16 mfma lrelu layer (transposed tensors)
  auto run_mfma = [&](const u16* Wf, const u16* Wd, const u16* X, u16* P,
                      const float* bP, const float* bD,
                      int Cout, int Cpad, int Kpad, int coTiles) {
    dim3 grid(64, coTiles, 8);
    mfma2<1, 4><<<grid, blk256, 0, stream>>>(Wf, X, P, nullptr, bP, nullptr,
                                             sSum, sSq, nullptr, nullptr, Cout, Cpad, Kpad, N);
    finalize_kernel<<<dim3(2), blk256, 0, stream>>>(sSum, sSq, sMean, sIstd, Cout, invBN);
    mfma2<2, 4><<<grid, blk256, 0, stream>>>(Wd, X, P, nullptr, nullptr, bD,
                                             nullptr, nullptr, sMean, sIstd, Cout, Cpad, Kpad, N);
  };

  // 0. zero stats once; thereafter finalize_kernel self-zeroes for next layer
  zero_kernel<<<dim3(4), blk256, 0, stream>>>(stats, 1024);
  // 1. KNN (one wave per point)
  knn_kernel<<<dim3(N / 4, 8), blk256, 0, stream>>>(x, idx, N);
  // 2. pos layer
  pos_stats<<<dim3(N * 20 / 256, 8), blk256, 0, stream>>>(x, idx, pos_Wf, sSum, sSq, N);
  finalize_kernel<<<dim3(2), blk256, 0, stream>>>(sSum, sSq, sMean, sIstd, 21, 1.f / (8.f * N * 20.f));
  pos_apply<<<dim3(N, 8), blk64, 0, stream>>>(x, idx, pos_Wf, pos_Wd, pool_Wd, sMean, sIstd, h0, N);

  // 3. early fp32 chain (argmax-exact path)
  run_lrelu32(c1_Wf, c1_Wd, h0, h1, 21, 21, 21, invBN);
  run_lrelu32(st1_Wf, st1_Wd, h1, s1b, 21, 21, 21, invBN);
  run_lrelu32(st2_Wf, st2_Wd, s1b, s2b, 21, 42, 21, invBN);
  run_lrelu32(st3_Wf, st3_Wd, s2b, st3o, 42, 341, 42, invBN);

  // 4. st_pool over N (fp32-exact argmax), CPT=4 -> 64-co tiles
  gemm_vn<4, 4><<<dim3(64, 6, 8), blk256, 0, stream>>>(stp_Wd, st3o, (float*)nullptr,
                                                       nullptr, nullptr, nullptr, nullptr,
                                                       poolPart, 341, 341, 341, N);
  pool_reduce<<<dim3(341, 8), blk64, 0, stream>>>(poolPart, st3o, pooled, N);

  // 5. weights -> padded bf16 (poolPart now dead)
  w_to_bf16<<<dim3((384 * 352 + 255) / 256), blk256, 0, stream>>>(std1_Wf, W1fp, 341, 341, 682, 384, 352);
  w_to_bf16<<<dim3((384 * 352 + 255) / 256), blk256, 0, stream>>>(std1_Wd, W1dp, 341, 341, 682, 384, 352);
  w_to_bf16<<<dim3((192 * 352 + 255) / 256), blk256, 0, stream>>>(std2_Wf, W2fp, 170, 341, 341, 192, 352);
  w_to_bf16<<<dim3((192 * 352 + 255) / 256), blk256, 0, stream>>>(std2_Wd, W2dp, 170, 341, 341, 192, 352);
  w_to_bf16<<<dim3((384 * 64 + 255) / 256), blk256, 0, stream>>>(c3_W, Wc3p, 341, 42, 42, 384, 64);
  w_to_bf16<<<dim3((64 * 64 + 255) / 256), blk256, 0, stream>>>(c2_Wf, Wc2f, 42, 42, 42, 64, 64);
  w_to_bf16<<<dim3((64 * 64 + 255) / 256), blk256, 0, stream>>>(c2_Wd, Wc2d, 42, 42, 42, 64, 64);
  w_to_bf16<<<dim3((16 * 192 + 255) / 256), blk256, 0, stream>>>(stdlin, Wzp, 3, 170, 170, 16, 192);

  // 6. stf chain (tiny)
  stf_lrelu<<<dim3(170), blk64, 0, stream>>>(stf1_Wf, stf1_Wd, pooled, stf1o, 341, 170);
  stf_lrelu<<<dim3(85),  blk64, 0, stream>>>(stf2_Wf, stf2_Wd, stf1o, stf2o, 170, 85);
  vnlin_small<<<dim3(2), blk256, 0, stream>>>(stf3_W, stf2o, sfin, 85, 21);

  // 7. concat -> transposed bf16 (LDS-tiled); c2 (mfma)
  concat_tt<<<dim3(N / 64, 3, 8), blk256, 0, stream>>>(h1, sfin, s2bb, N);
  run_mfma(Wc2f, Wc2d, s2bb, h2b, nullptr, nullptr, 42, 64, 64, 1);

  // 8. c3 + bn (mfma P+stats, then fused bn-apply + h_mean)
  {
    dim3 grid(64, 6, 8);
    mfma2<1, 4><<<grid, blk256, 0, stream>>>(Wc3p, h2b, Hbuf, nullptr, nullptr, nullptr,
                                             sSum, sSq, nullptr, nullptr, 341, 352, 64, N);
  }
  finalize_kernel<<<dim3(2), blk256, 0, stream>>>(sSum, sSq, sMean, sIstd, 341, invBN);
  zero_kernel<<<dim3(32), blk256, 0, stream>>>(Hm, 8 * 1023);
  bn_apply_mean<<<dim3(64, 8), dim3(384), 0, stream>>>(Hbuf, sMean, sIstd, Hm, N);
  hm_finalize<<<dim3(32), blk256, 0, stream>>>(Hm, 1.f / (float)N);
  bias_kernel<<<dim3(32), blk256, 0, stream>>>(std1_Wf, std1_Wd, Hm, biasP, biasD);

  // 9. VNStdFeature (mfma)
  run_mfma(W1fp, W1dp, Hbuf, Pstd1, biasP, biasD, 341, 352, 352, 6);
  run_mfma(W2fp, W2dp, Pstd1, Pstd2, nullptr, nullptr, 170, 192, 352, 3);

  // 10. z0 (mfma MODE0, fp32 out) + n-tiled einsum/max + reduce
  mfma2<0, 1><<<dim3(64, 1, 8), blk256, 0, stream>>>(Wzp, Pstd2, nullptr, z0out,
                                                     nullptr, nullptr, nullptr, nullptr,
                                                     nullptr, nullptr, 3, 16, 192, N);
  final_max_part<<<dim3(11, NT, 8), blk256, 0, stream>>>(Hbuf, Hm, z0out, fmPart, N, NT);
  final_max_reduce<<<dim3((8 * 682 * 3 + 255) / 256), blk256, 0, stream>>>(fmPart, outv, NT);
}

// Round 12
// 2690.280 us; speedup vs baseline: 1.4493x; 1.0763x over previous
//
#include <hip/hip_runtime.h>
#include <cstdint>
#include <cstddef>

// VN-PointNet encoder. Inputs fp32, outputs fp32 (out 8x2046 ++ z0 8x3x3x4096).
// Early chain (pos..st3) fp32 single-buffered LDS GEMM; st_pool fp32 with
// async-dbuf (global_load_lds) over channel-padded st3o [b][352][3][N].
// Post-pool chain (c2,c3,std1,std2,z0) on bf16 MFMA, k-major transposed
// [b][v][n][Cpad]. KNN: one wave/point register top-8. final_max n-tiled.
// Standard (B,C,3,N) layout: flat ((b*C+c)*3+v)*N + n.

typedef unsigned short u16;
using bh8  = __attribute__((ext_vector_type(8))) short;
using f32x4 = __attribute__((ext_vector_type(4))) float;

__device__ __forceinline__ float b2f(u16 v) {
  return __uint_as_float(((unsigned)v) << 16);
}
__device__ __forceinline__ u16 f2b(float f) {
  unsigned u = __float_as_uint(f);
  u += 0x7FFFu + ((u >> 16) & 1u);   // round-to-nearest-even
  return (u16)(u >> 16);
}

__device__ __forceinline__ float ldg(const float* p, size_t i) { return p[i]; }
__device__ __forceinline__ float ldg(const u16* p, size_t i) { return b2f(p[i]); }
__device__ __forceinline__ void st4(float* p, size_t i, float a, float b, float c, float d) {
  float4 v; v.x = a; v.y = b; v.z = c; v.w = d; *(float4*)(p + i) = v;
}

#define FMA4(A, S, V) { A.x += (S)*(V).x; A.y += (S)*(V).y; A.z += (S)*(V).z; A.w += (S)*(V).w; }

__device__ __forceinline__ unsigned long long packKey(float v, int n) {
  unsigned u = __float_as_uint(v);
  u = (u & 0x80000000u) ? ~u : (u | 0x80000000u);   // total-order float
  return ((unsigned long long)u << 32) | (unsigned long long)(0xFFFFFFFFu - (unsigned)n);
}

// ------------------------------------------- KNN top-20: one wave per point
#define CSWAP(T) { if (c > T) { unsigned long long tmp = T; T = c; c = tmp; } }
__global__ __launch_bounds__(256) void knn_kernel(const float* __restrict__ x,
                                                  int* __restrict__ idxOut, int N) {
  int b = blockIdx.y;
  int wv = threadIdx.x >> 6, lane = threadIdx.x & 63;
  int i = blockIdx.x * 4 + wv;
  const float* xb = x + (size_t)b * 3 * N;
  float xi0 = xb[i], xi1 = xb[N + i], xi2 = xb[2 * (size_t)N + i];
  float xxi = xi0 * xi0 + xi1 * xi1 + xi2 * xi2;
  unsigned long long t0 = 0, t1 = 0, t2 = 0, t3 = 0, t4 = 0, t5 = 0, t6 = 0, t7 = 0;
  #pragma unroll 8
  for (int s = 0; s < 64; ++s) {
    int j = s * 64 + lane;
    float a0 = xb[j], a1 = xb[N + j], a2 = xb[2 * (size_t)N + j];
    float inner = xi0 * a0 + xi1 * a1 + xi2 * a2;
    float xxj = a0 * a0 + a1 * a1 + a2 * a2;
    float pd = 2.f * inner - xxi - xxj;          // = -||xi-xj||^2
    unsigned long long c = packKey(pd, j);
    if (c > t7) { CSWAP(t0) CSWAP(t1) CSWAP(t2) CSWAP(t3) CSWAP(t4) CSWAP(t5) CSWAP(t6) CSWAP(t7) }
  }
  int* row = idxOut + ((size_t)b * N + i) * 20;
  for (int kk = 0; kk < 20; ++kk) {
    unsigned long long k = t0;
    #pragma unroll
    for (int off = 1; off < 64; off <<= 1) {
      unsigned long long o = __shfl_xor(k, off);
      if (o > k) k = o;
    }
    if (lane == 0) row[kk] = (int)(0xFFFFFFFFu - (unsigned)(k & 0xFFFFFFFFull));
    if (k == t0) { t0 = t1; t1 = t2; t2 = t3; t3 = t4; t4 = t5; t5 = t6; t6 = t7; t7 = 0; }
  }
}
#undef CSWAP

// ------------------------------------------------- pos layer: bn statistics
__global__ __launch_bounds__(256) void pos_stats(const float* __restrict__ x,
                                                 const int* __restrict__ idx,
                                                 const float* __restrict__ Wf,
                                                 float* __restrict__ statSum,
                                                 float* __restrict__ statSq, int N) {
  __shared__ float wf[64];
  __shared__ float part[4][42];
  int tid = threadIdx.x;
  if (tid < 63) wf[tid] = Wf[tid];
  __syncthreads();
  int b = blockIdx.y;
  int lin = blockIdx.x * 256 + tid;           // over N*20 exactly
  int n = lin / 20, kk = lin - n * 20;
  const float* xb = x + (size_t)b * 3 * N;
  int j = idx[((size_t)b * N + n) * 20 + kk];
  float c0 = xb[n], c1 = xb[N + n], c2 = xb[2 * (size_t)N + n];
  float a0 = xb[j], a1 = xb[N + j], a2 = xb[2 * (size_t)N + j];
  float e00 = a0 - c0, e01 = a1 - c1, e02 = a2 - c2;
  float e20 = a1 * c2 - a2 * c1, e21 = a2 * c0 - a0 * c2, e22 = a0 * c1 - a1 * c0;
  int lane = tid & 63, wave = tid >> 6;
  #pragma unroll
  for (int c = 0; c < 21; ++c) {
    float w0 = wf[c * 3], w1 = wf[c * 3 + 1], w2 = wf[c * 3 + 2];
    float p0 = w0 * e00 + w1 * c0 + w2 * e20;
    float p1 = w0 * e01 + w1 * c1 + w2 * e21;
    float p2 = w0 * e02 + w1 * c2 + w2 * e22;
    float nr = sqrtf(p0 * p0 + p1 * p1 + p2 * p2) + 1e-6f;
    float u1 = nr, u2 = nr * nr;
    #pragma unroll
    for (int off = 32; off; off >>= 1) { u1 += __shfl_down(u1, off); u2 += __shfl_down(u2, off); }
    if (lane == 0) { part[wave][c] = u1; part[wave][21 + c] = u2; }
  }
  __syncthreads();
  if (tid < 42) {
    float t = part[0][tid] + part[1][tid] + part[2][tid] + part[3][tid];
    if (tid < 21) atomicAdd(&statSum[tid], t);
    else atomicAdd(&statSq[tid - 21], t);
  }
}

// ------------- pos layer: lrelu + maxpool over k fused (one wave per point)
__global__ __launch_bounds__(64) void pos_apply(const float* __restrict__ x,
                                                const int* __restrict__ idx,
                                                const float* __restrict__ Wf,
                                                const float* __restrict__ Wd,
                                                const float* __restrict__ Wpool,
                                                const float* __restrict__ statMean,
                                                const float* __restrict__ statIstd,
                                                float* __restrict__ h0, int N) {
  __shared__ float wpool[441];
  __shared__ float hbuf[64];
  int tid = threadIdx.x;
  for (int l = tid; l < 441; l += 64) wpool[l] = Wpool[l];
  int b = blockIdx.y, n = blockIdx.x;
  bool act = tid < 63;
  int c = act ? tid / 3 : 0;
  int v = act ? tid - c * 3 : 0;
  const float* xb = x + (size_t)b * 3 * N;
  float c0 = xb[n], c1 = xb[N + n], c2 = xb[2 * (size_t)N + n];
  float wf0 = 0, wf1 = 0, wf2 = 0, wd0 = 0, wd1 = 0, wd2 = 0, mn = 0, is = 1.f;
  if (act) {
    wf0 = Wf[c * 3]; wf1 = Wf[c * 3 + 1]; wf2 = Wf[c * 3 + 2];
    wd0 = Wd[c * 3]; wd1 = Wd[c * 3 + 1]; wd2 = Wd[c * 3 + 2];
    mn = statMean[c]; is = statIstd[c];
  }
  __syncthreads();
  float best = -3.4e38f, bh = 0.f;
  const int* idxRow = idx + ((size_t)b * N + n) * 20;
  for (int kk = 0; kk < 20; ++kk) {
    int j = idxRow[kk];
    float a0 = xb[j], a1 = xb[N + j], a2 = xb[2 * (size_t)N + j];
    float av  = (v == 0) ? a0 : ((v == 1) ? a1 : a2);
    float cv  = (v == 0) ? c0 : ((v == 1) ? c1 : c2);
    float a1v = (v == 0) ? a1 : ((v == 1) ? a2 : a0);
    float a2v = (v == 0) ? a2 : ((v == 1) ? a0 : a1);
    float c1v = (v == 0) ? c1 : ((v == 1) ? c2 : c0);
    float c2v = (v == 0) ? c2 : ((v == 1) ? c0 : c1);
    float e0 = av - cv;                 // neighbor - center
    float e1 = cv;                      // center
    float e2 = a1v * c2v - a2v * c1v;   // cross(nb, center)[v]
    float p = wf0 * e0 + wf1 * e1 + wf2 * e2;
    float d = wd0 * e0 + wd1 * e1 + wd2 * e2;
    int base = c * 3;
    float pp = p * p;
    float n2 = __shfl(pp, base) + __shfl(pp, base + 1) + __shfl(pp, base + 2);
    float nr = sqrtf(n2) + 1e-6f;
    float sc = ((nr - mn) * is) / nr;
    float pb = p * sc;
    float pd2 = pb * d, dd = d * d;
    float dot = __shfl(pd2, base) + __shfl(pd2, base + 1) + __shfl(pd2, base + 2);
    float dsq = __shfl(dd, base) + __shfl(dd, base + 1) + __shfl(dd, base + 2);
    float h = (dot >= 0.f) ? pb : pb - (dot / (dsq + 1e-6f)) * d;
    hbuf[tid] = act ? h : 0.f;
    __syncthreads();
    float d2 = 0.f;
    #pragma unroll 7
    for (int cc = 0; cc < 21; ++cc) d2 += wpool[c * 21 + cc] * hbuf[cc * 3 + v];
    float hd = h * d2;
    float dotp = __shfl(hd, base) + __shfl(hd, base + 1) + __shfl(hd, base + 2);
    if (act && dotp > best) { best = dotp; bh = h; }   // strict >: first max = argmax
    __syncthreads();
  }
  if (act) h0[(((size_t)b * 21 + c) * 3 + v) * N + n] = bh;
}

// -------------------------------------------------------- fp32 VN "GEMM"
// (16*CPT)co x 64n tile, CPT co per thread, single-buffered LDS.
// MODE 5: P = Wf.X -> write Y fp32 (CoutStride rows) + stats
// MODE 6: D = Wf.X; read P from Y, bn+lrelu, write in place
template<int MODE, int CPT, typename TX, typename TY>
__global__ __launch_bounds__(256) void gemm_vn(
    const float* __restrict__ Wf,
    const TX* __restrict__ X, TY* __restrict__ Y,
    float* __restrict__ statSum, float* __restrict__ statSq,
    const float* __restrict__ statMean, const float* __restrict__ statIstd,
    int Cin, int Cout, int CoutStride, int wstride, int N) {
  __shared__ float Xs[16][3][64];
  __shared__ float Wfs[16 * CPT][17];
  const int tid = threadIdx.x;
  const int tx = tid & 15, ty = tid >> 4;
  const int b = blockIdx.z;
  const int n0 = blockIdx.x * 64;
  const int co0 = blockIdx.y * (16 * CPT);
  const TX* Xb = X + (size_t)b * Cin * 3 * N;

  float4 acc[CPT][3];
  #pragma unroll
  for (int c = 0; c < CPT; ++c)
    #pragma unroll
    for (int v = 0; v < 3; ++v) acc[c][v] = {0.f, 0.f, 0.f, 0.f};

  for (int k0 = 0; k0 < Cin; k0 += 16) {
    #pragma unroll
    for (int l0 = 0; l0 < 12; ++l0) {
      int l = l0 * 256 + tid;
      int n = l & 63, v = (l >> 6) % 3, kk = l / 192;
      int ci = k0 + kk;
      Xs[kk][v][n] = (ci < Cin) ? ldg(Xb, ((size_t)ci * 3 + v) * N + n0 + n) : 0.f;
    }
    {
      int kk = tid & 15, coL = tid >> 4, ci = k0 + kk;
      #pragma unroll
      for (int c = 0; c < CPT; ++c) {
        int co = co0 + coL + 16 * c;
        bool ok = (co < Cout) && (ci < Cin);
        Wfs[coL + 16 * c][kk] = ok ? Wf[(size_t)co * wstride + ci] : 0.f;
      }
    }
    __syncthreads();
    #pragma unroll
    for (int kk = 0; kk < 16; ++kk) {
      float4 x0 = *(const float4*)&Xs[kk][0][tx * 4];
      float4 x1 = *(const float4*)&Xs[kk][1][tx * 4];
      float4 x2 = *(const float4*)&Xs[kk][2][tx * 4];
      #pragma unroll
      for (int c = 0; c < CPT; ++c) {
        float w = Wfs[ty + 16 * c][kk];
        FMA4(acc[c][0], w, x0); FMA4(acc[c][1], w, x1); FMA4(acc[c][2], w, x2);
      }
    }
    __syncthreads();
  }

  #pragma unroll
  for (int c = 0; c < CPT; ++c) {
    int co = co0 + ty + 16 * c;
    float p_[3][4];
    #pragma unroll
    for (int v = 0; v < 3; ++v) {
      const float* av = (const float*)&acc[c][v];
      p_[v][0] = av[0]; p_[v][1] = av[1]; p_[v][2] = av[2]; p_[v][3] = av[3];
    }
    if constexpr (MODE == 5) {
      float s1 = 0.f, s2 = 0.f;
      if (co < Cout) {
        size_t yb = ((size_t)b * CoutStride + co) * 3 * N + n0 + tx * 4;
        #pragma unroll
        for (int j = 0; j < 4; ++j) {
          float nr = sqrtf(p_[0][j]*p_[0][j] + p_[1][j]*p_[1][j] + p_[2][j]*p_[2][j]) + 1e-6f;
          s1 += nr; s2 += nr * nr;
        }
        st4(Y, yb,                 p_[0][0], p_[0][1], p_[0][2], p_[0][3]);
        st4(Y, yb + N,             p_[1][0], p_[1][1], p_[1][2], p_[1][3]);
        st4(Y, yb + 2 * (size_t)N, p_[2][0], p_[2][1], p_[2][2], p_[2][3]);
      }
      #pragma unroll
      for (int off = 8; off; off >>= 1) { s1 += __shfl_down(s1, off); s2 += __shfl_down(s2, off); }
      if (tx == 0 && co < Cout) { atomicAdd(&statSum[co], s1); atomicAdd(&statSq[co], s2); }
    } else if constexpr (MODE == 6) {
      if (co < Cout) {
        float mn = statMean[co], is = statIstd[co];
        size_t yb = ((size_t)b * CoutStride + co) * 3 * N + n0 + tx * 4;
        float4 P0 = *(const float4*)&Y[yb];
        float4 P1 = *(const float4*)&Y[yb + N];
        float4 P2 = *(const float4*)&Y[yb + 2 * (size_t)N];
        float pr[3][4] = {{P0.x,P0.y,P0.z,P0.w},{P1.x,P1.y,P1.z,P1.w},{P2.x,P2.y,P2.z,P2.w}};
        float o_[3][4];
        #pragma unroll
        for (int j = 0; j < 4; ++j) {
          float q0 = pr[0][j], q1 = pr[1][j], q2 = pr[2][j];
          float e0 = p_[0][j], e1 = p_[1][j], e2 = p_[2][j];
          float nr = sqrtf(q0*q0 + q1*q1 + q2*q2) + 1e-6f;
          float sc = ((nr - mn) * is) / nr;
          q0 *= sc; q1 *= sc; q2 *= sc;
          float dot = q0*e0 + q1*e1 + q2*e2;
          if (dot < 0.f) {
            float dsq = e0*e0 + e1*e1 + e2*e2;
            float t = dot / (dsq + 1e-6f);
            q0 -= t*e0; q1 -= t*e1; q2 -= t*e2;
          }
          o_[0][j] = q0; o_[1][j] = q1; o_[2][j] = q2;
        }
        st4(Y, yb,                 o_[0][0], o_[0][1], o_[0][2], o_[0][3]);
        st4(Y, yb + N,             o_[1][0], o_[1][1], o_[1][2], o_[1][3]);
        st4(Y, yb + 2 * (size_t)N, o_[2][0], o_[2][1], o_[2][2], o_[2][3]);
      }
    }
  }
}

// --------------------------- st_pool GEMM: async-dbuf via global_load_lds
// X padded [b][352][3][N] fp32 (pad channels' W rows are zero -> exact).
// W padded [384][352] fp32 zero-filled. CPT=4 -> 64co x 64n per block.
__global__ __launch_bounds__(256) void gemm_pool_db(
    const float* __restrict__ Wp, const float* __restrict__ Xp,
    unsigned long long* __restrict__ poolPart, int Cout, int N) {
  constexpr int KP = 352, CPT = 4;
  __shared__ float Xs[2][16][3][64];
  __shared__ float Wfs[2][16 * CPT][16];
  const int tid = threadIdx.x;
  const int tx = tid & 15, ty = tid >> 4;
  const int lane = tid & 63, w = tid >> 6;
  const int b = blockIdx.z;
  const int n0 = blockIdx.x * 64;
  const int co0 = blockIdx.y * (16 * CPT);
  const float* Xb = Xp + (size_t)b * KP * 3 * N;

  auto stage = [&](int k0, int buf) {
    #pragma unroll
    for (int l0 = 0; l0 < 12; ++l0) {
      int q = l0 * 4 + w;                 // 0..47 -> (kk, v) unique
      int vv = q % 3, kk = q / 3;
      const float* g = Xb + ((size_t)(k0 + kk) * 3 + vv) * N + n0 + lane;
      __builtin_amdgcn_global_load_lds(
          (const __attribute__((address_space(1))) float*)g,
          (__attribute__((address_space(3))) float*)&Xs[buf][kk][vv][0], 4, 0, 0);
    }
    #pragma unroll
    for (int c = 0; c < CPT; ++c) {
      const float* g = Wp + (size_t)(co0 + w * 4 + (lane >> 4) + 16 * c) * KP + k0 + (lane & 15);
      __builtin_amdgcn_global_load_lds(
          (const __attribute__((address_space(1))) float*)g,
          (__attribute__((address_space(3))) float*)&Wfs[buf][w * 4 + 16 * c][0], 4, 0, 0);
    }
  };

  float4 acc[CPT][3];
  #pragma unroll
  for (int c = 0; c < CPT; ++c)
    #pragma unroll
    for (int v = 0; v < 3; ++v) acc[c][v] = {0.f, 0.f, 0.f, 0.f};

  stage(0, 0);
  __syncthreads();
  constexpr int KT = KP / 16;
  for (int kt = 0; kt < KT; ++kt) {
    int buf = kt & 1;
    if (kt + 1 < KT) stage((kt + 1) * 16, buf ^ 1);
    #pragma unroll
    for (int kk = 0; kk < 16; ++kk) {
      float4 x0 = *(const float4*)&Xs[buf][kk][0][tx * 4];
      float4 x1 = *(const float4*)&Xs[buf][kk][1][tx * 4];
      float4 x2 = *(const float4*)&Xs[buf][kk][2][tx * 4];
      #pragma unroll
      for (int c = 0; c < CPT; ++c) {
        float wv = Wfs[buf][ty + 16 * c][kk];
        FMA4(acc[c][0], wv, x0); FMA4(acc[c][1], wv, x1); FMA4(acc[c][2], wv, x2);
      }
    }
    __syncthreads();   // drains prefetch vmcnt + syncs buffer swap
  }

  #pragma unroll
  for (int c = 0; c < CPT; ++c) {
    int co = co0 + ty + 16 * c;
    unsigned long long key = 0;
    if (co < Cout) {
      const float* av0 = (const float*)&acc[c][0];
      const float* av1 = (const float*)&acc[c][1];
      const float* av2 = (const float*)&acc[c][2];
      size_t xb2 = ((size_t)co * 3) * N + n0 + tx * 4;
      #pragma unroll
      for (int j = 0; j < 4; ++j) {
        float X0 = Xb[xb2 + j];
        float X1 = Xb[xb2 + N + j];
        float X2 = Xb[xb2 + 2 * (size_t)N + j];
        float dot = X0 * av0[j] + X1 * av1[j] + X2 * av2[j];
        unsigned long long k2 = packKey(dot, n0 + tx * 4 + j);
        if (k2 > key) key = k2;
      }
    }
    #pragma unroll
    for (int off = 8; off; off >>= 1) {
      unsigned long long o = __shfl_down(key, off);
      if (o > key) key = o;
    }
    if (tx == 0 && co < Cout) poolPart[((size_t)b * Cout + co) * 64 + blockIdx.x] = key;
  }
}

// ------------------------------------- transposed-layout MFMA bf16 VN GEMM
// Tensors: Xt/P are [b][3][N][Cpad] bf16, channels zero-padded.
// MODE 0: Z = W.X -> fp32 standard layout (z0)
// MODE 1: P = W.X (+biasP) -> write P bf16 (incl. zero pad) + per-co stats
// MODE 2: D = W.X (+biasD); read P, bn+lrelu, write in place
template<int MODE, int NS>
__global__ __launch_bounds__(256) void mfma2(
    const u16* __restrict__ W, const u16* __restrict__ Xt,
    u16* __restrict__ P, float* __restrict__ Zout,
    const float* __restrict__ biasP, const float* __restrict__ biasD,
    float* __restrict__ statSum, float* __restrict__ statSq,
    const float* __restrict__ statMean, const float* __restrict__ statIstd,
    int Cout, int Cpad, int Kpad, int N) {
  const int tid = threadIdx.x, lane = tid & 63, w = tid >> 6;
  const int quad = lane >> 4, l16 = lane & 15;
  const int b = blockIdx.z, n0 = blockIdx.x * 64, co0 = blockIdx.y * 64;
  const int n = n0 + w * 16 + l16;
  const u16* Xb = Xt + (size_t)b * 3 * N * Kpad;
  f32x4 acc[NS][3];
  #pragma unroll
  for (int s = 0; s < NS; ++s)
    #pragma unroll
    for (int v = 0; v < 3; ++v) acc[s][v] = {0.f, 0.f, 0.f, 0.f};

  for (int k0 = 0; k0 < Kpad; k0 += 32) {
    bh8 bx[3];
    #pragma unroll
    for (int v = 0; v < 3; ++v)
      bx[v] = *(const bh8*)(Xb + ((size_t)v * N + n) * Kpad + k0 + quad * 8);
    #pragma unroll
    for (int s = 0; s < NS; ++s) {
      bh8 a = *(const bh8*)(W + (size_t)(co0 + s * 16 + l16) * Kpad + k0 + quad * 8);
      #pragma unroll
      for (int v = 0; v < 3; ++v)
        acc[s][v] = __builtin_amdgcn_mfma_f32_16x16x32_bf16(a, bx[v], acc[s][v], 0, 0, 0);
    }
  }

  u16* Pb = P + (size_t)b * 3 * N * Cpad;
  #pragma unroll
  for (int s = 0; s < NS; ++s) {
    int cb = co0 + s * 16 + quad * 4;
    if constexpr (MODE == 0) {
      #pragma unroll
      for (int r = 0; r < 4; ++r) {
        int co = cb + r;
        if (co < Cout) {
          size_t zb = (((size_t)b * Cout + co) * 3) * N + n;
          Zout[zb] = acc[s][0][r];
          Zout[zb + N] = acc[s][1][r];
          Zout[zb + 2 * (size_t)N] = acc[s][2][r];
        }
      }
    } else if constexpr (MODE == 1) {
      if (cb < Cpad) {
        float q[3][4];
        #pragma unroll
        for (int r = 0; r < 4; ++r) {
          int co = cb + r;
          float b0 = 0, b1 = 0, b2 = 0;
          if (biasP != nullptr && co < Cout) {
            size_t bi = ((size_t)b * Cout + co) * 3;
            b0 = biasP[bi]; b1 = biasP[bi + 1]; b2 = biasP[bi + 2];
          }
          float q0 = acc[s][0][r] + b0, q1 = acc[s][1][r] + b1, q2 = acc[s][2][r] + b2;
          if (co >= Cout) { q0 = 0.f; q1 = 0.f; q2 = 0.f; }
          q[0][r] = q0; q[1][r] = q1; q[2][r] = q2;
          float nr = sqrtf(q0*q0 + q1*q1 + q2*q2) + 1e-6f;
          float s1 = nr, s2 = nr * nr;
          #pragma unroll
          for (int off = 1; off < 16; off <<= 1) { s1 += __shfl_xor(s1, off); s2 += __shfl_xor(s2, off); }
          if (l16 == 0 && co < Cout) { atomicAdd(&statSum[co], s1); atomicAdd(&statSq[co], s2); }
        }
        #pragma unroll
        for (int v = 0; v < 3; ++v) {
          u16 ob[4];
          ob[0] = f2b(q[v][0]); ob[1] = f2b(q[v][1]); ob[2] = f2b(q[v][2]); ob[3] = f2b(q[v][3]);
          *(ushort4*)(Pb + ((size_t)v * N + n) * Cpad + cb) = *(ushort4*)ob;
        }
      }
    } else {  // MODE 2
      if (cb < Cpad) {
        u16 pa[3][4];
        #pragma unroll
        for (int v = 0; v < 3; ++v)
          *(ushort4*)pa[v] = *(const ushort4*)(Pb + ((size_t)v * N + n) * Cpad + cb);
        float o[3][4];
        #pragma unroll
        for (int r = 0; r < 4; ++r) {
          int co = cb + r;
          float r0 = 0.f, r1 = 0.f, r2 = 0.f;
          if (co < Cout) {
            float p0 = b2f(pa[0][r]), p1 = b2f(pa[1][r]), p2 = b2f(pa[2][r]);
            float d0 = acc[s][0][r], d1 = acc[s][1][r], d2 = acc[s][2][r];
            if (biasD != nullptr) {
              size_t bi = ((size_t)b * Cout + co) * 3;
              d0 += biasD[bi]; d1 += biasD[bi + 1]; d2 += biasD[bi + 2];
            }
            float mn = statMean[co], is = statIstd[co];
            float nr = sqrtf(p0*p0 + p1*p1 + p2*p2) + 1e-6f;
            float sc = ((nr - mn) * is) / nr;
            float q0 = p0 * sc, q1 = p1 * sc, q2 = p2 * sc;
            float dot = q0*d0 + q1*d1 + q2*d2;
            if (dot < 0.f) {
              float dsq = d0*d0 + d1*d1 + d2*d2;
              float t = dot / (dsq + 1e-6f);
              q0 -= t*d0; q1 -= t*d1; q2 -= t*d2;
            }
            r0 = q0; r1 = q1; r2 = q2;
          }
          o[0][r] = r0; o[1][r] = r1; o[2][r] = r2;
        }
        #pragma unroll
        for (int v = 0; v < 3; ++v) {
          u16 ob[4];
          ob[0] = f2b(o[v][0]); ob[1] = f2b(o[v][1]); ob[2] = f2b(o[v][2]); ob[3] = f2b(o[v][3]);
          *(ushort4*)(Pb + ((size_t)v * N + n) * Cpad + cb) = *(ushort4*)ob;
        }
      }
    }
  }
}

// weight fp32 -> padded bf16 [CoutPad x Kpad]
__global__ void w_to_bf16(const float* __restrict__ W, u16* __restrict__ Wp,
                          int Cout, int Cin, int wstride, int CoutPad, int Kpad) {
  int t = blockIdx.x * 256 + threadIdx.x;
  if (t >= CoutPad * Kpad) return;
  int co = t / Kpad, ci = t - co * Kpad;
  Wp[t] = (co < Cout && ci < Cin) ? f2b(W[(size_t)co * wstride + ci]) : (u16)0;
}

// weight fp32 -> padded fp32 [CoutPad x Kpad] (zeros beyond)
__global__ void w_to_f32pad(const float* __restrict__ W, float* __restrict__ Wp,
                            int Cout, int Cin, int wstride, int CoutPad, int Kpad) {
  int t = blockIdx.x * 256 + threadIdx.x;
  if (t >= CoutPad * Kpad) return;
  int co = t / Kpad, ci = t - co * Kpad;
  Wp[t] = (co < Cout && ci < Cin) ? W[(size_t)co * wstride + ci] : 0.f;
}

// ----------------------------------------------------------- small kernels
__global__ void zero_kernel(float* p, int n) {
  int t = blockIdx.x * 256 + threadIdx.x;
  if (t < n) p[t] = 0.f;
}

// computes mean/istd AND re-zeroes sum/sq (512 wide) for the next layer
__global__ void finalize_kernel(float* __restrict__ sum, float* __restrict__ sq,
                                float* __restrict__ mean, float* __restrict__ istd,
                                int C, float invCount) {
  int c = blockIdx.x * 256 + threadIdx.x;
  if (c < C) {
    float m = sum[c] * invCount;
    float v = sq[c] * invCount - m * m;
    if (v < 0.f) v = 0.f;
    mean[c] = m;
    istd[c] = 1.f / sqrtf(v + 1e-5f);
  }
  if (c < 512) { sum[c] = 0.f; sq[c] = 0.f; }
}

__global__ __launch_bounds__(64) void pool_reduce(const unsigned long long* __restrict__ part,
                                                  const float* __restrict__ s3,
                                                  float* __restrict__ pooled, int N) {
  int co = blockIdx.x, b = blockIdx.y, lane = threadIdx.x;
  unsigned long long key = part[((size_t)b * 341 + co) * 64 + lane];
  #pragma unroll
  for (int off = 32; off; off >>= 1) {
    unsigned long long o = __shfl_down(key, off);
    if (o > key) key = o;
  }
  if (lane == 0) {
    int n = (int)(0xFFFFFFFFu - (unsigned)(key & 0xFFFFFFFFull));
    size_t base = ((size_t)b * 352 + co) * 3;       // padded channel stride
    size_t obase = ((size_t)b * 341 + co) * 3;
    pooled[obase + 0] = s3[(base + 0) * N + n];
    pooled[obase + 1] = s3[(base + 1) * N + n];
    pooled[obase + 2] = s3[(base + 2) * N + n];
  }
}

// vn_lrelu on (B,Cin,3) tiny tensors (bn stats over batch axis only)
__global__ __launch_bounds__(64) void stf_lrelu(const float* __restrict__ Wf,
                                                const float* __restrict__ Wd,
                                                const float* __restrict__ X,
                                                float* __restrict__ Y, int Cin, int Cout) {
  __shared__ float P[24], D[24], NORM[8], SC[8], DOT[8], DSQ[8], MS[2];
  int co = blockIdx.x, tid = threadIdx.x;
  if (tid < 48) {
    int l = tid < 24 ? tid : tid - 24;
    int b = l / 3, v = l - b * 3;
    const float* W = (tid < 24 ? Wf : Wd) + (size_t)co * Cin;
    const float* xb = X + ((size_t)b * Cin) * 3 + v;
    float acc = 0.f;
    for (int ci = 0; ci < Cin; ++ci) acc += W[ci] * xb[ci * 3];
    if (tid < 24) P[l] = acc; else D[l] = acc;
  }
  __syncthreads();
  if (tid < 8) NORM[tid] = sqrtf(P[tid*3]*P[tid*3] + P[tid*3+1]*P[tid*3+1] + P[tid*3+2]*P[tid*3+2]) + 1e-6f;
  __syncthreads();
  if (tid == 0) {
    float m = 0.f;
    for (int b2 = 0; b2 < 8; ++b2) m += NORM[b2];
    m *= 0.125f;
    float var = 0.f;
    for (int b2 = 0; b2 < 8; ++b2) { float dd = NORM[b2] - m; var += dd * dd; }
    var *= 0.125f;
    MS[0] = m; MS[1] = 1.f / sqrtf(var + 1e-5f);
  }
  __syncthreads();
  if (tid < 8) {
    float sc = ((NORM[tid] - MS[0]) * MS[1]) / NORM[tid];
    float dot = 0.f, dsq = 0.f;
    for (int v = 0; v < 3; ++v) {
      float pb = P[tid*3+v] * sc; float dv = D[tid*3+v];
      dot += pb * dv; dsq += dv * dv;
    }
    SC[tid] = sc; DOT[tid] = dot; DSQ[tid] = dsq;
  }
  __syncthreads();
  if (tid < 24) {
    int b = tid / 3;
    float pb = P[tid] * SC[b];
    float o = (DOT[b] >= 0.f) ? pb : pb - (DOT[b] / (DSQ[b] + 1e-6f)) * D[tid];
    Y[((size_t)b * Cout + co) * 3 + (tid - b * 3)] = o;
  }
}

__global__ void vnlin_small(const float* __restrict__ W, const float* __restrict__ X,
                            float* __restrict__ Y, int Cin, int Cout) {
  int t = blockIdx.x * 256 + threadIdx.x;   // over 8*Cout*3
  if (t >= 8 * Cout * 3) return;
  int v = t % 3, r = t / 3;
  int co = r % Cout, b = r / Cout;
  float acc = 0.f;
  for (int ci = 0; ci < Cin; ++ci) acc += W[(size_t)co * Cin + ci] * X[((size_t)b * Cin + ci) * 3 + v];
  Y[t] = acc;
}

// concat [h1 ; broadcast sfin ; zero-pad] -> transposed bf16 [b][v][n][64]
__global__ __launch_bounds__(256) void concat_tt(const float* __restrict__ h1,
                                                 const float* __restrict__ sfin,
                                                 u16* __restrict__ s2bb, int N) {
  __shared__ u16 tile[64][66];
  int b = blockIdx.z, v = blockIdx.y, n0 = blockIdx.x * 64;
  int tn = threadIdx.x & 63, tc = threadIdx.x >> 6;   // tc in [0,4)
  for (int c = tc; c < 64; c += 4) {
    u16 val = 0;
    if (c < 21) val = f2b(h1[(((size_t)b * 21 + c) * 3 + v) * N + n0 + tn]);
    else if (c < 42) val = f2b(sfin[((size_t)b * 21 + (c - 21)) * 3 + v]);
    tile[c][tn] = val;
  }
  __syncthreads();
  u16* dst = s2bb + (((size_t)b * 3 + v) * N + n0) * 64;
  for (int n = tc; n < 64; n += 4)
    dst[(size_t)n * 64 + tn] = tile[tn][n];
}

// in-place bn on transposed H + accumulate per-(c,v) sums for h_mean
__global__ __launch_bounds__(384) void bn_apply_mean(u16* __restrict__ H,
    const float* __restrict__ sMean, const float* __restrict__ sIstd,
    float* __restrict__ HmAcc, int N) {
  int c = threadIdx.x;
  if (c >= 341) return;
  int b = blockIdx.y, nt = blockIdx.x;
  float mn = sMean[c], is = sIstd[c];
  float a0 = 0.f, a1 = 0.f, a2 = 0.f;
  size_t base = (size_t)b * 3 * N * 352;
  for (int n = nt * 64; n < nt * 64 + 64; ++n) {
    size_t i0 = base + ((size_t)0 * N + n) * 352 + c;
    size_t i1 = base + ((size_t)1 * N + n) * 352 + c;
    size_t i2 = base + ((size_t)2 * N + n) * 352 + c;
    float p0 = b2f(H[i0]), p1 = b2f(H[i1]), p2 = b2f(H[i2]);
    float nr = sqrtf(p0*p0 + p1*p1 + p2*p2) + 1e-6f;
    float sc = ((nr - mn) * is) / nr;
    p0 *= sc; p1 *= sc; p2 *= sc;
    H[i0] = f2b(p0); H[i1] = f2b(p1); H[i2] = f2b(p2);
    a0 += p0; a1 += p1; a2 += p2;
  }
  size_t hb = ((size_t)b * 341 + c) * 3;
  atomicAdd(&HmAcc[hb], a0); atomicAdd(&HmAcc[hb + 1], a1); atomicAdd(&HmAcc[hb + 2], a2);
}

__global__ void hm_finalize(float* Hm, float invN) {
  int t = blockIdx.x * 256 + threadIdx.x;
  if (t < 8 * 341 * 3) Hm[t] *= invN;
}

// bias terms for std1: W[:,341:682] . h_mean   (n-invariant half of concat)
__global__ void bias_kernel(const float* __restrict__ Wf, const float* __restrict__ Wd,
                            const float* __restrict__ Hm,
                            float* __restrict__ biasP, float* __restrict__ biasD) {
  int t = blockIdx.x * 256 + threadIdx.x;   // over 8*341*3
  if (t >= 8 * 341 * 3) return;
  int v = t % 3, r = t / 3;
  int co = r % 341, b = r / 341;
  const float* hm = Hm + (size_t)b * 1023 + v;
  float ap = 0.f, ad = 0.f;
  for (int j = 0; j < 341; ++j) {
    float h = hm[j * 3];
    ap += Wf[(size_t)co * 682 + 341 + j] * h;
    ad += Wd[(size_t)co * 682 + 341 + j] * h;
  }
  biasP[t] = ap; biasD[t] = ad;
}

// h_std einsum + partial max over an n-chunk; rows >=341 use h_mean.
// part layout: [((b*682+i)*3+v)*NT + nt]
__global__ __launch_bounds__(256) void final_max_part(const u16* __restrict__ H,
    const float* __restrict__ Hm, const float* __restrict__ z0,
    float* __restrict__ part, int N, int NT) {
  __shared__ float red[3][4][64];
  int b = blockIdx.z, nt = blockIdx.y;
  int il = threadIdx.x & 63, nsub = threadIdx.x >> 6;
  int i = blockIdx.x * 64 + il;
  bool valid = i < 682, lo = i < 341;
  float c0 = 0, c1 = 0, c2 = 0;
  if (valid && !lo) {
    size_t hb = ((size_t)b * 341 + (i - 341)) * 3;
    c0 = Hm[hb]; c1 = Hm[hb + 1]; c2 = Hm[hb + 2];
  }
  const float* zb = z0 + (size_t)b * 9 * N;
  const u16* Hb = H + (size_t)b * 3 * N * 352;
  float m0 = -3.4e38f, m1 = -3.4e38f, m2 = -3.4e38f;
  int ii = lo ? i : 0;
  int chunk = N / NT, nBeg = nt * chunk;
  for (int n = nBeg + nsub; n < nBeg + chunk; n += 4) {
    float a0, a1, a2;
    if (lo) {
      a0 = b2f(Hb[((size_t)0 * N + n) * 352 + ii]);
      a1 = b2f(Hb[((size_t)1 * N + n) * 352 + ii]);
      a2 = b2f(Hb[((size_t)2 * N + n) * 352 + ii]);
    } else { a0 = c0; a1 = c1; a2 = c2; }
    float s0 = a0 * zb[n]                + a1 * zb[3 * (size_t)N + n] + a2 * zb[6 * (size_t)N + n];
    float s1 = a0 * zb[N + n]            + a1 * zb[4 * (size_t)N + n] + a2 * zb[7 * (size_t)N + n];
    float s2 = a0 * zb[2 * (size_t)N + n]+ a1 * zb[5 * (size_t)N + n] + a2 * zb[8 * (size_t)N + n];
    m0 = fmaxf(m0, s0); m1 = fmaxf(m1, s1); m2 = fmaxf(m2, s2);
  }
  red[0][nsub][il] = m0; red[1][nsub][il] = m1; red[2][nsub][il] = m2;
  __syncthreads();
  if (nsub == 0 && valid) {
    for (int q = 1; q < 4; ++q) {
      m0 = fmaxf(m0, red[0][q][il]); m1 = fmaxf(m1, red[1][q][il]); m2 = fmaxf(m2, red[2][q][il]);
    }
    size_t pb = ((size_t)b * 682 + i) * 3;
    part[(pb + 0) * NT + nt] = m0;
    part[(pb + 1) * NT + nt] = m1;
    part[(pb + 2) * NT + nt] = m2;
  }
}

__global__ void final_max_reduce(const float* __restrict__ part,
                                 float* __restrict__ out, int NT) {
  int t = blockIdx.x * 256 + threadIdx.x;   // over 8*682*3
  if (t >= 8 * 682 * 3) return;
  const float* p = part + (size_t)t * NT;
  float m = p[0];
  for (int k = 1; k < NT; ++k) m = fmaxf(m, p[k]);
  out[t] = m;
}

// ------------------------------------------------------------------- host
extern "C" void kernel_launch(void* const* d_in, const int* in_sizes, int n_in,
                              void* d_out, int out_size, void* d_ws, size_t ws_size,
                              hipStream_t stream) {
  (void)in_sizes; (void)n_in; (void)out_size; (void)ws_size;
  const float* x       = (const float*)d_in[0];
  const float* pos_Wf  = (const float*)d_in[1];
  const float* pos_Wd  = (const float*)d_in[2];
  const float* pool_Wd = (const float*)d_in[3];
  const float* c1_Wf   = (const float*)d_in[4];
  const float* c1_Wd   = (const float*)d_in[5];
  const float* st1_Wf  = (const float*)d_in[6];
  const float* st1_Wd  = (const float*)d_in[7];
  const float* st2_Wf  = (const float*)d_in[8];
  const float* st2_Wd  = (const float*)d_in[9];
  const float* st3_Wf  = (const float*)d_in[10];
  const float* st3_Wd  = (const float*)d_in[11];
  const float* stp_Wd  = (const float*)d_in[12];
  const float* stf1_Wf = (const float*)d_in[13];
  const float* stf1_Wd = (const float*)d_in[14];
  const float* stf2_Wf = (const float*)d_in[15];
  const float* stf2_Wd = (const float*)d_in[16];
  const float* stf3_W  = (const float*)d_in[17];
  const float* c2_Wf   = (const float*)d_in[18];
  const float* c2_Wd   = (const float*)d_in[19];
  const float* c3_W    = (const float*)d_in[20];
  const float* std1_Wf = (const float*)d_in[21];
  const float* std1_Wd = (const float*)d_in[22];
  const float* std2_Wf = (const float*)d_in[23];
  const float* std2_Wd = (const float*)d_in[24];
  const float* stdlin  = (const float*)d_in[25];

  float* outv  = (float*)d_out;           // fp32: [8*2046] ++ z0 [8*3*3*4096]
  float* z0out = outv + 8 * 2046;

  const int N = 4096;
  const int NT = 32;                       // final_max n-tiles
  char* ws = (char*)d_ws;
  size_t off = 0;
  auto alloc = [&](size_t bytes) -> char* {
    char* p = ws + off;
    off += (bytes + 255) & ~(size_t)255;
    return p;
  };
  float* stats = (float*)alloc(2048 * sizeof(float));
  float* sSum = stats, *sSq = stats + 512, *sMean = stats + 1024, *sIstd = stats + 1536;
  int* idx = (int*)alloc((size_t)8 * N * 20 * 4);
  unsigned long long* poolPart = (unsigned long long*)alloc((size_t)8 * 341 * 64 * 8);
  float* fmPart = (float*)alloc((size_t)8 * 682 * 3 * NT * 4);
  float* Wpoolp = (float*)alloc((size_t)384 * 352 * 4);   // padded fp32 stp_Wd
  float* pooled = (float*)alloc(8 * 341 * 3 * 4);
  float* stf1o  = (float*)alloc(8 * 170 * 3 * 4);
  float* stf2o  = (float*)alloc(8 * 85 * 3 * 4);
  float* sfin   = (float*)alloc(8 * 21 * 3 * 4);
  float* Hm     = (float*)alloc(8 * 1023 * 4);
  float* biasP  = (float*)alloc(8 * 341 * 3 * 4);
  float* biasD  = (float*)alloc(8 * 341 * 3 * 4);
  const size_t E21 = (size_t)8 * 21 * 3 * N, E42 = (size_t)8 * 42 * 3 * N;
  const size_t T352 = (size_t)8 * 3 * N * 352 * 2;   // bf16 ^T 352-ch
  const size_t T192 = (size_t)8 * 3 * N * 192 * 2;
  const size_t T64  = (size_t)8 * 3 * N * 64 * 2;
  const size_t F352 = (size_t)8 * 352 * 3 * N * 4;   // fp32 padded st3o
  char* regionA = alloc(T352);
  char* regionB = alloc(F352);                       // 138.4 MB
  float* h0  = (float*)regionA;
  float* h1  = h0 + E21;
  float* s1b = h0 + 2 * E21;
  float* s2b = h0 + 3 * E21;                  // st2 out (fp32), st3 input
  float* st3o = (float*)regionB;              // st3 out, padded [b][352][3][N]
  u16* Hbuf  = (u16*)regionB;                 // c3 out ^T, live until final_max
  u16* Pstd2 = (u16*)(regionB + T352);        // std2 P / out ^T
  u16* s2bb  = (u16*)(regionB + T352 + T192); // concat out ^T (Cpad 64)
  u16* h2b   = (u16*)(regionB + T352 + T192 + T64); // c2 P / out ^T
  u16* Pstd1 = (u16*)regionA;                 // std1 P / out ^T (early stack dead)
  // padded bf16 weights in poolPart (dead after pool_reduce); sizes in u16
  u16* W1fp = (u16*)poolPart;                 // 384x352
  u16* W1dp = W1fp + 384 * 352;
  u16* W2fp = W1dp + 384 * 352;               // 192x352
  u16* W2dp = W2fp + 192 * 352;
  u16* Wc3p = W2dp + 192 * 352;               // 384x64
  u16* Wc2f = Wc3p + 384 * 64;                // 64x64
  u16* Wc2d = Wc2f + 64 * 64;
  u16* Wzp  = Wc2d + 64 * 64;                 // 16x192

  dim3 blk256(256), blk64(64);
  // fp32 lrelu layer: MODE5 (P+stats) -> finalize -> MODE6 (D + apply in place)
  auto run_lrelu32 = [&](const float* Wf, const float* Wd, const float* X, float* Y,
                         int Cin, int Cout, int CoutStride, int wstride, float invCnt) {
    dim3 grid(64, (Cout + 31) / 32, 8);
    gemm_vn<5, 2><<<grid, blk256, 0, stream>>>(Wf, X, Y, sSum, sSq,
                                               nullptr, nullptr, Cin, Cout, CoutStride, wstride, N);
    finalize_kernel<<<dim3(2), blk256, 0, stream>>>(sSum, sSq, sMean, sIstd, Cout, invCnt);
    gemm_vn<6, 2><<<grid, blk256, 0, stream>>>(Wd, X, Y, nullptr, nullptr,
                                               sMean, sIstd, Cin, Cout, CoutStride, wstride, N);
  };
  const float invBN = 1.f / (8.f * N);
  // bf16 mfma lrelu layer (transposed tensors)
  auto run_mfma = [&](const u16* Wf, const u16* Wd, const u16* X, u16* P,
                      const float* bP, const float* bD,
                      int Cout, int Cpad, int Kpad, int coTiles) {
    dim3 grid(64, coTiles, 8);
    mfma2<1, 4><<<grid, blk256, 0, stream>>>(Wf, X, P, nullptr, bP, nullptr,
                                             sSum, sSq, nullptr, nullptr, Cout, Cpad, Kpad, N);
    finalize_kernel<<<dim3(2), blk256, 0, stream>>>(sSum, sSq, sMean, sIstd, Cout, invBN);
    mfma2<2, 4><<<grid, blk256, 0, stream>>>(Wd, X, P, nullptr, nullptr, bD,
                                             nullptr, nullptr, sMean, sIstd, Cout, Cpad, Kpad, N);
  };

  // 0. zero stats once; finalize_kernel self-zeroes thereafter; pad stp_Wd
  zero_kernel<<<dim3(4), blk256, 0, stream>>>(stats, 1024);
  w_to_f32pad<<<dim3((384 * 352 + 255) / 256), blk256, 0, stream>>>(stp_Wd, Wpoolp, 341, 341, 341, 384, 352);
  // 1. KNN (one wave per point)
  knn_kernel<<<dim3(N / 4, 8), blk256, 0, stream>>>(x, idx, N);
  // 2. pos layer
  pos_stats<<<dim3(N * 20 / 256, 8), blk256, 0, stream>>>(x, idx, pos_Wf, sSum, sSq, N);
  finalize_kernel<<<dim3(2), blk256, 0, stream>>>(sSum, sSq, sMean, sIstd, 21, 1.f / (8.f * N * 20.f));
  pos_apply<<<dim3(N, 8), blk64, 0, stream>>>(x, idx, pos_Wf, pos_Wd, pool_Wd, sMean, sIstd, h0, N);

  // 3. early fp32 chain (argmax-exact path)
  run_lrelu32(c1_Wf, c1_Wd, h0, h1, 21, 21, 21, 21, invBN);
  run_lrelu32(st1_Wf, st1_Wd, h1, s1b, 21, 21, 21, 21, invBN);
  run_lrelu32(st2_Wf, st2_Wd, s1b, s2b, 21, 42, 42, 21, invBN);
  run_lrelu32(st3_Wf, st3_Wd, s2b, st3o, 42, 341, 352, 42, invBN);   // padded out

  // 4. st_pool over N (fp32-exact argmax), async-dbuf GEMM
  gemm_pool_db<<<dim3(64, 6, 8), blk256, 0, stream>>>(Wpoolp, st3o, poolPart, 341, N);
  pool_reduce<<<dim3(341, 8), blk64, 0, stream>>>(poolPart, st3o, pooled, N);

  // 5. weights -> padded bf16 (poolPart now dead)
  w_to_bf16<<<dim3((384 * 352 + 255) / 256), blk256, 0, stream>>>(std1_Wf, W1fp, 341, 341, 682, 384, 352);
  w_to_bf16<<<dim3((384 * 352 + 255) / 256), blk256, 0, stream>>>(std1_Wd, W1dp, 341, 341, 682, 384, 352);
  w_to_bf16<<<dim3((192 * 352 + 255) / 256), blk256, 0, stream>>>(std2_Wf, W2fp, 170, 341, 341, 192, 352);
  w_to_bf16<<<dim3((192 * 352 + 255) / 256), blk256, 0, stream>>>(std2_Wd, W2dp, 170, 341, 341, 192, 352);
  w_to_bf16<<<dim3((384 * 64 + 255) / 256), blk256, 0, stream>>>(c3_W, Wc3p, 341, 42, 42, 384, 64);
  w_to_bf16<<<dim3((64 * 64 + 255) / 256), blk256, 0, stream>>>(c2_Wf, Wc2f, 42, 42, 42, 64, 64);
  w_to_bf16<<<dim3((64 * 64 + 255) / 256), blk256, 0, stream>>>(c2_Wd, Wc2d, 42, 42, 42, 64, 64);
  w_to_bf16<<<dim3((16 * 192 + 255) / 256), blk256, 0, stream>>>(stdlin, Wzp, 3, 170, 170, 16, 192);

  // 6. stf chain (tiny)
  stf_lrelu<<<dim3(170), blk64, 0, stream>>>(stf1_Wf, stf1_Wd, pooled, stf1o, 341, 170);
  stf_lrelu<<<dim3(85),  blk64, 0, stream>>>(stf2_Wf, stf2_Wd, stf1o, stf2o, 170, 85);
  vnlin_small<<<dim3(2), blk256, 0, stream>>>(stf3_W, stf2o, sfin, 85, 21);

  // 7. concat -> transposed bf16 (LDS-tiled); c2 (mfma)
  concat_tt<<<dim3(N / 64, 3, 8), blk256, 0, stream>>>(h1, sfin, s2bb, N);
  run_mfma(Wc2f, Wc2d, s2bb, h2b, nullptr, nullptr, 42, 64, 64, 1);

  // 8. c3 + bn (mfma P+stats, then fused bn-apply + h_mean)
  {
    dim3 grid(64, 6, 8);
    mfma2<1, 4><<<grid, blk256, 0, stream>>>(Wc3p, h2b, Hbuf, nullptr, nullptr, nullptr,
                                             sSum, sSq, nullptr, nullptr, 341, 352, 64, N);
  }
  finalize_kernel<<<dim3(2), blk256, 0, stream>>>(sSum, sSq, sMean, sIstd, 341, invBN);
  zero_kernel<<<dim3(32), blk256, 0, stream>>>(Hm, 8 * 1023);
  bn_apply_mean<<<dim3(64, 8), dim3(384), 0, stream>>>(Hbuf, sMean, sIstd, Hm, N);
  hm_finalize<<<dim3(32), blk256, 0, stream>>>(Hm, 1.f / (float)N);
  bias_kernel<<<dim3(32), blk256, 0, stream>>>(std1_Wf, std1_Wd, Hm, biasP, biasD);

  // 9. VNStdFeature (mfma)
  run_mfma(W1fp, W1dp, Hbuf, Pstd1, biasP, biasD, 341, 352, 352, 6);
  run_mfma(W2fp, W2dp, Pstd1, Pstd2, nullptr, nullptr, 170, 192, 352, 3);

  // 10. z0 (mfma MODE0, fp32 out) + n-tiled einsum/max + reduce
  mfma2<0, 1><<<dim3(64, 1, 8), blk256, 0, stream>>>(Wzp, Pstd2, nullptr, z0out,
                                                     nullptr, nullptr, nullptr, nullptr,
                                                     nullptr, nullptr, 3, 16, 192, N);
  final_max_part<<<dim3(11, NT, 8), blk256, 0, stream>>>(Hbuf, Hm, z0out, fmPart, N, NT);
  final_max_reduce<<<dim3((8 * 682 * 3 + 255) / 256), blk256, 0, stream>>>(fmPart, outv, NT);
}

// Round 13
// 2683.755 us; speedup vs baseline: 1.4529x; 1.0024x over previous
//
#include <hip/hip_runtime.h>
#include <cstdint>
#include <cstddef>

// VN-PointNet encoder. Inputs fp32, outputs fp32 (out 8x2046 ++ z0 8x3x3x4096).
// Early chain fp32 with async-dbuf (global_load_lds) GEMMs over channel-padded
// tensors (21->32, 42->48, 341->352); pad channels kept zero by construction.
// st_pool same structure. Post-pool chain (c2,c3,std1,std2,z0) on bf16 MFMA,
// k-major transposed [b][v][n][Cpad]. KNN: one wave/point register top-8.
// final_max n-tiled. Standard (B,C,3,N): flat ((b*C+c)*3+v)*N + n.

typedef unsigned short u16;
using bh8  = __attribute__((ext_vector_type(8))) short;
using f32x4 = __attribute__((ext_vector_type(4))) float;

__device__ __forceinline__ float b2f(u16 v) {
  return __uint_as_float(((unsigned)v) << 16);
}
__device__ __forceinline__ u16 f2b(float f) {
  unsigned u = __float_as_uint(f);
  u += 0x7FFFu + ((u >> 16) & 1u);   // round-to-nearest-even
  return (u16)(u >> 16);
}

__device__ __forceinline__ void st4(float* p, size_t i, float a, float b, float c, float d) {
  float4 v; v.x = a; v.y = b; v.z = c; v.w = d; *(float4*)(p + i) = v;
}

#define FMA4(A, S, V) { A.x += (S)*(V).x; A.y += (S)*(V).y; A.z += (S)*(V).z; A.w += (S)*(V).w; }

__device__ __forceinline__ unsigned long long packKey(float v, int n) {
  unsigned u = __float_as_uint(v);
  u = (u & 0x80000000u) ? ~u : (u | 0x80000000u);   // total-order float
  return ((unsigned long long)u << 32) | (unsigned long long)(0xFFFFFFFFu - (unsigned)n);
}

// ------------------------------------------- KNN top-20: one wave per point
#define CSWAP(T) { if (c > T) { unsigned long long tmp = T; T = c; c = tmp; } }
__global__ __launch_bounds__(256) void knn_kernel(const float* __restrict__ x,
                                                  int* __restrict__ idxOut, int N) {
  int b = blockIdx.y;
  int wv = threadIdx.x >> 6, lane = threadIdx.x & 63;
  int i = blockIdx.x * 4 + wv;
  const float* xb = x + (size_t)b * 3 * N;
  float xi0 = xb[i], xi1 = xb[N + i], xi2 = xb[2 * (size_t)N + i];
  float xxi = xi0 * xi0 + xi1 * xi1 + xi2 * xi2;
  unsigned long long t0 = 0, t1 = 0, t2 = 0, t3 = 0, t4 = 0, t5 = 0, t6 = 0, t7 = 0;
  #pragma unroll 8
  for (int s = 0; s < 64; ++s) {
    int j = s * 64 + lane;
    float a0 = xb[j], a1 = xb[N + j], a2 = xb[2 * (size_t)N + j];
    float inner = xi0 * a0 + xi1 * a1 + xi2 * a2;
    float xxj = a0 * a0 + a1 * a1 + a2 * a2;
    float pd = 2.f * inner - xxi - xxj;          // = -||xi-xj||^2
    unsigned long long c = packKey(pd, j);
    if (c > t7) { CSWAP(t0) CSWAP(t1) CSWAP(t2) CSWAP(t3) CSWAP(t4) CSWAP(t5) CSWAP(t6) CSWAP(t7) }
  }
  int* row = idxOut + ((size_t)b * N + i) * 20;
  for (int kk = 0; kk < 20; ++kk) {
    unsigned long long k = t0;
    #pragma unroll
    for (int off = 1; off < 64; off <<= 1) {
      unsigned long long o = __shfl_xor(k, off);
      if (o > k) k = o;
    }
    if (lane == 0) row[kk] = (int)(0xFFFFFFFFu - (unsigned)(k & 0xFFFFFFFFull));
    if (k == t0) { t0 = t1; t1 = t2; t2 = t3; t3 = t4; t4 = t5; t5 = t6; t6 = t7; t7 = 0; }
  }
}
#undef CSWAP

// ------------------------------------------------- pos layer: bn statistics
__global__ __launch_bounds__(256) void pos_stats(const float* __restrict__ x,
                                                 const int* __restrict__ idx,
                                                 const float* __restrict__ Wf,
                                                 float* __restrict__ statSum,
                                                 float* __restrict__ statSq, int N) {
  __shared__ float wf[64];
  __shared__ float part[4][42];
  int tid = threadIdx.x;
  if (tid < 63) wf[tid] = Wf[tid];
  __syncthreads();
  int b = blockIdx.y;
  int lin = blockIdx.x * 256 + tid;           // over N*20 exactly
  int n = lin / 20, kk = lin - n * 20;
  const float* xb = x + (size_t)b * 3 * N;
  int j = idx[((size_t)b * N + n) * 20 + kk];
  float c0 = xb[n], c1 = xb[N + n], c2 = xb[2 * (size_t)N + n];
  float a0 = xb[j], a1 = xb[N + j], a2 = xb[2 * (size_t)N + j];
  float e00 = a0 - c0, e01 = a1 - c1, e02 = a2 - c2;
  float e20 = a1 * c2 - a2 * c1, e21 = a2 * c0 - a0 * c2, e22 = a0 * c1 - a1 * c0;
  int lane = tid & 63, wave = tid >> 6;
  #pragma unroll
  for (int c = 0; c < 21; ++c) {
    float w0 = wf[c * 3], w1 = wf[c * 3 + 1], w2 = wf[c * 3 + 2];
    float p0 = w0 * e00 + w1 * c0 + w2 * e20;
    float p1 = w0 * e01 + w1 * c1 + w2 * e21;
    float p2 = w0 * e02 + w1 * c2 + w2 * e22;
    float nr = sqrtf(p0 * p0 + p1 * p1 + p2 * p2) + 1e-6f;
    float u1 = nr, u2 = nr * nr;
    #pragma unroll
    for (int off = 32; off; off >>= 1) { u1 += __shfl_down(u1, off); u2 += __shfl_down(u2, off); }
    if (lane == 0) { part[wave][c] = u1; part[wave][21 + c] = u2; }
  }
  __syncthreads();
  if (tid < 42) {
    float t = part[0][tid] + part[1][tid] + part[2][tid] + part[3][tid];
    if (tid < 21) atomicAdd(&statSum[tid], t);
    else atomicAdd(&statSq[tid - 21], t);
  }
}

// ------------- pos layer: lrelu + maxpool over k fused; writes 32ch-padded h0
__global__ __launch_bounds__(64) void pos_apply(const float* __restrict__ x,
                                                const int* __restrict__ idx,
                                                const float* __restrict__ Wf,
                                                const float* __restrict__ Wd,
                                                const float* __restrict__ Wpool,
                                                const float* __restrict__ statMean,
                                                const float* __restrict__ statIstd,
                                                float* __restrict__ h0, int N) {
  __shared__ float wpool[441];
  __shared__ float hbuf[64];
  int tid = threadIdx.x;
  for (int l = tid; l < 441; l += 64) wpool[l] = Wpool[l];
  int b = blockIdx.y, n = blockIdx.x;
  bool act = tid < 63;
  int c = act ? tid / 3 : 0;
  int v = act ? tid - c * 3 : 0;
  const float* xb = x + (size_t)b * 3 * N;
  float c0 = xb[n], c1 = xb[N + n], c2 = xb[2 * (size_t)N + n];
  float wf0 = 0, wf1 = 0, wf2 = 0, wd0 = 0, wd1 = 0, wd2 = 0, mn = 0, is = 1.f;
  if (act) {
    wf0 = Wf[c * 3]; wf1 = Wf[c * 3 + 1]; wf2 = Wf[c * 3 + 2];
    wd0 = Wd[c * 3]; wd1 = Wd[c * 3 + 1]; wd2 = Wd[c * 3 + 2];
    mn = statMean[c]; is = statIstd[c];
  }
  __syncthreads();
  float best = -3.4e38f, bh = 0.f;
  const int* idxRow = idx + ((size_t)b * N + n) * 20;
  for (int kk = 0; kk < 20; ++kk) {
    int j = idxRow[kk];
    float a0 = xb[j], a1 = xb[N + j], a2 = xb[2 * (size_t)N + j];
    float av  = (v == 0) ? a0 : ((v == 1) ? a1 : a2);
    float cv  = (v == 0) ? c0 : ((v == 1) ? c1 : c2);
    float a1v = (v == 0) ? a1 : ((v == 1) ? a2 : a0);
    float a2v = (v == 0) ? a2 : ((v == 1) ? a0 : a1);
    float c1v = (v == 0) ? c1 : ((v == 1) ? c2 : c0);
    float c2v = (v == 0) ? c2 : ((v == 1) ? c0 : c1);
    float e0 = av - cv;                 // neighbor - center
    float e1 = cv;                      // center
    float e2 = a1v * c2v - a2v * c1v;   // cross(nb, center)[v]
    float p = wf0 * e0 + wf1 * e1 + wf2 * e2;
    float d = wd0 * e0 + wd1 * e1 + wd2 * e2;
    int base = c * 3;
    float pp = p * p;
    float n2 = __shfl(pp, base) + __shfl(pp, base + 1) + __shfl(pp, base + 2);
    float nr = sqrtf(n2) + 1e-6f;
    float sc = ((nr - mn) * is) / nr;
    float pb = p * sc;
    float pd2 = pb * d, dd = d * d;
    float dot = __shfl(pd2, base) + __shfl(pd2, base + 1) + __shfl(pd2, base + 2);
    float dsq = __shfl(dd, base) + __shfl(dd, base + 1) + __shfl(dd, base + 2);
    float h = (dot >= 0.f) ? pb : pb - (dot / (dsq + 1e-6f)) * d;
    hbuf[tid] = act ? h : 0.f;
    __syncthreads();
    float d2 = 0.f;
    #pragma unroll 7
    for (int cc = 0; cc < 21; ++cc) d2 += wpool[c * 21 + cc] * hbuf[cc * 3 + v];
    float hd = h * d2;
    float dotp = __shfl(hd, base) + __shfl(hd, base + 1) + __shfl(hd, base + 2);
    if (act && dotp > best) { best = dotp; bh = h; }   // strict >: first max = argmax
    __syncthreads();
  }
  if (act) h0[(((size_t)b * 32 + c) * 3 + v) * N + n] = bh;
}

// zero pad channels [Cfrom,Cpad) of a padded fp32 tensor [b][Cpad][3][N]
__global__ void zero_padch(float* __restrict__ p, int Cfrom, int Cpad, int N) {
  size_t t = (size_t)blockIdx.x * 256 + threadIdx.x;
  size_t per = (size_t)(Cpad - Cfrom) * 3 * N;
  if (t >= 8 * per) return;
  int b = (int)(t / per);
  size_t r = t - (size_t)b * per;
  p[(((size_t)b * Cpad + Cfrom) * 3) * N + r] = 0.f;
}

// ----------------- unified fp32 async-dbuf GEMM over channel-padded tensors
// X [b][Kpad][3][N], Y [b][CpadY][3][N], W [CoutTiles*16*CPT x Kpad] zero-pad.
// MODE 5: P = W.X -> Y + stats(co<Cout). Pad rows store acc (=0).
// MODE 6: D = W.X; read P from Y, bn+lrelu in place; pad rows -> 0.
template<int MODE, int CPT>
__global__ __launch_bounds__(256) void gemm_db(
    const float* __restrict__ Wp, const float* __restrict__ Xp,
    float* __restrict__ Yp,
    float* __restrict__ statSum, float* __restrict__ statSq,
    const float* __restrict__ statMean, const float* __restrict__ statIstd,
    int Cout, int CpadY, int Kpad, int N) {
  __shared__ float Xs[2][16][3][64];
  __shared__ float Wfs[2][16 * CPT][16];
  const int tid = threadIdx.x;
  const int tx = tid & 15, ty = tid >> 4;
  const int lane = tid & 63, w = tid >> 6;
  const int b = blockIdx.z;
  const int n0 = blockIdx.x * 64;
  const int co0 = blockIdx.y * (16 * CPT);
  const float* Xb = Xp + (size_t)b * Kpad * 3 * N;

  auto stage = [&](int k0, int buf) {
    #pragma unroll
    for (int l0 = 0; l0 < 12; ++l0) {
      int q = l0 * 4 + w;                 // 0..47 -> (kk, v)
      int vv = q % 3, kk = q / 3;
      const float* g = Xb + ((size_t)(k0 + kk) * 3 + vv) * N + n0 + lane;
      __builtin_amdgcn_global_load_lds(
          (const __attribute__((address_space(1))) float*)g,
          (__attribute__((address_space(3))) float*)&Xs[buf][kk][vv][0], 4, 0, 0);
    }
    #pragma unroll
    for (int c = 0; c < CPT; ++c) {
      const float* g = Wp + (size_t)(co0 + w * 4 + (lane >> 4) + 16 * c) * Kpad + k0 + (lane & 15);
      __builtin_amdgcn_global_load_lds(
          (const __attribute__((address_space(1))) float*)g,
          (__attribute__((address_space(3))) float*)&Wfs[buf][w * 4 + 16 * c][0], 4, 0, 0);
    }
  };

  float4 acc[CPT][3];
  #pragma unroll
  for (int c = 0; c < CPT; ++c)
    #pragma unroll
    for (int v = 0; v < 3; ++v) acc[c][v] = {0.f, 0.f, 0.f, 0.f};

  stage(0, 0);
  __syncthreads();
  const int KT = Kpad / 16;
  for (int kt = 0; kt < KT; ++kt) {
    int buf = kt & 1;
    if (kt + 1 < KT) stage((kt + 1) * 16, buf ^ 1);
    #pragma unroll
    for (int kk = 0; kk < 16; ++kk) {
      float4 x0 = *(const float4*)&Xs[buf][kk][0][tx * 4];
      float4 x1 = *(const float4*)&Xs[buf][kk][1][tx * 4];
      float4 x2 = *(const float4*)&Xs[buf][kk][2][tx * 4];
      #pragma unroll
      for (int c = 0; c < CPT; ++c) {
        float wv = Wfs[buf][ty + 16 * c][kk];
        FMA4(acc[c][0], wv, x0); FMA4(acc[c][1], wv, x1); FMA4(acc[c][2], wv, x2);
      }
    }
    __syncthreads();
  }

  #pragma unroll
  for (int c = 0; c < CPT; ++c) {
    int co = co0 + ty + 16 * c;
    if (co >= CpadY) continue;
    const float* a0 = (const float*)&acc[c][0];
    const float* a1 = (const float*)&acc[c][1];
    const float* a2 = (const float*)&acc[c][2];
    size_t yb = ((size_t)b * CpadY + co) * 3 * N + n0 + tx * 4;
    if constexpr (MODE == 5) {
      float s1 = 0.f, s2 = 0.f;
      #pragma unroll
      for (int j = 0; j < 4; ++j) {
        float nr = sqrtf(a0[j]*a0[j] + a1[j]*a1[j] + a2[j]*a2[j]) + 1e-6f;
        s1 += nr; s2 += nr * nr;
      }
      st4(Yp, yb,                 a0[0], a0[1], a0[2], a0[3]);
      st4(Yp, yb + N,             a1[0], a1[1], a1[2], a1[3]);
      st4(Yp, yb + 2 * (size_t)N, a2[0], a2[1], a2[2], a2[3]);
      #pragma unroll
      for (int off = 8; off; off >>= 1) { s1 += __shfl_down(s1, off); s2 += __shfl_down(s2, off); }
      if (tx == 0 && co < Cout) { atomicAdd(&statSum[co], s1); atomicAdd(&statSq[co], s2); }
    } else {  // MODE 6
      if (co < Cout) {
        float mn = statMean[co], is = statIstd[co];
        float4 P0 = *(const float4*)&Yp[yb];
        float4 P1 = *(const float4*)&Yp[yb + N];
        float4 P2 = *(const float4*)&Yp[yb + 2 * (size_t)N];
        float pr[3][4] = {{P0.x,P0.y,P0.z,P0.w},{P1.x,P1.y,P1.z,P1.w},{P2.x,P2.y,P2.z,P2.w}};
        float o_[3][4];
        #pragma unroll
        for (int j = 0; j < 4; ++j) {
          float q0 = pr[0][j], q1 = pr[1][j], q2 = pr[2][j];
          float e0 = a0[j], e1 = a1[j], e2 = a2[j];
          float nr = sqrtf(q0*q0 + q1*q1 + q2*q2) + 1e-6f;
          float sc = ((nr - mn) * is) / nr;
          q0 *= sc; q1 *= sc; q2 *= sc;
          float dot = q0*e0 + q1*e1 + q2*e2;
          if (dot < 0.f) {
            float dsq = e0*e0 + e1*e1 + e2*e2;
            float t = dot / (dsq + 1e-6f);
            q0 -= t*e0; q1 -= t*e1; q2 -= t*e2;
          }
          o_[0][j] = q0; o_[1][j] = q1; o_[2][j] = q2;
        }
        st4(Yp, yb,                 o_[0][0], o_[0][1], o_[0][2], o_[0][3]);
        st4(Yp, yb + N,             o_[1][0], o_[1][1], o_[1][2], o_[1][3]);
        st4(Yp, yb + 2 * (size_t)N, o_[2][0], o_[2][1], o_[2][2], o_[2][3]);
      } else {
        st4(Yp, yb, 0.f, 0.f, 0.f, 0.f);
        st4(Yp, yb + N, 0.f, 0.f, 0.f, 0.f);
        st4(Yp, yb + 2 * (size_t)N, 0.f, 0.f, 0.f, 0.f);
      }
    }
  }
}

// --------------------------- st_pool GEMM: async-dbuf via global_load_lds
__global__ __launch_bounds__(256) void gemm_pool_db(
    const float* __restrict__ Wp, const float* __restrict__ Xp,
    unsigned long long* __restrict__ poolPart, int Cout, int N) {
  constexpr int KP = 352, CPT = 4;
  __shared__ float Xs[2][16][3][64];
  __shared__ float Wfs[2][16 * CPT][16];
  const int tid = threadIdx.x;
  const int tx = tid & 15, ty = tid >> 4;
  const int lane = tid & 63, w = tid >> 6;
  const int b = blockIdx.z;
  const int n0 = blockIdx.x * 64;
  const int co0 = blockIdx.y * (16 * CPT);
  const float* Xb = Xp + (size_t)b * KP * 3 * N;

  auto stage = [&](int k0, int buf) {
    #pragma unroll
    for (int l0 = 0; l0 < 12; ++l0) {
      int q = l0 * 4 + w;
      int vv = q % 3, kk = q / 3;
      const float* g = Xb + ((size_t)(k0 + kk) * 3 + vv) * N + n0 + lane;
      __builtin_amdgcn_global_load_lds(
          (const __attribute__((address_space(1))) float*)g,
          (__attribute__((address_space(3))) float*)&Xs[buf][kk][vv][0], 4, 0, 0);
    }
    #pragma unroll
    for (int c = 0; c < CPT; ++c) {
      const float* g = Wp + (size_t)(co0 + w * 4 + (lane >> 4) + 16 * c) * KP + k0 + (lane & 15);
      __builtin_amdgcn_global_load_lds(
          (const __attribute__((address_space(1))) float*)g,
          (__attribute__((address_space(3))) float*)&Wfs[buf][w * 4 + 16 * c][0], 4, 0, 0);
    }
  };

  float4 acc[CPT][3];
  #pragma unroll
  for (int c = 0; c < CPT; ++c)
    #pragma unroll
    for (int v = 0; v < 3; ++v) acc[c][v] = {0.f, 0.f, 0.f, 0.f};

  stage(0, 0);
  __syncthreads();
  constexpr int KT = KP / 16;
  for (int kt = 0; kt < KT; ++kt) {
    int buf = kt & 1;
    if (kt + 1 < KT) stage((kt + 1) * 16, buf ^ 1);
    #pragma unroll
    for (int kk = 0; kk < 16; ++kk) {
      float4 x0 = *(const float4*)&Xs[buf][kk][0][tx * 4];
      float4 x1 = *(const float4*)&Xs[buf][kk][1][tx * 4];
      float4 x2 = *(const float4*)&Xs[buf][kk][2][tx * 4];
      #pragma unroll
      for (int c = 0; c < CPT; ++c) {
        float wv = Wfs[buf][ty + 16 * c][kk];
        FMA4(acc[c][0], wv, x0); FMA4(acc[c][1], wv, x1); FMA4(acc[c][2], wv, x2);
      }
    }
    __syncthreads();
  }

  #pragma unroll
  for (int c = 0; c < CPT; ++c) {
    int co = co0 + ty + 16 * c;
    unsigned long long key = 0;
    if (co < Cout) {
      const float* av0 = (const float*)&acc[c][0];
      const float* av1 = (const float*)&acc[c][1];
      const float* av2 = (const float*)&acc[c][2];
      size_t xb2 = ((size_t)co * 3) * N + n0 + tx * 4;
      #pragma unroll
      for (int j = 0; j < 4; ++j) {
        float X0 = Xb[xb2 + j];
        float X1 = Xb[xb2 + N + j];
        float X2 = Xb[xb2 + 2 * (size_t)N + j];
        float dot = X0 * av0[j] + X1 * av1[j] + X2 * av2[j];
        unsigned long long k2 = packKey(dot, n0 + tx * 4 + j);
        if (k2 > key) key = k2;
      }
    }
    #pragma unroll
    for (int off = 8; off; off >>= 1) {
      unsigned long long o = __shfl_down(key, off);
      if (o > key) key = o;
    }
    if (tx == 0 && co < Cout) poolPart[((size_t)b * Cout + co) * 64 + blockIdx.x] = key;
  }
}

// ------------------------------------- transposed-layout MFMA bf16 VN GEMM
template<int MODE, int NS>
__global__ __launch_bounds__(256) void mfma2(
    const u16* __restrict__ W, const u16* __restrict__ Xt,
    u16* __restrict__ P, float* __restrict__ Zout,
    const float* __restrict__ biasP, const float* __restrict__ biasD,
    float* __restrict__ statSum, float* __restrict__ statSq,
    const float* __restrict__ statMean, const float* __restrict__ statIstd,
    int Cout, int Cpad, int Kpad, int N) {
  const int tid = threadIdx.x, lane = tid & 63, w = tid >> 6;
  const int quad = lane >> 4, l16 = lane & 15;
  const int b = blockIdx.z, n0 = blockIdx.x * 64, co0 = blockIdx.y * 64;
  const int n = n0 + w * 16 + l16;
  const u16* Xb = Xt + (size_t)b * 3 * N * Kpad;
  f32x4 acc[NS][3];
  #pragma unroll
  for (int s = 0; s < NS; ++s)
    #pragma unroll
    for (int v = 0; v < 3; ++v) acc[s][v] = {0.f, 0.f, 0.f, 0.f};

  for (int k0 = 0; k0 < Kpad; k0 += 32) {
    bh8 bx[3];
    #pragma unroll
    for (int v = 0; v < 3; ++v)
      bx[v] = *(const bh8*)(Xb + ((size_t)v * N + n) * Kpad + k0 + quad * 8);
    #pragma unroll
    for (int s = 0; s < NS; ++s) {
      bh8 a = *(const bh8*)(W + (size_t)(co0 + s * 16 + l16) * Kpad + k0 + quad * 8);
      #pragma unroll
      for (int v = 0; v < 3; ++v)
        acc[s][v] = __builtin_amdgcn_mfma_f32_16x16x32_bf16(a, bx[v], acc[s][v], 0, 0, 0);
    }
  }

  u16* Pb = P + (size_t)b * 3 * N * Cpad;
  #pragma unroll
  for (int s = 0; s < NS; ++s) {
    int cb = co0 + s * 16 + quad * 4;
    if constexpr (MODE == 0) {
      #pragma unroll
      for (int r = 0; r < 4; ++r) {
        int co = cb + r;
        if (co < Cout) {
          size_t zb = (((size_t)b * Cout + co) * 3) * N + n;
          Zout[zb] = acc[s][0][r];
          Zout[zb + N] = acc[s][1][r];
          Zout[zb + 2 * (size_t)N] = acc[s][2][r];
        }
      }
    } else if constexpr (MODE == 1) {
      if (cb < Cpad) {
        float q[3][4];
        #pragma unroll
        for (int r = 0; r < 4; ++r) {
          int co = cb + r;
          float b0 = 0, b1 = 0, b2 = 0;
          if (biasP != nullptr && co < Cout) {
            size_t bi = ((size_t)b * Cout + co) * 3;
            b0 = biasP[bi]; b1 = biasP[bi + 1]; b2 = biasP[bi + 2];
          }
          float q0 = acc[s][0][r] + b0, q1 = acc[s][1][r] + b1, q2 = acc[s][2][r] + b2;
          if (co >= Cout) { q0 = 0.f; q1 = 0.f; q2 = 0.f; }
          q[0][r] = q0; q[1][r] = q1; q[2][r] = q2;
          float nr = sqrtf(q0*q0 + q1*q1 + q2*q2) + 1e-6f;
          float s1 = nr, s2 = nr * nr;
          #pragma unroll
          for (int off = 1; off < 16; off <<= 1) { s1 += __shfl_xor(s1, off); s2 += __shfl_xor(s2, off); }
          if (l16 == 0 && co < Cout) { atomicAdd(&statSum[co], s1); atomicAdd(&statSq[co], s2); }
        }
        #pragma unroll
        for (int v = 0; v < 3; ++v) {
          u16 ob[4];
          ob[0] = f2b(q[v][0]); ob[1] = f2b(q[v][1]); ob[2] = f2b(q[v][2]); ob[3] = f2b(q[v][3]);
          *(ushort4*)(Pb + ((size_t)v * N + n) * Cpad + cb) = *(ushort4*)ob;
        }
      }
    } else {  // MODE 2
      if (cb < Cpad) {
        u16 pa[3][4];
        #pragma unroll
        for (int v = 0; v < 3; ++v)
          *(ushort4*)pa[v] = *(const ushort4*)(Pb + ((size_t)v * N + n) * Cpad + cb);
        float o[3][4];
        #pragma unroll
        for (int r = 0; r < 4; ++r) {
          int co = cb + r;
          float r0 = 0.f, r1 = 0.f, r2 = 0.f;
          if (co < Cout) {
            float p0 = b2f(pa[0][r]), p1 = b2f(pa[1][r]), p2 = b2f(pa[2][r]);
            float d0 = acc[s][0][r], d1 = acc[s][1][r], d2 = acc[s][2][r];
            if (biasD != nullptr) {
              size_t bi = ((size_t)b * Cout + co) * 3;
              d0 += biasD[bi]; d1 += biasD[bi + 1]; d2 += biasD[bi + 2];
            }
            float mn = statMean[co], is = statIstd[co];
            float nr = sqrtf(p0*p0 + p1*p1 + p2*p2) + 1e-6f;
            float sc = ((nr - mn) * is) / nr;
            float q0 = p0 * sc, q1 = p1 * sc, q2 = p2 * sc;
            float dot = q0*d0 + q1*d1 + q2*d2;
            if (dot < 0.f) {
              float dsq = d0*d0 + d1*d1 + d2*d2;
              float t = dot / (dsq + 1e-6f);
              q0 -= t*d0; q1 -= t*d1; q2 -= t*d2;
            }
            r0 = q0; r1 = q1; r2 = q2;
          }
          o[0][r] = r0; o[1][r] = r1; o[2][r] = r2;
        }
        #pragma unroll
        for (int v = 0; v < 3; ++v) {
          u16 ob[4];
          ob[0] = f2b(o[v][0]); ob[1] = f2b(o[v][1]); ob[2] = f2b(o[v][2]); ob[3] = f2b(o[v][3]);
          *(ushort4*)(Pb + ((size_t)v * N + n) * Cpad + cb) = *(ushort4*)ob;
        }
      }
    }
  }
}

// weight fp32 -> padded bf16 [CoutPad x Kpad]
__global__ void w_to_bf16(const float* __restrict__ W, u16* __restrict__ Wp,
                          int Cout, int Cin, int wstride, int CoutPad, int Kpad) {
  int t = blockIdx.x * 256 + threadIdx.x;
  if (t >= CoutPad * Kpad) return;
  int co = t / Kpad, ci = t - co * Kpad;
  Wp[t] = (co < Cout && ci < Cin) ? f2b(W[(size_t)co * wstride + ci]) : (u16)0;
}

// weight fp32 -> padded fp32 [CoutPad x Kpad] (zeros beyond)
__global__ void w_to_f32pad(const float* __restrict__ W, float* __restrict__ Wp,
                            int Cout, int Cin, int wstride, int CoutPad, int Kpad) {
  int t = blockIdx.x * 256 + threadIdx.x;
  if (t >= CoutPad * Kpad) return;
  int co = t / Kpad, ci = t - co * Kpad;
  Wp[t] = (co < Cout && ci < Cin) ? W[(size_t)co * wstride + ci] : 0.f;
}

// ----------------------------------------------------------- small kernels
__global__ void zero_kernel(float* p, int n) {
  int t = blockIdx.x * 256 + threadIdx.x;
  if (t < n) p[t] = 0.f;
}

// computes mean/istd AND re-zeroes sum/sq (512 wide) for the next layer
__global__ void finalize_kernel(float* __restrict__ sum, float* __restrict__ sq,
                                float* __restrict__ mean, float* __restrict__ istd,
                                int C, float invCount) {
  int c = blockIdx.x * 256 + threadIdx.x;
  if (c < C) {
    float m = sum[c] * invCount;
    float v = sq[c] * invCount - m * m;
    if (v < 0.f) v = 0.f;
    mean[c] = m;
    istd[c] = 1.f / sqrtf(v + 1e-5f);
  }
  if (c < 512) { sum[c] = 0.f; sq[c] = 0.f; }
}

__global__ __launch_bounds__(64) void pool_reduce(const unsigned long long* __restrict__ part,
                                                  const float* __restrict__ s3,
                                                  float* __restrict__ pooled, int N) {
  int co = blockIdx.x, b = blockIdx.y, lane = threadIdx.x;
  unsigned long long key = part[((size_t)b * 341 + co) * 64 + lane];
  #pragma unroll
  for (int off = 32; off; off >>= 1) {
    unsigned long long o = __shfl_down(key, off);
    if (o > key) key = o;
  }
  if (lane == 0) {
    int n = (int)(0xFFFFFFFFu - (unsigned)(key & 0xFFFFFFFFull));
    size_t base = ((size_t)b * 352 + co) * 3;       // padded channel stride
    size_t obase = ((size_t)b * 341 + co) * 3;
    pooled[obase + 0] = s3[(base + 0) * N + n];
    pooled[obase + 1] = s3[(base + 1) * N + n];
    pooled[obase + 2] = s3[(base + 2) * N + n];
  }
}

// vn_lrelu on (B,Cin,3) tiny tensors (bn stats over batch axis only)
__global__ __launch_bounds__(64) void stf_lrelu(const float* __restrict__ Wf,
                                                const float* __restrict__ Wd,
                                                const float* __restrict__ X,
                                                float* __restrict__ Y, int Cin, int Cout) {
  __shared__ float P[24], D[24], NORM[8], SC[8], DOT[8], DSQ[8], MS[2];
  int co = blockIdx.x, tid = threadIdx.x;
  if (tid < 48) {
    int l = tid < 24 ? tid : tid - 24;
    int b = l / 3, v = l - b * 3;
    const float* W = (tid < 24 ? Wf : Wd) + (size_t)co * Cin;
    const float* xb = X + ((size_t)b * Cin) * 3 + v;
    float acc = 0.f;
    for (int ci = 0; ci < Cin; ++ci) acc += W[ci] * xb[ci * 3];
    if (tid < 24) P[l] = acc; else D[l] = acc;
  }
  __syncthreads();
  if (tid < 8) NORM[tid] = sqrtf(P[tid*3]*P[tid*3] + P[tid*3+1]*P[tid*3+1] + P[tid*3+2]*P[tid*3+2]) + 1e-6f;
  __syncthreads();
  if (tid == 0) {
    float m = 0.f;
    for (int b2 = 0; b2 < 8; ++b2) m += NORM[b2];
    m *= 0.125f;
    float var = 0.f;
    for (int b2 = 0; b2 < 8; ++b2) { float dd = NORM[b2] - m; var += dd * dd; }
    var *= 0.125f;
    MS[0] = m; MS[1] = 1.f / sqrtf(var + 1e-5f);
  }
  __syncthreads();
  if (tid < 8) {
    float sc = ((NORM[tid] - MS[0]) * MS[1]) / NORM[tid];
    float dot = 0.f, dsq = 0.f;
    for (int v = 0; v < 3; ++v) {
      float pb = P[tid*3+v] * sc; float dv = D[tid*3+v];
      dot += pb * dv; dsq += dv * dv;
    }
    SC[tid] = sc; DOT[tid] = dot; DSQ[tid] = dsq;
  }
  __syncthreads();
  if (tid < 24) {
    int b = tid / 3;
    float pb = P[tid] * SC[b];
    float o = (DOT[b] >= 0.f) ? pb : pb - (DOT[b] / (DSQ[b] + 1e-6f)) * D[tid];
    Y[((size_t)b * Cout + co) * 3 + (tid - b * 3)] = o;
  }
}

__global__ void vnlin_small(const float* __restrict__ W, const float* __restrict__ X,
                            float* __restrict__ Y, int Cin, int Cout) {
  int t = blockIdx.x * 256 + threadIdx.x;   // over 8*Cout*3
  if (t >= 8 * Cout * 3) return;
  int v = t % 3, r = t / 3;
  int co = r % Cout, b = r / Cout;
  float acc = 0.f;
  for (int ci = 0; ci < Cin; ++ci) acc += W[(size_t)co * Cin + ci] * X[((size_t)b * Cin + ci) * 3 + v];
  Y[t] = acc;
}

// concat [h1(32ch padded) ; broadcast sfin ; zero-pad] -> ^T bf16 [b][v][n][64]
__global__ __launch_bounds__(256) void concat_tt(const float* __restrict__ h1,
                                                 const float* __restrict__ sfin,
                                                 u16* __restrict__ s2bb, int N) {
  __shared__ u16 tile[64][66];
  int b = blockIdx.z, v = blockIdx.y, n0 = blockIdx.x * 64;
  int tn = threadIdx.x & 63, tc = threadIdx.x >> 6;   // tc in [0,4)
  for (int c = tc; c < 64; c += 4) {
    u16 val = 0;
    if (c < 21) val = f2b(h1[(((size_t)b * 32 + c) * 3 + v) * N + n0 + tn]);
    else if (c < 42) val = f2b(sfin[((size_t)b * 21 + (c - 21)) * 3 + v]);
    tile[c][tn] = val;
  }
  __syncthreads();
  u16* dst = s2bb + (((size_t)b * 3 + v) * N + n0) * 64;
  for (int n = tc; n < 64; n += 4)
    dst[(size_t)n * 64 + tn] = tile[tn][n];
}

// in-place bn on transposed H + accumulate per-(c,v) sums for h_mean
__global__ __launch_bounds__(384) void bn_apply_mean(u16* __restrict__ H,
    const float* __restrict__ sMean, const float* __restrict__ sIstd,
    float* __restrict__ HmAcc, int N) {
  int c = threadIdx.x;
  if (c >= 341) return;
  int b = blockIdx.y, nt = blockIdx.x;
  float mn = sMean[c], is = sIstd[c];
  float a0 = 0.f, a1 = 0.f, a2 = 0.f;
  size_t base = (size_t)b * 3 * N * 352;
  for (int n = nt * 64; n < nt * 64 + 64; ++n) {
    size_t i0 = base + ((size_t)0 * N + n) * 352 + c;
    size_t i1 = base + ((size_t)1 * N + n) * 352 + c;
    size_t i2 = base + ((size_t)2 * N + n) * 352 + c;
    float p0 = b2f(H[i0]), p1 = b2f(H[i1]), p2 = b2f(H[i2]);
    float nr = sqrtf(p0*p0 + p1*p1 + p2*p2) + 1e-6f;
    float sc = ((nr - mn) * is) / nr;
    p0 *= sc; p1 *= sc; p2 *= sc;
    H[i0] = f2b(p0); H[i1] = f2b(p1); H[i2] = f2b(p2);
    a0 += p0; a1 += p1; a2 += p2;
  }
  size_t hb = ((size_t)b * 341 + c) * 3;
  atomicAdd(&HmAcc[hb], a0); atomicAdd(&HmAcc[hb + 1], a1); atomicAdd(&HmAcc[hb + 2], a2);
}

__global__ void hm_finalize(float* Hm, float invN) {
  int t = blockIdx.x * 256 + threadIdx.x;
  if (t < 8 * 341 * 3) Hm[t] *= invN;
}

// bias terms for std1: W[:,341:682] . h_mean   (n-invariant half of concat)
__global__ void bias_kernel(const float* __restrict__ Wf, const float* __restrict__ Wd,
                            const float* __restrict__ Hm,
                            float* __restrict__ biasP, float* __restrict__ biasD) {
  int t = blockIdx.x * 256 + threadIdx.x;   // over 8*341*3
  if (t >= 8 * 341 * 3) return;
  int v = t % 3, r = t / 3;
  int co = r % 341, b = r / 341;
  const float* hm = Hm + (size_t)b * 1023 + v;
  float ap = 0.f, ad = 0.f;
  for (int j = 0; j < 341; ++j) {
    float h = hm[j * 3];
    ap += Wf[(size_t)co * 682 + 341 + j] * h;
    ad += Wd[(size_t)co * 682 + 341 + j] * h;
  }
  biasP[t] = ap; biasD[t] = ad;
}

// h_std einsum + partial max over an n-chunk; rows >=341 use h_mean.
__global__ __launch_bounds__(256) void final_max_part(const u16* __restrict__ H,
    const float* __restrict__ Hm, const float* __restrict__ z0,
    float* __restrict__ part, int N, int NT) {
  __shared__ float red[3][4][64];
  int b = blockIdx.z, nt = blockIdx.y;
  int il = threadIdx.x & 63, nsub = threadIdx.x >> 6;
  int i = blockIdx.x * 64 + il;
  bool valid = i < 682, lo = i < 341;
  float c0 = 0, c1 = 0, c2 = 0;
  if (valid && !lo) {
    size_t hb = ((size_t)b * 341 + (i - 341)) * 3;
    c0 = Hm[hb]; c1 = Hm[hb + 1]; c2 = Hm[hb + 2];
  }
  const float* zb = z0 + (size_t)b * 9 * N;
  const u16* Hb = H + (size_t)b * 3 * N * 352;
  float m0 = -3.4e38f, m1 = -3.4e38f, m2 = -3.4e38f;
  int ii = lo ? i : 0;
  int chunk = N / NT, nBeg = nt * chunk;
  for (int n = nBeg + nsub; n < nBeg + chunk; n += 4) {
    float a0, a1, a2;
    if (lo) {
      a0 = b2f(Hb[((size_t)0 * N + n) * 352 + ii]);
      a1 = b2f(Hb[((size_t)1 * N + n) * 352 + ii]);
      a2 = b2f(Hb[((size_t)2 * N + n) * 352 + ii]);
    } else { a0 = c0; a1 = c1; a2 = c2; }
    float s0 = a0 * zb[n]                + a1 * zb[3 * (size_t)N + n] + a2 * zb[6 * (size_t)N + n];
    float s1 = a0 * zb[N + n]            + a1 * zb[4 * (size_t)N + n] + a2 * zb[7 * (size_t)N + n];
    float s2 = a0 * zb[2 * (size_t)N + n]+ a1 * zb[5 * (size_t)N + n] + a2 * zb[8 * (size_t)N + n];
    m0 = fmaxf(m0, s0); m1 = fmaxf(m1, s1); m2 = fmaxf(m2, s2);
  }
  red[0][nsub][il] = m0; red[1][nsub][il] = m1; red[2][nsub][il] = m2;
  __syncthreads();
  if (nsub == 0 && valid) {
    for (int q = 1; q < 4; ++q) {
      m0 = fmaxf(m0, red[0][q][il]); m1 = fmaxf(m1, red[1][q][il]); m2 = fmaxf(m2, red[2][q][il]);
    }
    size_t pb = ((size_t)b * 682 + i) * 3;
    part[(pb + 0) * NT + nt] = m0;
    part[(pb + 1) * NT + nt] = m1;
    part[(pb + 2) * NT + nt] = m2;
  }
}

__global__ void final_max_reduce(const float* __restrict__ part,
                                 float* __restrict__ out, int NT) {
  int t = blockIdx.x * 256 + threadIdx.x;   // over 8*682*3
  if (t >= 8 * 682 * 3) return;
  const float* p = part + (size_t)t * NT;
  float m = p[0];
  for (int k = 1; k < NT; ++k) m = fmaxf(m, p[k]);
  out[t] = m;
}

// ------------------------------------------------------------------- host
extern "C" void kernel_launch(void* const* d_in, const int* in_sizes, int n_in,
                              void* d_out, int out_size, void* d_ws, size_t ws_size,
                              hipStream_t stream) {
  (void)in_sizes; (void)n_in; (void)out_size; (void)ws_size;
  const float* x       = (const float*)d_in[0];
  const float* pos_Wf  = (const float*)d_in[1];
  const float* pos_Wd  = (const float*)d_in[2];
  const float* pool_Wd = (const float*)d_in[3];
  const float* c1_Wf   = (const float*)d_in[4];
  const float* c1_Wd   = (const float*)d_in[5];
  const float* st1_Wf  = (const float*)d_in[6];
  const float* st1_Wd  = (const float*)d_in[7];
  const float* st2_Wf  = (const float*)d_in[8];
  const float* st2_Wd  = (const float*)d_in[9];
  const float* st3_Wf  = (const float*)d_in[10];
  const float* st3_Wd  = (const float*)d_in[11];
  const float* stp_Wd  = (const float*)d_in[12];
  const float* stf1_Wf = (const float*)d_in[13];
  const float* stf1_Wd = (const float*)d_in[14];
  const float* stf2_Wf = (const float*)d_in[15];
  const float* stf2_Wd = (const float*)d_in[16];
  const float* stf3_W  = (const float*)d_in[17];
  const float* c2_Wf   = (const float*)d_in[18];
  const float* c2_Wd   = (const float*)d_in[19];
  const float* c3_W    = (const float*)d_in[20];
  const float* std1_Wf = (const float*)d_in[21];
  const float* std1_Wd = (const float*)d_in[22];
  const float* std2_Wf = (const float*)d_in[23];
  const float* std2_Wd = (const float*)d_in[24];
  const float* stdlin  = (const float*)d_in[25];

  float* outv  = (float*)d_out;           // fp32: [8*2046] ++ z0 [8*3*3*4096]
  float* z0out = outv + 8 * 2046;

  const int N = 4096;
  const int NT = 32;                       // final_max n-tiles
  char* ws = (char*)d_ws;
  size_t off = 0;
  auto alloc = [&](size_t bytes) -> char* {
    char* p = ws + off;
    off += (bytes + 255) & ~(size_t)255;
    return p;
  };
  float* stats = (float*)alloc(2048 * sizeof(float));
  float* sSum = stats, *sSq = stats + 512, *sMean = stats + 1024, *sIstd = stats + 1536;
  int* idx = (int*)alloc((size_t)8 * N * 20 * 4);
  unsigned long long* poolPart = (unsigned long long*)alloc((size_t)8 * 341 * 64 * 8);
  float* fmPart = (float*)alloc((size_t)8 * 682 * 3 * NT * 4);
  // padded fp32 weights
  float* Wpoolp = (float*)alloc((size_t)384 * 352 * 4);
  float* Wc1f = (float*)alloc(32 * 32 * 4);
  float* Wc1d = (float*)alloc(32 * 32 * 4);
  float* Ws1f = (float*)alloc(32 * 32 * 4);
  float* Ws1d = (float*)alloc(32 * 32 * 4);
  float* Ws2f = (float*)alloc(64 * 32 * 4);
  float* Ws2d = (float*)alloc(64 * 32 * 4);
  float* Ws3f = (float*)alloc(352 * 48 * 4);
  float* Ws3d = (float*)alloc(352 * 48 * 4);
  float* pooled = (float*)alloc(8 * 341 * 3 * 4);
  float* stf1o  = (float*)alloc(8 * 170 * 3 * 4);
  float* stf2o  = (float*)alloc(8 * 85 * 3 * 4);
  float* sfin   = (float*)alloc(8 * 21 * 3 * 4);
  float* Hm     = (float*)alloc(8 * 1023 * 4);
  float* biasP  = (float*)alloc(8 * 341 * 3 * 4);
  float* biasD  = (float*)alloc(8 * 341 * 3 * 4);
  const size_t P32 = (size_t)8 * 32 * 3 * N;         // padded 32-ch elems
  const size_t P48 = (size_t)8 * 48 * 3 * N;
  const size_t T352 = (size_t)8 * 3 * N * 352 * 2;   // bf16 ^T 352-ch bytes
  const size_t T192 = (size_t)8 * 3 * N * 192 * 2;
  const size_t T64  = (size_t)8 * 3 * N * 64 * 2;
  const size_t F352 = (size_t)8 * 352 * 3 * N * 4;   // fp32 padded st3o bytes
  char* regionA = alloc(T352);                       // 69.2MB: early stack / Pstd1
  char* regionB = alloc(F352);                       // 138.4MB
  float* h0  = (float*)regionA;                      // [b][32][3][N]
  float* h1  = h0 + P32;
  float* s1b = h1 + P32;
  float* s2b = s1b + P32;                            // [b][48][3][N]
  float* st3o = (float*)regionB;                     // [b][352][3][N]
  u16* Hbuf  = (u16*)regionB;                        // c3 out ^T
  u16* Pstd2 = (u16*)(regionB + T352);
  u16* s2bb  = (u16*)(regionB + T352 + T192);
  u16* h2b   = (u16*)(regionB + T352 + T192 + T64);
  u16* Pstd1 = (u16*)regionA;
  // padded bf16 weights in poolPart (dead after pool_reduce)
  u16* W1fp = (u16*)poolPart;                 // 384x352
  u16* W1dp = W1fp + 384 * 352;
  u16* W2fp = W1dp + 384 * 352;               // 192x352
  u16* W2dp = W2fp + 192 * 352;
  u16* Wc3p = W2dp + 192 * 352;               // 384x64
  u16* Wc2f = Wc3p + 384 * 64;                // 64x64
  u16* Wc2d = Wc2f + 64 * 64;
  u16* Wzp  = Wc2d + 64 * 64;                 // 16x192

  dim3 blk256(256), blk64(64);
  const float invBN = 1.f / (8.f * N);
  // fp32 async-dbuf lrelu layer over padded tensors
  auto run_db = [&](const float* Wfp, const float* Wdp, const float* X, float* Y,
                    int Cout, int CpadY, int Kpad, int coTiles, float invCnt) {
    dim3 grid(64, coTiles, 8);
    gemm_db<5, 2><<<grid, blk256, 0, stream>>>(Wfp, X, Y, sSum, sSq, nullptr, nullptr,
                                               Cout, CpadY, Kpad, N);
    finalize_kernel<<<dim3(2), blk256, 0, stream>>>(sSum, sSq, sMean, sIstd, Cout, invCnt);
    gemm_db<6, 2><<<grid, blk256, 0, stream>>>(Wdp, X, Y, nullptr, nullptr, sMean, sIstd,
                                               Cout, CpadY, Kpad, N);
  };
  // bf16 mfma lrelu layer (transposed tensors)
  auto run_mfma = [&](const u16* Wf, const u16* Wd, const u16* X, u16* P,
                      const float* bP, const float* bD,
                      int Cout, int Cpad, int Kpad, int coTiles) {
    dim3 grid(64, coTiles, 8);
    mfma2<1, 4><<<grid, blk256, 0, stream>>>(Wf, X, P, nullptr, bP, nullptr,
                                             sSum, sSq, nullptr, nullptr, Cout, Cpad, Kpad, N);
    finalize_kernel<<<dim3(2), blk256, 0, stream>>>(sSum, sSq, sMean, sIstd, Cout, invBN);
    mfma2<2, 4><<<grid, blk256, 0, stream>>>(Wd, X, P, nullptr, nullptr, bD,
                                             nullptr, nullptr, sMean, sIstd, Cout, Cpad, Kpad, N);
  };

  // 0. init: stats zero, pad weights, zero h0 pad channels
  zero_kernel<<<dim3(4), blk256, 0, stream>>>(stats, 1024);
  w_to_f32pad<<<dim3((384 * 352 + 255) / 256), blk256, 0, stream>>>(stp_Wd, Wpoolp, 341, 341, 341, 384, 352);
  w_to_f32pad<<<dim3((32 * 32 + 255) / 256), blk256, 0, stream>>>(c1_Wf, Wc1f, 21, 21, 21, 32, 32);
  w_to_f32pad<<<dim3((32 * 32 + 255) / 256), blk256, 0, stream>>>(c1_Wd, Wc1d, 21, 21, 21, 32, 32);
  w_to_f32pad<<<dim3((32 * 32 + 255) / 256), blk256, 0, stream>>>(st1_Wf, Ws1f, 21, 21, 21, 32, 32);
  w_to_f32pad<<<dim3((32 * 32 + 255) / 256), blk256, 0, stream>>>(st1_Wd, Ws1d, 21, 21, 21, 32, 32);
  w_to_f32pad<<<dim3((64 * 32 + 255) / 256), blk256, 0, stream>>>(st2_Wf, Ws2f, 42, 21, 21, 64, 32);
  w_to_f32pad<<<dim3((64 * 32 + 255) / 256), blk256, 0, stream>>>(st2_Wd, Ws2d, 42, 21, 21, 64, 32);
  w_to_f32pad<<<dim3((352 * 48 + 255) / 256), blk256, 0, stream>>>(st3_Wf, Ws3f, 341, 42, 42, 352, 48);
  w_to_f32pad<<<dim3((352 * 48 + 255) / 256), blk256, 0, stream>>>(st3_Wd, Ws3d, 341, 42, 42, 352, 48);
  zero_padch<<<dim3((8 * 11 * 3 * N + 255) / 256), blk256, 0, stream>>>(h0, 21, 32, N);

  // 1. KNN (one wave per point)
  knn_kernel<<<dim3(N / 4, 8), blk256, 0, stream>>>(x, idx, N);
  // 2. pos layer
  pos_stats<<<dim3(N * 20 / 256, 8), blk256, 0, stream>>>(x, idx, pos_Wf, sSum, sSq, N);
  finalize_kernel<<<dim3(2), blk256, 0, stream>>>(sSum, sSq, sMean, sIstd, 21, 1.f / (8.f * N * 20.f));
  pos_apply<<<dim3(N, 8), blk64, 0, stream>>>(x, idx, pos_Wf, pos_Wd, pool_Wd, sMean, sIstd, h0, N);

  // 3. early fp32 chain (argmax-exact path), async-dbuf over padded tensors
  run_db(Wc1f, Wc1d, h0, h1, 21, 32, 32, 1, invBN);
  run_db(Ws1f, Ws1d, h1, s1b, 21, 32, 32, 1, invBN);
  run_db(Ws2f, Ws2d, s1b, s2b, 42, 48, 32, 2, invBN);
  run_db(Ws3f, Ws3d, s2b, st3o, 341, 352, 48, 11, invBN);

  // 4. st_pool over N (fp32-exact argmax), async-dbuf GEMM
  gemm_pool_db<<<dim3(64, 6, 8), blk256, 0, stream>>>(Wpoolp, st3o, poolPart, 341, N);
  pool_reduce<<<dim3(341, 8), blk64, 0, stream>>>(poolPart, st3o, pooled, N);

  // 5. weights -> padded bf16 (poolPart now dead)
  w_to_bf16<<<dim3((384 * 352 + 255) / 256), blk256, 0, stream>>>(std1_Wf, W1fp, 341, 341, 682, 384, 352);
  w_to_bf16<<<dim3((384 * 352 + 255) / 256), blk256, 0, stream>>>(std1_Wd, W1dp, 341, 341, 682, 384, 352);
  w_to_bf16<<<dim3((192 * 352 + 255) / 256), blk256, 0, stream>>>(std2_Wf, W2fp, 170, 341, 341, 192, 352);
  w_to_bf16<<<dim3((192 * 352 + 255) / 256), blk256, 0, stream>>>(std2_Wd, W2dp, 170, 341, 341, 192, 352);
  w_to_bf16<<<dim3((384 * 64 + 255) / 256), blk256, 0, stream>>>(c3_W, Wc3p, 341, 42, 42, 384, 64);
  w_to_bf16<<<dim3((64 * 64 + 255) / 256), blk256, 0, stream>>>(c2_Wf, Wc2f, 42, 42, 42, 64, 64);
  w_to_bf16<<<dim3((64 * 64 + 255) / 256), blk256, 0, stream>>>(c2_Wd, Wc2d, 42, 42, 42, 64, 64);
  w_to_bf16<<<dim3((16 * 192 + 255) / 256), blk256, 0, stream>>>(stdlin, Wzp, 3, 170, 170, 16, 192);

  // 6. stf chain (tiny)
  stf_lrelu<<<dim3(170), blk64, 0, stream>>>(stf1_Wf, stf1_Wd, pooled, stf1o, 341, 170);
  stf_lrelu<<<dim3(85),  blk64, 0, stream>>>(stf2_Wf, stf2_Wd, stf1o, stf2o, 170, 85);
  vnlin_small<<<dim3(2), blk256, 0, stream>>>(stf3_W, stf2o, sfin, 85, 21);

  // 7. concat -> transposed bf16 (LDS-tiled); c2 (mfma)
  concat_tt<<<dim3(N / 64, 3, 8), blk256, 0, stream>>>(h1, sfin, s2bb, N);
  run_mfma(Wc2f, Wc2d, s2bb, h2b, nullptr, nullptr, 42, 64, 64, 1);

  // 8. c3 + bn (mfma P+stats, then fused bn-apply + h_mean)
  {
    dim3 grid(64, 6, 8);
    mfma2<1, 4><<<grid, blk256, 0, stream>>>(Wc3p, h2b, Hbuf, nullptr, nullptr, nullptr,
                                             sSum, sSq, nullptr, nullptr, 341, 352, 64, N);
  }
  finalize_kernel<<<dim3(2), blk256, 0, stream>>>(sSum, sSq, sMean, sIstd, 341, invBN);
  zero_kernel<<<dim3(32), blk256, 0, stream>>>(Hm, 8 * 1023);
  bn_apply_mean<<<dim3(64, 8), dim3(384), 0, stream>>>(Hbuf, sMean, sIstd, Hm, N);
  hm_finalize<<<dim3(32), blk256, 0, stream>>>(Hm, 1.f / (float)N);
  bias_kernel<<<dim3(32), blk256, 0, stream>>>(std1_Wf, std1_Wd, Hm, biasP, biasD);

  // 9. VNStdFeature (mfma)
  run_mfma(W1fp, W1dp, Hbuf, Pstd1, biasP, biasD, 341, 352, 352, 6);
  run_mfma(W2fp, W2dp, Pstd1, Pstd2, nullptr, nullptr, 170, 192, 352, 3);

  // 10. z0 (mfma MODE0, fp32 out) + n-tiled einsum/max + reduce
  mfma2<0, 1><<<dim3(64, 1, 8), blk256, 0, stream>>>(Wzp, Pstd2, nullptr, z0out,
                                                     nullptr, nullptr, nullptr, nullptr,
                                                     nullptr, nullptr, 3, 16, 192, N);
  final_max_part<<<dim3(11, NT, 8), blk256, 0, stream>>>(Hbuf, Hm, z0out, fmPart, N, NT);
  final_max_reduce<<<dim3((8 * 682 * 3 + 255) / 256), blk256, 0, stream>>>(fmPart, outv, NT);
}

// Round 14
// 2614.290 us; speedup vs baseline: 1.4915x; 1.0266x over previous
//
#include <hip/hip_runtime.h>
#include <cstdint>
#include <cstddef>

// VN-PointNet encoder. Inputs fp32, outputs fp32 (out 8x2046 ++ z0 8x3x3x4096).
// Early chain fp32 with async-dbuf (global_load_lds) GEMMs over channel-padded
// tensors; st_pool CPT=6. Post-pool chain on bf16 MFMA, k-major transposed
// [b][v][n][Cpad]. KNN: one wave/point register top-8. final_max n-tiled.
// Init launches consolidated into prep_f32 / prep_bf16.
// Standard (B,C,3,N): flat ((b*C+c)*3+v)*N + n.

typedef unsigned short u16;
using bh8  = __attribute__((ext_vector_type(8))) short;
using f32x4 = __attribute__((ext_vector_type(4))) float;

__device__ __forceinline__ float b2f(u16 v) {
  return __uint_as_float(((unsigned)v) << 16);
}
__device__ __forceinline__ u16 f2b(float f) {
  unsigned u = __float_as_uint(f);
  u += 0x7FFFu + ((u >> 16) & 1u);   // round-to-nearest-even
  return (u16)(u >> 16);
}

__device__ __forceinline__ void st4(float* p, size_t i, float a, float b, float c, float d) {
  float4 v; v.x = a; v.y = b; v.z = c; v.w = d; *(float4*)(p + i) = v;
}

#define FMA4(A, S, V) { A.x += (S)*(V).x; A.y += (S)*(V).y; A.z += (S)*(V).z; A.w += (S)*(V).w; }

__device__ __forceinline__ unsigned long long packKey(float v, int n) {
  unsigned u = __float_as_uint(v);
  u = (u & 0x80000000u) ? ~u : (u | 0x80000000u);   // total-order float
  return ((unsigned long long)u << 32) | (unsigned long long)(0xFFFFFFFFu - (unsigned)n);
}

// ------------------------------------------- KNN top-20: one wave per point
#define CSWAP(T) { if (c > T) { unsigned long long tmp = T; T = c; c = tmp; } }
__global__ __launch_bounds__(256) void knn_kernel(const float* __restrict__ x,
                                                  int* __restrict__ idxOut, int N) {
  int b = blockIdx.y;
  int wv = threadIdx.x >> 6, lane = threadIdx.x & 63;
  int i = blockIdx.x * 4 + wv;
  const float* xb = x + (size_t)b * 3 * N;
  float xi0 = xb[i], xi1 = xb[N + i], xi2 = xb[2 * (size_t)N + i];
  float xxi = xi0 * xi0 + xi1 * xi1 + xi2 * xi2;
  unsigned long long t0 = 0, t1 = 0, t2 = 0, t3 = 0, t4 = 0, t5 = 0, t6 = 0, t7 = 0;
  #pragma unroll 8
  for (int s = 0; s < 64; ++s) {
    int j = s * 64 + lane;
    float a0 = xb[j], a1 = xb[N + j], a2 = xb[2 * (size_t)N + j];
    float inner = xi0 * a0 + xi1 * a1 + xi2 * a2;
    float xxj = a0 * a0 + a1 * a1 + a2 * a2;
    float pd = 2.f * inner - xxi - xxj;          // = -||xi-xj||^2
    unsigned long long c = packKey(pd, j);
    if (c > t7) { CSWAP(t0) CSWAP(t1) CSWAP(t2) CSWAP(t3) CSWAP(t4) CSWAP(t5) CSWAP(t6) CSWAP(t7) }
  }
  int* row = idxOut + ((size_t)b * N + i) * 20;
  for (int kk = 0; kk < 20; ++kk) {
    unsigned long long k = t0;
    #pragma unroll
    for (int off = 1; off < 64; off <<= 1) {
      unsigned long long o = __shfl_xor(k, off);
      if (o > k) k = o;
    }
    if (lane == 0) row[kk] = (int)(0xFFFFFFFFu - (unsigned)(k & 0xFFFFFFFFull));
    if (k == t0) { t0 = t1; t1 = t2; t2 = t3; t3 = t4; t4 = t5; t5 = t6; t6 = t7; t7 = 0; }
  }
}
#undef CSWAP

// ------------------------------------------------- pos layer: bn statistics
__global__ __launch_bounds__(256) void pos_stats(const float* __restrict__ x,
                                                 const int* __restrict__ idx,
                                                 const float* __restrict__ Wf,
                                                 float* __restrict__ statSum,
                                                 float* __restrict__ statSq, int N) {
  __shared__ float wf[64];
  __shared__ float part[4][42];
  int tid = threadIdx.x;
  if (tid < 63) wf[tid] = Wf[tid];
  __syncthreads();
  int b = blockIdx.y;
  int lin = blockIdx.x * 256 + tid;           // over N*20 exactly
  int n = lin / 20, kk = lin - n * 20;
  const float* xb = x + (size_t)b * 3 * N;
  int j = idx[((size_t)b * N + n) * 20 + kk];
  float c0 = xb[n], c1 = xb[N + n], c2 = xb[2 * (size_t)N + n];
  float a0 = xb[j], a1 = xb[N + j], a2 = xb[2 * (size_t)N + j];
  float e00 = a0 - c0, e01 = a1 - c1, e02 = a2 - c2;
  float e20 = a1 * c2 - a2 * c1, e21 = a2 * c0 - a0 * c2, e22 = a0 * c1 - a1 * c0;
  int lane = tid & 63, wave = tid >> 6;
  #pragma unroll
  for (int c = 0; c < 21; ++c) {
    float w0 = wf[c * 3], w1 = wf[c * 3 + 1], w2 = wf[c * 3 + 2];
    float p0 = w0 * e00 + w1 * c0 + w2 * e20;
    float p1 = w0 * e01 + w1 * c1 + w2 * e21;
    float p2 = w0 * e02 + w1 * c2 + w2 * e22;
    float nr = sqrtf(p0 * p0 + p1 * p1 + p2 * p2) + 1e-6f;
    float u1 = nr, u2 = nr * nr;
    #pragma unroll
    for (int off = 32; off; off >>= 1) { u1 += __shfl_down(u1, off); u2 += __shfl_down(u2, off); }
    if (lane == 0) { part[wave][c] = u1; part[wave][21 + c] = u2; }
  }
  __syncthreads();
  if (tid < 42) {
    float t = part[0][tid] + part[1][tid] + part[2][tid] + part[3][tid];
    if (tid < 21) atomicAdd(&statSum[tid], t);
    else atomicAdd(&statSq[tid - 21], t);
  }
}

// ------------- pos layer: lrelu + maxpool over k fused; writes 32ch-padded h0
__global__ __launch_bounds__(64) void pos_apply(const float* __restrict__ x,
                                                const int* __restrict__ idx,
                                                const float* __restrict__ Wf,
                                                const float* __restrict__ Wd,
                                                const float* __restrict__ Wpool,
                                                const float* __restrict__ statMean,
                                                const float* __restrict__ statIstd,
                                                float* __restrict__ h0, int N) {
  __shared__ float wpool[441];
  __shared__ float hbuf[64];
  int tid = threadIdx.x;
  for (int l = tid; l < 441; l += 64) wpool[l] = Wpool[l];
  int b = blockIdx.y, n = blockIdx.x;
  bool act = tid < 63;
  int c = act ? tid / 3 : 0;
  int v = act ? tid - c * 3 : 0;
  const float* xb = x + (size_t)b * 3 * N;
  float c0 = xb[n], c1 = xb[N + n], c2 = xb[2 * (size_t)N + n];
  float wf0 = 0, wf1 = 0, wf2 = 0, wd0 = 0, wd1 = 0, wd2 = 0, mn = 0, is = 1.f;
  if (act) {
    wf0 = Wf[c * 3]; wf1 = Wf[c * 3 + 1]; wf2 = Wf[c * 3 + 2];
    wd0 = Wd[c * 3]; wd1 = Wd[c * 3 + 1]; wd2 = Wd[c * 3 + 2];
    mn = statMean[c]; is = statIstd[c];
  }
  __syncthreads();
  float best = -3.4e38f, bh = 0.f;
  const int* idxRow = idx + ((size_t)b * N + n) * 20;
  for (int kk = 0; kk < 20; ++kk) {
    int j = idxRow[kk];
    float a0 = xb[j], a1 = xb[N + j], a2 = xb[2 * (size_t)N + j];
    float av  = (v == 0) ? a0 : ((v == 1) ? a1 : a2);
    float cv  = (v == 0) ? c0 : ((v == 1) ? c1 : c2);
    float a1v = (v == 0) ? a1 : ((v == 1) ? a2 : a0);
    float a2v = (v == 0) ? a2 : ((v == 1) ? a0 : a1);
    float c1v = (v == 0) ? c1 : ((v == 1) ? c2 : c0);
    float c2v = (v == 0) ? c2 : ((v == 1) ? c0 : c1);
    float e0 = av - cv;                 // neighbor - center
    float e1 = cv;                      // center
    float e2 = a1v * c2v - a2v * c1v;   // cross(nb, center)[v]
    float p = wf0 * e0 + wf1 * e1 + wf2 * e2;
    float d = wd0 * e0 + wd1 * e1 + wd2 * e2;
    int base = c * 3;
    float pp = p * p;
    float n2 = __shfl(pp, base) + __shfl(pp, base + 1) + __shfl(pp, base + 2);
    float nr = sqrtf(n2) + 1e-6f;
    float sc = ((nr - mn) * is) / nr;
    float pb = p * sc;
    float pd2 = pb * d, dd = d * d;
    float dot = __shfl(pd2, base) + __shfl(pd2, base + 1) + __shfl(pd2, base + 2);
    float dsq = __shfl(dd, base) + __shfl(dd, base + 1) + __shfl(dd, base + 2);
    float h = (dot >= 0.f) ? pb : pb - (dot / (dsq + 1e-6f)) * d;
    hbuf[tid] = act ? h : 0.f;
    __syncthreads();
    float d2 = 0.f;
    #pragma unroll 7
    for (int cc = 0; cc < 21; ++cc) d2 += wpool[c * 21 + cc] * hbuf[cc * 3 + v];
    float hd = h * d2;
    float dotp = __shfl(hd, base) + __shfl(hd, base + 1) + __shfl(hd, base + 2);
    if (act && dotp > best) { best = dotp; bh = h; }   // strict >: first max = argmax
    __syncthreads();
  }
  if (act) h0[(((size_t)b * 32 + c) * 3 + v) * N + n] = bh;
}

// ----------------- unified fp32 async-dbuf GEMM over channel-padded tensors
// MODE 5: P = W.X -> Y + stats(co<Cout). Pad rows store acc (=0).
// MODE 6: D = W.X; read P from Y, bn+lrelu in place; pad rows -> 0.
template<int MODE, int CPT>
__global__ __launch_bounds__(256) void gemm_db(
    const float* __restrict__ Wp, const float* __restrict__ Xp,
    float* __restrict__ Yp,
    float* __restrict__ statSum, float* __restrict__ statSq,
    const float* __restrict__ statMean, const float* __restrict__ statIstd,
    int Cout, int CpadY, int Kpad, int N) {
  __shared__ float Xs[2][16][3][64];
  __shared__ float Wfs[2][16 * CPT][16];
  const int tid = threadIdx.x;
  const int tx = tid & 15, ty = tid >> 4;
  const int lane = tid & 63, w = tid >> 6;
  const int b = blockIdx.z;
  const int n0 = blockIdx.x * 64;
  const int co0 = blockIdx.y * (16 * CPT);
  const float* Xb = Xp + (size_t)b * Kpad * 3 * N;

  auto stage = [&](int k0, int buf) {
    #pragma unroll
    for (int l0 = 0; l0 < 12; ++l0) {
      int q = l0 * 4 + w;                 // 0..47 -> (kk, v)
      int vv = q % 3, kk = q / 3;
      const float* g = Xb + ((size_t)(k0 + kk) * 3 + vv) * N + n0 + lane;
      __builtin_amdgcn_global_load_lds(
          (const __attribute__((address_space(1))) float*)g,
          (__attribute__((address_space(3))) float*)&Xs[buf][kk][vv][0], 4, 0, 0);
    }
    #pragma unroll
    for (int c = 0; c < CPT; ++c) {
      const float* g = Wp + (size_t)(co0 + w * 4 + (lane >> 4) + 16 * c) * Kpad + k0 + (lane & 15);
      __builtin_amdgcn_global_load_lds(
          (const __attribute__((address_space(1))) float*)g,
          (__attribute__((address_space(3))) float*)&Wfs[buf][w * 4 + 16 * c][0], 4, 0, 0);
    }
  };

  float4 acc[CPT][3];
  #pragma unroll
  for (int c = 0; c < CPT; ++c)
    #pragma unroll
    for (int v = 0; v < 3; ++v) acc[c][v] = {0.f, 0.f, 0.f, 0.f};

  stage(0, 0);
  __syncthreads();
  const int KT = Kpad / 16;
  for (int kt = 0; kt < KT; ++kt) {
    int buf = kt & 1;
    if (kt + 1 < KT) stage((kt + 1) * 16, buf ^ 1);
    #pragma unroll
    for (int kk = 0; kk < 16; ++kk) {
      float4 x0 = *(const float4*)&Xs[buf][kk][0][tx * 4];
      float4 x1 = *(const float4*)&Xs[buf][kk][1][tx * 4];
      float4 x2 = *(const float4*)&Xs[buf][kk][2][tx * 4];
      #pragma unroll
      for (int c = 0; c < CPT; ++c) {
        float wv = Wfs[buf][ty + 16 * c][kk];
        FMA4(acc[c][0], wv, x0); FMA4(acc[c][1], wv, x1); FMA4(acc[c][2], wv, x2);
      }
    }
    __syncthreads();
  }

  #pragma unroll
  for (int c = 0; c < CPT; ++c) {
    int co = co0 + ty + 16 * c;
    if (co >= CpadY) continue;
    const float* a0 = (const float*)&acc[c][0];
    const float* a1 = (const float*)&acc[c][1];
    const float* a2 = (const float*)&acc[c][2];
    size_t yb = ((size_t)b * CpadY + co) * 3 * N + n0 + tx * 4;
    if constexpr (MODE == 5) {
      float s1 = 0.f, s2 = 0.f;
      #pragma unroll
      for (int j = 0; j < 4; ++j) {
        float nr = sqrtf(a0[j]*a0[j] + a1[j]*a1[j] + a2[j]*a2[j]) + 1e-6f;
        s1 += nr; s2 += nr * nr;
      }
      st4(Yp, yb,                 a0[0], a0[1], a0[2], a0[3]);
      st4(Yp, yb + N,             a1[0], a1[1], a1[2], a1[3]);
      st4(Yp, yb + 2 * (size_t)N, a2[0], a2[1], a2[2], a2[3]);
      #pragma unroll
      for (int off = 8; off; off >>= 1) { s1 += __shfl_down(s1, off); s2 += __shfl_down(s2, off); }
      if (tx == 0 && co < Cout) { atomicAdd(&statSum[co], s1); atomicAdd(&statSq[co], s2); }
    } else {  // MODE 6
      if (co < Cout) {
        float mn = statMean[co], is = statIstd[co];
        float4 P0 = *(const float4*)&Yp[yb];
        float4 P1 = *(const float4*)&Yp[yb + N];
        float4 P2 = *(const float4*)&Yp[yb + 2 * (size_t)N];
        float pr[3][4] = {{P0.x,P0.y,P0.z,P0.w},{P1.x,P1.y,P1.z,P1.w},{P2.x,P2.y,P2.z,P2.w}};
        float o_[3][4];
        #pragma unroll
        for (int j = 0; j < 4; ++j) {
          float q0 = pr[0][j], q1 = pr[1][j], q2 = pr[2][j];
          float e0 = a0[j], e1 = a1[j], e2 = a2[j];
          float nr = sqrtf(q0*q0 + q1*q1 + q2*q2) + 1e-6f;
          float sc = ((nr - mn) * is) / nr;
          q0 *= sc; q1 *= sc; q2 *= sc;
          float dot = q0*e0 + q1*e1 + q2*e2;
          if (dot < 0.f) {
            float dsq = e0*e0 + e1*e1 + e2*e2;
            float t = dot / (dsq + 1e-6f);
            q0 -= t*e0; q1 -= t*e1; q2 -= t*e2;
          }
          o_[0][j] = q0; o_[1][j] = q1; o_[2][j] = q2;
        }
        st4(Yp, yb,                 o_[0][0], o_[0][1], o_[0][2], o_[0][3]);
        st4(Yp, yb + N,             o_[1][0], o_[1][1], o_[1][2], o_[1][3]);
        st4(Yp, yb + 2 * (size_t)N, o_[2][0], o_[2][1], o_[2][2], o_[2][3]);
      } else {
        st4(Yp, yb, 0.f, 0.f, 0.f, 0.f);
        st4(Yp, yb + N, 0.f, 0.f, 0.f, 0.f);
        st4(Yp, yb + 2 * (size_t)N, 0.f, 0.f, 0.f, 0.f);
      }
    }
  }
}

// --------------------------- st_pool GEMM: async-dbuf, CPT=6 (96 co/block)
__global__ __launch_bounds__(256) void gemm_pool_db(
    const float* __restrict__ Wp, const float* __restrict__ Xp,
    unsigned long long* __restrict__ poolPart, int Cout, int N) {
  constexpr int KP = 352, CPT = 6;
  __shared__ float Xs[2][16][3][64];
  __shared__ float Wfs[2][16 * CPT][16];
  const int tid = threadIdx.x;
  const int tx = tid & 15, ty = tid >> 4;
  const int lane = tid & 63, w = tid >> 6;
  const int b = blockIdx.z;
  const int n0 = blockIdx.x * 64;
  const int co0 = blockIdx.y * (16 * CPT);
  const float* Xb = Xp + (size_t)b * KP * 3 * N;

  auto stage = [&](int k0, int buf) {
    #pragma unroll
    for (int l0 = 0; l0 < 12; ++l0) {
      int q = l0 * 4 + w;
      int vv = q % 3, kk = q / 3;
      const float* g = Xb + ((size_t)(k0 + kk) * 3 + vv) * N + n0 + lane;
      __builtin_amdgcn_global_load_lds(
          (const __attribute__((address_space(1))) float*)g,
          (__attribute__((address_space(3))) float*)&Xs[buf][kk][vv][0], 4, 0, 0);
    }
    #pragma unroll
    for (int c = 0; c < CPT; ++c) {
      const float* g = Wp + (size_t)(co0 + w * 4 + (lane >> 4) + 16 * c) * KP + k0 + (lane & 15);
      __builtin_amdgcn_global_load_lds(
          (const __attribute__((address_space(1))) float*)g,
          (__attribute__((address_space(3))) float*)&Wfs[buf][w * 4 + 16 * c][0], 4, 0, 0);
    }
  };

  float4 acc[CPT][3];
  #pragma unroll
  for (int c = 0; c < CPT; ++c)
    #pragma unroll
    for (int v = 0; v < 3; ++v) acc[c][v] = {0.f, 0.f, 0.f, 0.f};

  stage(0, 0);
  __syncthreads();
  constexpr int KT = KP / 16;
  for (int kt = 0; kt < KT; ++kt) {
    int buf = kt & 1;
    if (kt + 1 < KT) stage((kt + 1) * 16, buf ^ 1);
    #pragma unroll
    for (int kk = 0; kk < 16; ++kk) {
      float4 x0 = *(const float4*)&Xs[buf][kk][0][tx * 4];
      float4 x1 = *(const float4*)&Xs[buf][kk][1][tx * 4];
      float4 x2 = *(const float4*)&Xs[buf][kk][2][tx * 4];
      #pragma unroll
      for (int c = 0; c < CPT; ++c) {
        float wv = Wfs[buf][ty + 16 * c][kk];
        FMA4(acc[c][0], wv, x0); FMA4(acc[c][1], wv, x1); FMA4(acc[c][2], wv, x2);
      }
    }
    __syncthreads();
  }

  #pragma unroll
  for (int c = 0; c < CPT; ++c) {
    int co = co0 + ty + 16 * c;
    unsigned long long key = 0;
    if (co < Cout) {
      const float* av0 = (const float*)&acc[c][0];
      const float* av1 = (const float*)&acc[c][1];
      const float* av2 = (const float*)&acc[c][2];
      size_t xb2 = ((size_t)co * 3) * N + n0 + tx * 4;
      #pragma unroll
      for (int j = 0; j < 4; ++j) {
        float X0 = Xb[xb2 + j];
        float X1 = Xb[xb2 + N + j];
        float X2 = Xb[xb2 + 2 * (size_t)N + j];
        float dot = X0 * av0[j] + X1 * av1[j] + X2 * av2[j];
        unsigned long long k2 = packKey(dot, n0 + tx * 4 + j);
        if (k2 > key) key = k2;
      }
    }
    #pragma unroll
    for (int off = 8; off; off >>= 1) {
      unsigned long long o = __shfl_down(key, off);
      if (o > key) key = o;
    }
    if (tx == 0 && co < Cout) poolPart[((size_t)b * Cout + co) * 64 + blockIdx.x] = key;
  }
}

// ------------------------------------- transposed-layout MFMA bf16 VN GEMM
template<int MODE, int NS>
__global__ __launch_bounds__(256) void mfma2(
    const u16* __restrict__ W, const u16* __restrict__ Xt,
    u16* __restrict__ P, float* __restrict__ Zout,
    const float* __restrict__ biasP, const float* __restrict__ biasD,
    float* __restrict__ statSum, float* __restrict__ statSq,
    const float* __restrict__ statMean, const float* __restrict__ statIstd,
    int Cout, int Cpad, int Kpad, int N) {
  const int tid = threadIdx.x, lane = tid & 63, w = tid >> 6;
  const int quad = lane >> 4, l16 = lane & 15;
  const int b = blockIdx.z, n0 = blockIdx.x * 64, co0 = blockIdx.y * 64;
  const int n = n0 + w * 16 + l16;
  const u16* Xb = Xt + (size_t)b * 3 * N * Kpad;
  f32x4 acc[NS][3];
  #pragma unroll
  for (int s = 0; s < NS; ++s)
    #pragma unroll
    for (int v = 0; v < 3; ++v) acc[s][v] = {0.f, 0.f, 0.f, 0.f};

  for (int k0 = 0; k0 < Kpad; k0 += 32) {
    bh8 bx[3];
    #pragma unroll
    for (int v = 0; v < 3; ++v)
      bx[v] = *(const bh8*)(Xb + ((size_t)v * N + n) * Kpad + k0 + quad * 8);
    #pragma unroll
    for (int s = 0; s < NS; ++s) {
      bh8 a = *(const bh8*)(W + (size_t)(co0 + s * 16 + l16) * Kpad + k0 + quad * 8);
      #pragma unroll
      for (int v = 0; v < 3; ++v)
        acc[s][v] = __builtin_amdgcn_mfma_f32_16x16x32_bf16(a, bx[v], acc[s][v], 0, 0, 0);
    }
  }

  u16* Pb = P + (size_t)b * 3 * N * Cpad;
  #pragma unroll
  for (int s = 0; s < NS; ++s) {
    int cb = co0 + s * 16 + quad * 4;
    if constexpr (MODE == 0) {
      #pragma unroll
      for (int r = 0; r < 4; ++r) {
        int co = cb + r;
        if (co < Cout) {
          size_t zb = (((size_t)b * Cout + co) * 3) * N + n;
          Zout[zb] = acc[s][0][r];
          Zout[zb + N] = acc[s][1][r];
          Zout[zb + 2 * (size_t)N] = acc[s][2][r];
        }
      }
    } else if constexpr (MODE == 1) {
      if (cb < Cpad) {
        float q[3][4];
        #pragma unroll
        for (int r = 0; r < 4; ++r) {
          int co = cb + r;
          float b0 = 0, b1 = 0, b2 = 0;
          if (biasP != nullptr && co < Cout) {
            size_t bi = ((size_t)b * Cout + co) * 3;
            b0 = biasP[bi]; b1 = biasP[bi + 1]; b2 = biasP[bi + 2];
          }
          float q0 = acc[s][0][r] + b0, q1 = acc[s][1][r] + b1, q2 = acc[s][2][r] + b2;
          if (co >= Cout) { q0 = 0.f; q1 = 0.f; q2 = 0.f; }
          q[0][r] = q0; q[1][r] = q1; q[2][r] = q2;
          float nr = sqrtf(q0*q0 + q1*q1 + q2*q2) + 1e-6f;
          float s1 = nr, s2 = nr * nr;
          #pragma unroll
          for (int off = 1; off < 16; off <<= 1) { s1 += __shfl_xor(s1, off); s2 += __shfl_xor(s2, off); }
          if (l16 == 0 && co < Cout) { atomicAdd(&statSum[co], s1); atomicAdd(&statSq[co], s2); }
        }
        #pragma unroll
        for (int v = 0; v < 3; ++v) {
          u16 ob[4];
          ob[0] = f2b(q[v][0]); ob[1] = f2b(q[v][1]); ob[2] = f2b(q[v][2]); ob[3] = f2b(q[v][3]);
          *(ushort4*)(Pb + ((size_t)v * N + n) * Cpad + cb) = *(ushort4*)ob;
        }
      }
    } else {  // MODE 2
      if (cb < Cpad) {
        u16 pa[3][4];
        #pragma unroll
        for (int v = 0; v < 3; ++v)
          *(ushort4*)pa[v] = *(const ushort4*)(Pb + ((size_t)v * N + n) * Cpad + cb);
        float o[3][4];
        #pragma unroll
        for (int r = 0; r < 4; ++r) {
          int co = cb + r;
          float r0 = 0.f, r1 = 0.f, r2 = 0.f;
          if (co < Cout) {
            float p0 = b2f(pa[0][r]), p1 = b2f(pa[1][r]), p2 = b2f(pa[2][r]);
            float d0 = acc[s][0][r], d1 = acc[s][1][r], d2 = acc[s][2][r];
            if (biasD != nullptr) {
              size_t bi = ((size_t)b * Cout + co) * 3;
              d0 += biasD[bi]; d1 += biasD[bi + 1]; d2 += biasD[bi + 2];
            }
            float mn = statMean[co], is = statIstd[co];
            float nr = sqrtf(p0*p0 + p1*p1 + p2*p2) + 1e-6f;
            float sc = ((nr - mn) * is) / nr;
            float q0 = p0 * sc, q1 = p1 * sc, q2 = p2 * sc;
            float dot = q0*d0 + q1*d1 + q2*d2;
            if (dot < 0.f) {
              float dsq = d0*d0 + d1*d1 + d2*d2;
              float t = dot / (dsq + 1e-6f);
              q0 -= t*d0; q1 -= t*d1; q2 -= t*d2;
            }
            r0 = q0; r1 = q1; r2 = q2;
          }
          o[0][r] = r0; o[1][r] = r1; o[2][r] = r2;
        }
        #pragma unroll
        for (int v = 0; v < 3; ++v) {
          u16 ob[4];
          ob[0] = f2b(o[v][0]); ob[1] = f2b(o[v][1]); ob[2] = f2b(o[v][2]); ob[3] = f2b(o[v][3]);
          *(ushort4*)(Pb + ((size_t)v * N + n) * Cpad + cb) = *(ushort4*)ob;
        }
      }
    }
  }
}

// ----------------------- consolidated init: fp32 weight pads + zeros
__device__ __forceinline__ void padf32(size_t r, const float* W, float* Wp,
                                       int Cout, int Cin, int ws, int Kpad) {
  int co = (int)(r / Kpad), ci = (int)(r - (size_t)co * Kpad);
  Wp[r] = (co < Cout && ci < Cin) ? W[(size_t)co * ws + ci] : 0.f;
}
__global__ void prep_f32(float* stats,
                         const float* stpW, float* Wpoolp,
                         const float* c1f, float* Wc1f, const float* c1d, float* Wc1d,
                         const float* s1f, float* Ws1f, const float* s1d, float* Ws1d,
                         const float* s2f, float* Ws2f, const float* s2d, float* Ws2d,
                         const float* s3f, float* Ws3f, const float* s3d, float* Ws3d,
                         float* h0, int N) {
  size_t t = (size_t)blockIdx.x * 256 + threadIdx.x;
  if (t < 1024) { stats[t] = 0.f; return; }
  t -= 1024;
  if (t < 135168) { padf32(t, stpW, Wpoolp, 341, 341, 341, 352); return; }
  t -= 135168;
  if (t < 1024) { padf32(t, c1f, Wc1f, 21, 21, 21, 32); return; }
  t -= 1024;
  if (t < 1024) { padf32(t, c1d, Wc1d, 21, 21, 21, 32); return; }
  t -= 1024;
  if (t < 1024) { padf32(t, s1f, Ws1f, 21, 21, 21, 32); return; }
  t -= 1024;
  if (t < 1024) { padf32(t, s1d, Ws1d, 21, 21, 21, 32); return; }
  t -= 1024;
  if (t < 2048) { padf32(t, s2f, Ws2f, 42, 21, 21, 32); return; }
  t -= 2048;
  if (t < 2048) { padf32(t, s2d, Ws2d, 42, 21, 21, 32); return; }
  t -= 2048;
  if (t < 18432) { padf32(t, s3f, Ws3f, 341, 42, 42, 48); return; }
  t -= 18432;
  if (t < 18432) { padf32(t, s3d, Ws3d, 341, 42, 42, 48); return; }
  t -= 18432;
  // h0 pad channels [21,32): 8 * 11*3*N
  size_t per = (size_t)11 * 3 * N;
  if (t < 8 * per) {
    int b = (int)(t / per);
    size_t r = t - (size_t)b * per;
    h0[(((size_t)b * 32 + 21) * 3) * N + r] = 0.f;
  }
}

// ----------------------- consolidated init: bf16 weight pads
__device__ __forceinline__ void padbf(size_t r, const float* W, u16* Wp,
                                      int Cout, int Cin, int ws, int Kpad) {
  int co = (int)(r / Kpad), ci = (int)(r - (size_t)co * Kpad);
  Wp[r] = (co < Cout && ci < Cin) ? f2b(W[(size_t)co * ws + ci]) : (u16)0;
}
__global__ void prep_bf16(const float* w1f, u16* W1fp, const float* w1d, u16* W1dp,
                          const float* w2f, u16* W2fp, const float* w2d, u16* W2dp,
                          const float* c3w, u16* Wc3p,
                          const float* c2f, u16* Wc2f, const float* c2d, u16* Wc2d,
                          const float* zl, u16* Wzp) {
  size_t t = (size_t)blockIdx.x * 256 + threadIdx.x;
  if (t < 135168) { padbf(t, w1f, W1fp, 341, 341, 682, 352); return; }
  t -= 135168;
  if (t < 135168) { padbf(t, w1d, W1dp, 341, 341, 682, 352); return; }
  t -= 135168;
  if (t < 67584) { padbf(t, w2f, W2fp, 170, 341, 341, 352); return; }
  t -= 67584;
  if (t < 67584) { padbf(t, w2d, W2dp, 170, 341, 341, 352); return; }
  t -= 67584;
  if (t < 24576) { padbf(t, c3w, Wc3p, 341, 42, 42, 64); return; }
  t -= 24576;
  if (t < 4096) { padbf(t, c2f, Wc2f, 42, 42, 42, 64); return; }
  t -= 4096;
  if (t < 4096) { padbf(t, c2d, Wc2d, 42, 42, 42, 64); return; }
  t -= 4096;
  if (t < 3072) { padbf(t, zl, Wzp, 3, 170, 170, 192); }
}

// ----------------------------------------------------------- small kernels
__global__ void zero_kernel(float* p, int n) {
  int t = blockIdx.x * 256 + threadIdx.x;
  if (t < n) p[t] = 0.f;
}

// computes mean/istd AND re-zeroes sum/sq (512 wide) for the next layer
__global__ void finalize_kernel(float* __restrict__ sum, float* __restrict__ sq,
                                float* __restrict__ mean, float* __restrict__ istd,
                                int C, float invCount) {
  int c = blockIdx.x * 256 + threadIdx.x;
  if (c < C) {
    float m = sum[c] * invCount;
    float v = sq[c] * invCount - m * m;
    if (v < 0.f) v = 0.f;
    mean[c] = m;
    istd[c] = 1.f / sqrtf(v + 1e-5f);
  }
  if (c < 512) { sum[c] = 0.f; sq[c] = 0.f; }
}

__global__ __launch_bounds__(64) void pool_reduce(const unsigned long long* __restrict__ part,
                                                  const float* __restrict__ s3,
                                                  float* __restrict__ pooled, int N) {
  int co = blockIdx.x, b = blockIdx.y, lane = threadIdx.x;
  unsigned long long key = part[((size_t)b * 341 + co) * 64 + lane];
  #pragma unroll
  for (int off = 32; off; off >>= 1) {
    unsigned long long o = __shfl_down(key, off);
    if (o > key) key = o;
  }
  if (lane == 0) {
    int n = (int)(0xFFFFFFFFu - (unsigned)(key & 0xFFFFFFFFull));
    size_t base = ((size_t)b * 352 + co) * 3;       // padded channel stride
    size_t obase = ((size_t)b * 341 + co) * 3;
    pooled[obase + 0] = s3[(base + 0) * N + n];
    pooled[obase + 1] = s3[(base + 1) * N + n];
    pooled[obase + 2] = s3[(base + 2) * N + n];
  }
}

// vn_lrelu on (B,Cin,3) tiny tensors (bn stats over batch axis only)
__global__ __launch_bounds__(64) void stf_lrelu(const float* __restrict__ Wf,
                                                const float* __restrict__ Wd,
                                                const float* __restrict__ X,
                                                float* __restrict__ Y, int Cin, int Cout) {
  __shared__ float P[24], D[24], NORM[8], SC[8], DOT[8], DSQ[8], MS[2];
  int co = blockIdx.x, tid = threadIdx.x;
  if (tid < 48) {
    int l = tid < 24 ? tid : tid - 24;
    int b = l / 3, v = l - b * 3;
    const float* W = (tid < 24 ? Wf : Wd) + (size_t)co * Cin;
    const float* xb = X + ((size_t)b * Cin) * 3 + v;
    float acc = 0.f;
    for (int ci = 0; ci < Cin; ++ci) acc += W[ci] * xb[ci * 3];
    if (tid < 24) P[l] = acc; else D[l] = acc;
  }
  __syncthreads();
  if (tid < 8) NORM[tid] = sqrtf(P[tid*3]*P[tid*3] + P[tid*3+1]*P[tid*3+1] + P[tid*3+2]*P[tid*3+2]) + 1e-6f;
  __syncthreads();
  if (tid == 0) {
    float m = 0.f;
    for (int b2 = 0; b2 < 8; ++b2) m += NORM[b2];
    m *= 0.125f;
    float var = 0.f;
    for (int b2 = 0; b2 < 8; ++b2) { float dd = NORM[b2] - m; var += dd * dd; }
    var *= 0.125f;
    MS[0] = m; MS[1] = 1.f / sqrtf(var + 1e-5f);
  }
  __syncthreads();
  if (tid < 8) {
    float sc = ((NORM[tid] - MS[0]) * MS[1]) / NORM[tid];
    float dot = 0.f, dsq = 0.f;
    for (int v = 0; v < 3; ++v) {
      float pb = P[tid*3+v] * sc; float dv = D[tid*3+v];
      dot += pb * dv; dsq += dv * dv;
    }
    SC[tid] = sc; DOT[tid] = dot; DSQ[tid] = dsq;
  }
  __syncthreads();
  if (tid < 24) {
    int b = tid / 3;
    float pb = P[tid] * SC[b];
    float o = (DOT[b] >= 0.f) ? pb : pb - (DOT[b] / (DSQ[b] + 1e-6f)) * D[tid];
    Y[((size_t)b * Cout + co) * 3 + (tid - b * 3)] = o;
  }
}

__global__ void vnlin_small(const float* __restrict__ W, const float* __restrict__ X,
                            float* __restrict__ Y, int Cin, int Cout) {
  int t = blockIdx.x * 256 + threadIdx.x;   // over 8*Cout*3
  if (t >= 8 * Cout * 3) return;
  int v = t % 3, r = t / 3;
  int co = r % Cout, b = r / Cout;
  float acc = 0.f;
  for (int ci = 0; ci < Cin; ++ci) acc += W[(size_t)co * Cin + ci] * X[((size_t)b * Cin + ci) * 3 + v];
  Y[t] = acc;
}

// concat [h1(32ch padded) ; broadcast sfin ; zero-pad] -> ^T bf16 [b][v][n][64]
__global__ __launch_bounds__(256) void concat_tt(const float* __restrict__ h1,
                                                 const float* __restrict__ sfin,
                                                 u16* __restrict__ s2bb, int N) {
  __shared__ u16 tile[64][66];
  int b = blockIdx.z, v = blockIdx.y, n0 = blockIdx.x * 64;
  int tn = threadIdx.x & 63, tc = threadIdx.x >> 6;   // tc in [0,4)
  for (int c = tc; c < 64; c += 4) {
    u16 val = 0;
    if (c < 21) val = f2b(h1[(((size_t)b * 32 + c) * 3 + v) * N + n0 + tn]);
    else if (c < 42) val = f2b(sfin[((size_t)b * 21 + (c - 21)) * 3 + v]);
    tile[c][tn] = val;
  }
  __syncthreads();
  u16* dst = s2bb + (((size_t)b * 3 + v) * N + n0) * 64;
  for (int n = tc; n < 64; n += 4)
    dst[(size_t)n * 64 + tn] = tile[tn][n];
}

// in-place bn on transposed H + accumulate per-(c,v) sums for h_mean
__global__ __launch_bounds__(384) void bn_apply_mean(u16* __restrict__ H,
    const float* __restrict__ sMean, const float* __restrict__ sIstd,
    float* __restrict__ HmAcc, int N) {
  int c = threadIdx.x;
  if (c >= 341) return;
  int b = blockIdx.y, nt = blockIdx.x;
  float mn = sMean[c], is = sIstd[c];
  float a0 = 0.f, a1 = 0.f, a2 = 0.f;
  size_t base = (size_t)b * 3 * N * 352;
  for (int n = nt * 64; n < nt * 64 + 64; ++n) {
    size_t i0 = base + ((size_t)0 * N + n) * 352 + c;
    size_t i1 = base + ((size_t)1 * N + n) * 352 + c;
    size_t i2 = base + ((size_t)2 * N + n) * 352 + c;
    float p0 = b2f(H[i0]), p1 = b2f(H[i1]), p2 = b2f(H[i2]);
    float nr = sqrtf(p0*p0 + p1*p1 + p2*p2) + 1e-6f;
    float sc = ((nr - mn) * is) / nr;
    p0 *= sc; p1 *= sc; p2 *= sc;
    H[i0] = f2b(p0); H[i1] = f2b(p1); H[i2] = f2b(p2);
    a0 += p0; a1 += p1; a2 += p2;
  }
  size_t hb = ((size_t)b * 341 + c) * 3;
  atomicAdd(&HmAcc[hb], a0); atomicAdd(&HmAcc[hb + 1], a1); atomicAdd(&HmAcc[hb + 2], a2);
}

// bias terms for std1: W[:,341:682] . (HmAcc * invN)
__global__ void bias_kernel(const float* __restrict__ Wf, const float* __restrict__ Wd,
                            const float* __restrict__ Hm, float invN,
                            float* __restrict__ biasP, float* __restrict__ biasD) {
  int t = blockIdx.x * 256 + threadIdx.x;   // over 8*341*3
  if (t >= 8 * 341 * 3) return;
  int v = t % 3, r = t / 3;
  int co = r % 341, b = r / 341;
  const float* hm = Hm + (size_t)b * 1023 + v;
  float ap = 0.f, ad = 0.f;
  for (int j = 0; j < 341; ++j) {
    float h = hm[j * 3] * invN;
    ap += Wf[(size_t)co * 682 + 341 + j] * h;
    ad += Wd[(size_t)co * 682 + 341 + j] * h;
  }
  biasP[t] = ap; biasD[t] = ad;
}

// h_std einsum + partial max over an n-chunk; rows >=341 use HmAcc*invN.
__global__ __launch_bounds__(256) void final_max_part(const u16* __restrict__ H,
    const float* __restrict__ Hm, float invN, const float* __restrict__ z0,
    float* __restrict__ part, int N, int NT) {
  __shared__ float red[3][4][64];
  int b = blockIdx.z, nt = blockIdx.y;
  int il = threadIdx.x & 63, nsub = threadIdx.x >> 6;
  int i = blockIdx.x * 64 + il;
  bool valid = i < 682, lo = i < 341;
  float c0 = 0, c1 = 0, c2 = 0;
  if (valid && !lo) {
    size_t hb = ((size_t)b * 341 + (i - 341)) * 3;
    c0 = Hm[hb] * invN; c1 = Hm[hb + 1] * invN; c2 = Hm[hb + 2] * invN;
  }
  const float* zb = z0 + (size_t)b * 9 * N;
  const u16* Hb = H + (size_t)b * 3 * N * 352;
  float m0 = -3.4e38f, m1 = -3.4e38f, m2 = -3.4e38f;
  int ii = lo ? i : 0;
  int chunk = N / NT, nBeg = nt * chunk;
  for (int n = nBeg + nsub; n < nBeg + chunk; n += 4) {
    float a0, a1, a2;
    if (lo) {
      a0 = b2f(Hb[((size_t)0 * N + n) * 352 + ii]);
      a1 = b2f(Hb[((size_t)1 * N + n) * 352 + ii]);
      a2 = b2f(Hb[((size_t)2 * N + n) * 352 + ii]);
    } else { a0 = c0; a1 = c1; a2 = c2; }
    float s0 = a0 * zb[n]                + a1 * zb[3 * (size_t)N + n] + a2 * zb[6 * (size_t)N + n];
    float s1 = a0 * zb[N + n]            + a1 * zb[4 * (size_t)N + n] + a2 * zb[7 * (size_t)N + n];
    float s2 = a0 * zb[2 * (size_t)N + n]+ a1 * zb[5 * (size_t)N + n] + a2 * zb[8 * (size_t)N + n];
    m0 = fmaxf(m0, s0); m1 = fmaxf(m1, s1); m2 = fmaxf(m2, s2);
  }
  red[0][nsub][il] = m0; red[1][nsub][il] = m1; red[2][nsub][il] = m2;
  __syncthreads();
  if (nsub == 0 && valid) {
    for (int q = 1; q < 4; ++q) {
      m0 = fmaxf(m0, red[0][q][il]); m1 = fmaxf(m1, red[1][q][il]); m2 = fmaxf(m2, red[2][q][il]);
    }
    size_t pb = ((size_t)b * 682 + i) * 3;
    part[(pb + 0) * NT + nt] = m0;
    part[(pb + 1) * NT + nt] = m1;
    part[(pb + 2) * NT + nt] = m2;
  }
}

__global__ void final_max_reduce(const float* __restrict__ part,
                                 float* __restrict__ out, int NT) {
  int t = blockIdx.x * 256 + threadIdx.x;   // over 8*682*3
  if (t >= 8 * 682 * 3) return;
  const float* p = part + (size_t)t * NT;
  float m = p[0];
  for (int k = 1; k < NT; ++k) m = fmaxf(m, p[k]);
  out[t] = m;
}

// ------------------------------------------------------------------- host
extern "C" void kernel_launch(void* const* d_in, const int* in_sizes, int n_in,
                              void* d_out, int out_size, void* d_ws, size_t ws_size,
                              hipStream_t stream) {
  (void)in_sizes; (void)n_in; (void)out_size; (void)ws_size;
  const float* x       = (const float*)d_in[0];
  const float* pos_Wf  = (const float*)d_in[1];
  const float* pos_Wd  = (const float*)d_in[2];
  const float* pool_Wd = (const float*)d_in[3];
  const float* c1_Wf   = (const float*)d_in[4];
  const float* c1_Wd   = (const float*)d_in[5];
  const float* st1_Wf  = (const float*)d_in[6];
  const float* st1_Wd  = (const float*)d_in[7];
  const float* st2_Wf  = (const float*)d_in[8];
  const float* st2_Wd  = (const float*)d_in[9];
  const float* st3_Wf  = (const float*)d_in[10];
  const float* st3_Wd  = (const float*)d_in[11];
  const float* stp_Wd  = (const float*)d_in[12];
  const float* stf1_Wf = (const float*)d_in[13];
  const float* stf1_Wd = (const float*)d_in[14];
  const float* stf2_Wf = (const float*)d_in[15];
  const float* stf2_Wd = (const float*)d_in[16];
  const float* stf3_W  = (const float*)d_in[17];
  const float* c2_Wf   = (const float*)d_in[18];
  const float* c2_Wd   = (const float*)d_in[19];
  const float* c3_W    = (const float*)d_in[20];
  const float* std1_Wf = (const float*)d_in[21];
  const float* std1_Wd = (const float*)d_in[22];
  const float* std2_Wf = (const float*)d_in[23];
  const float* std2_Wd = (const float*)d_in[24];
  const float* stdlin  = (const float*)d_in[25];

  float* outv  = (float*)d_out;           // fp32: [8*2046] ++ z0 [8*3*3*4096]
  float* z0out = outv + 8 * 2046;

  const int N = 4096;
  const int NT = 32;                       // final_max n-tiles
  char* ws = (char*)d_ws;
  size_t off = 0;
  auto alloc = [&](size_t bytes) -> char* {
    char* p = ws + off;
    off += (bytes + 255) & ~(size_t)255;
    return p;
  };
  float* stats = (float*)alloc(2048 * sizeof(float));
  float* sSum = stats, *sSq = stats + 512, *sMean = stats + 1024, *sIstd = stats + 1536;
  int* idx = (int*)alloc((size_t)8 * N * 20 * 4);
  unsigned long long* poolPart = (unsigned long long*)alloc((size_t)8 * 341 * 64 * 8);
  float* fmPart = (float*)alloc((size_t)8 * 682 * 3 * NT * 4);
  // padded fp32 weights
  float* Wpoolp = (float*)alloc((size_t)384 * 352 * 4);
  float* Wc1f = (float*)alloc(32 * 32 * 4);
  float* Wc1d = (float*)alloc(32 * 32 * 4);
  float* Ws1f = (float*)alloc(32 * 32 * 4);
  float* Ws1d = (float*)alloc(32 * 32 * 4);
  float* Ws2f = (float*)alloc(64 * 32 * 4);
  float* Ws2d = (float*)alloc(64 * 32 * 4);
  float* Ws3f = (float*)alloc(384 * 48 * 4);
  float* Ws3d = (float*)alloc(384 * 48 * 4);
  float* pooled = (float*)alloc(8 * 341 * 3 * 4);
  float* stf1o  = (float*)alloc(8 * 170 * 3 * 4);
  float* stf2o  = (float*)alloc(8 * 85 * 3 * 4);
  float* sfin   = (float*)alloc(8 * 21 * 3 * 4);
  float* Hm     = (float*)alloc(8 * 1023 * 4);
  float* biasP  = (float*)alloc(8 * 341 * 3 * 4);
  float* biasD  = (float*)alloc(8 * 341 * 3 * 4);
  const size_t P32 = (size_t)8 * 32 * 3 * N;         // padded 32-ch elems
  const size_t T352 = (size_t)8 * 3 * N * 352 * 2;   // bf16 ^T 352-ch bytes
  const size_t T192 = (size_t)8 * 3 * N * 192 * 2;
  const size_t T64  = (size_t)8 * 3 * N * 64 * 2;
  const size_t F352 = (size_t)8 * 352 * 3 * N * 4;   // fp32 padded st3o bytes
  char* regionA = alloc(T352);                       // 69.2MB: early stack / Pstd1
  char* regionB = alloc(F352);                       // 138.4MB
  float* h0  = (float*)regionA;                      // [b][32][3][N]
  float* h1  = h0 + P32;
  float* s1b = h1 + P32;
  float* s2b = s1b + P32;                            // [b][32][3][N] (Cpad 32)
  float* st3o = (float*)regionB;                     // [b][352][3][N]
  u16* Hbuf  = (u16*)regionB;                        // c3 out ^T
  u16* Pstd2 = (u16*)(regionB + T352);
  u16* s2bb  = (u16*)(regionB + T352 + T192);
  u16* h2b   = (u16*)(regionB + T352 + T192 + T64);
  u16* Pstd1 = (u16*)regionA;
  // padded bf16 weights in poolPart (dead after pool_reduce)
  u16* W1fp = (u16*)poolPart;                 // 384x352
  u16* W1dp = W1fp + 384 * 352;
  u16* W2fp = W1dp + 384 * 352;               // 192x352
  u16* W2dp = W2fp + 192 * 352;
  u16* Wc3p = W2dp + 192 * 352;               // 384x64
  u16* Wc2f = Wc3p + 384 * 64;                // 64x64
  u16* Wc2d = Wc2f + 64 * 64;
  u16* Wzp  = Wc2d + 64 * 64;                 // 16x192

  dim3 blk256(256), blk64(64);
  const float invBN = 1.f / (8.f * N);
  // bf16 mfma lrelu layer (transposed tensors)
  auto run_mfma = [&](const u16* Wf, const u16* Wd, const u16* X, u16* P,
                      const float* bP, const float* bD,
                      int Cout, int Cpad, int Kpad, int coTiles) {
    dim3 grid(64, coTiles, 8);
    mfma2<1, 4><<<grid, blk256, 0, stream>>>(Wf, X, P, nullptr, bP, nullptr,
                                             sSum, sSq, nullptr, nullptr, Cout, Cpad, Kpad, N);
    finalize_kernel<<<dim3(2), blk256, 0, stream>>>(sSum, sSq, sMean, sIstd, Cout, invBN);
    mfma2<2, 4><<<grid, blk256, 0, stream>>>(Wd, X, P, nullptr, nullptr, bD,
                                             nullptr, nullptr, sMean, sIstd, Cout, Cpad, Kpad, N);
  };

  // 0. consolidated init (stats zero + fp32 pads + h0 pad-zero); bf16 pads
  {
    size_t tot = 1024 + 135168 + 4 * 1024 + 2 * 2048 + 2 * 18432 + (size_t)8 * 11 * 3 * N;
    prep_f32<<<dim3((unsigned)((tot + 255) / 256)), blk256, 0, stream>>>(
        stats, stp_Wd, Wpoolp, c1_Wf, Wc1f, c1_Wd, Wc1d, st1_Wf, Ws1f, st1_Wd, Ws1d,
        st2_Wf, Ws2f, st2_Wd, Ws2d, st3_Wf, Ws3f, st3_Wd, Ws3d, h0, N);
  }
  // 1. KNN (one wave per point)
  knn_kernel<<<dim3(N / 4, 8), blk256, 0, stream>>>(x, idx, N);
  // 2. pos layer
  pos_stats<<<dim3(N * 20 / 256, 8), blk256, 0, stream>>>(x, idx, pos_Wf, sSum, sSq, N);
  finalize_kernel<<<dim3(2), blk256, 0, stream>>>(sSum, sSq, sMean, sIstd, 21, 1.f / (8.f * N * 20.f));
  pos_apply<<<dim3(N, 8), blk64, 0, stream>>>(x, idx, pos_Wf, pos_Wd, pool_Wd, sMean, sIstd, h0, N);

  // 3. early fp32 chain (argmax-exact path), async-dbuf over padded tensors
  {
    dim3 g1(64, 1, 8);
    gemm_db<5, 2><<<g1, blk256, 0, stream>>>(Wc1f, h0, h1, sSum, sSq, nullptr, nullptr, 21, 32, 32, N);
    finalize_kernel<<<dim3(2), blk256, 0, stream>>>(sSum, sSq, sMean, sIstd, 21, invBN);
    gemm_db<6, 2><<<g1, blk256, 0, stream>>>(Wc1d, h0, h1, nullptr, nullptr, sMean, sIstd, 21, 32, 32, N);
    gemm_db<5, 2><<<g1, blk256, 0, stream>>>(Ws1f, h1, s1b, sSum, sSq, nullptr, nullptr, 21, 32, 32, N);
    finalize_kernel<<<dim3(2), blk256, 0, stream>>>(sSum, sSq, sMean, sIstd, 21, invBN);
    gemm_db<6, 2><<<g1, blk256, 0, stream>>>(Ws1d, h1, s1b, nullptr, nullptr, sMean, sIstd, 21, 32, 32, N);
    dim3 g2(64, 2, 8);
    gemm_db<5, 2><<<g2, blk256, 0, stream>>>(Ws2f, s1b, s2b, sSum, sSq, nullptr, nullptr, 42, 48, 32, N);
    finalize_kernel<<<dim3(2), blk256, 0, stream>>>(sSum, sSq, sMean, sIstd, 42, invBN);
    gemm_db<6, 2><<<g2, blk256, 0, stream>>>(Ws2d, s1b, s2b, nullptr, nullptr, sMean, sIstd, 42, 48, 32, N);
    dim3 g3(64, 6, 8);
    gemm_db<5, 4><<<g3, blk256, 0, stream>>>(Ws3f, s2b, st3o, sSum, sSq, nullptr, nullptr, 341, 352, 48, N);
    finalize_kernel<<<dim3(2), blk256, 0, stream>>>(sSum, sSq, sMean, sIstd, 341, invBN);
    gemm_db<6, 4><<<g3, blk256, 0, stream>>>(Ws3d, s2b, st3o, nullptr, nullptr, sMean, sIstd, 341, 352, 48, N);
  }

  // 4. st_pool over N (fp32-exact argmax), async-dbuf CPT=6
  gemm_pool_db<<<dim3(64, 4, 8), blk256, 0, stream>>>(Wpoolp, st3o, poolPart, 341, N);
  pool_reduce<<<dim3(341, 8), blk64, 0, stream>>>(poolPart, st3o, pooled, N);

  // 5. bf16 weight pads (poolPart now dead)
  prep_bf16<<<dim3((441344 + 255) / 256), blk256, 0, stream>>>(
      std1_Wf, W1fp, std1_Wd, W1dp, std2_Wf, W2fp, std2_Wd, W2dp,
      c3_W, Wc3p, c2_Wf, Wc2f, c2_Wd, Wc2d, stdlin, Wzp);

  // 6. stf chain (tiny)
  stf_lrelu<<<dim3(170), blk64, 0, stream>>>(stf1_Wf, stf1_Wd, pooled, stf1o, 341, 170);
  stf_lrelu<<<dim3(85),  blk64, 0, stream>>>(stf2_Wf, stf2_Wd, stf1o, stf2o, 170, 85);
  vnlin_small<<<dim3(2), blk256, 0, stream>>>(stf3_W, stf2o, sfin, 85, 21);

  // 7. concat -> transposed bf16 (LDS-tiled); c2 (mfma)
  concat_tt<<<dim3(N / 64, 3, 8), blk256, 0, stream>>>(h1, sfin, s2bb, N);
  run_mfma(Wc2f, Wc2d, s2bb, h2b, nullptr, nullptr, 42, 64, 64, 1);

  // 8. c3 + bn (mfma P+stats, then fused bn-apply + h_mean)
  {
    dim3 grid(64, 6, 8);
    mfma2<1, 4><<<grid, blk256, 0, stream>>>(Wc3p, h2b, Hbuf, nullptr, nullptr, nullptr,
                                             sSum, sSq, nullptr, nullptr, 341, 352, 64, N);
  }
  finalize_kernel<<<dim3(2), blk256, 0, stream>>>(sSum, sSq, sMean, sIstd, 341, invBN);
  zero_kernel<<<dim3(32), blk256, 0, stream>>>(Hm, 8 * 1023);
  bn_apply_mean<<<dim3(64, 8), dim3(384), 0, stream>>>(Hbuf, sMean, sIstd, Hm, N);
  bias_kernel<<<dim3(32), blk256, 0, stream>>>(std1_Wf, std1_Wd, Hm, 1.f / (float)N, biasP, biasD);

  // 9. VNStdFeature (mfma)
  run_mfma(W1fp, W1dp, Hbuf, Pstd1, biasP, biasD, 341, 352, 352, 6);
  run_mfma(W2fp, W2dp, Pstd1, Pstd2, nullptr, nullptr, 170, 192, 352, 3);

  // 10. z0 (mfma MODE0, fp32 out) + n-tiled einsum/max + reduce
  mfma2<0, 1><<<dim3(64, 1, 8), blk256, 0, stream>>>(Wzp, Pstd2, nullptr, z0out,
                                                     nullptr, nullptr, nullptr, nullptr,
                                                     nullptr, nullptr, 3, 16, 192, N);
  final_max_part<<<dim3(11, NT, 8), blk256, 0, stream>>>(Hbuf, Hm, 1.f / (float)N, z0out, fmPart, N, NT);
  final_max_reduce<<<dim3((8 * 682 * 3 + 255) / 256), blk256, 0, stream>>>(fmPart, outv, NT);
}